// Round 2
// baseline (2289.546 us; speedup 1.0000x reference)
//
#include <hip/hip_runtime.h>
#include <hip/hip_bf16.h>
#include <stdint.h>

typedef short  bf16x8_t __attribute__((ext_vector_type(8)));
typedef float  f32x4_t  __attribute__((ext_vector_type(4)));
typedef unsigned short u16;
typedef unsigned int   u32;

#define DEV __device__ __forceinline__

DEV u16 f2bf(float f){
  u32 u = __float_as_uint(f);
  u += 0x7fffu + ((u >> 16) & 1u);     // RNE
  return (u16)(u >> 16);
}
DEV float bf2f(u16 h){ return __uint_as_float(((u32)h) << 16); }

DEV void gl16(const void* g, void* l){
  __builtin_amdgcn_global_load_lds(
      (const __attribute__((address_space(1))) void*)g,
      (__attribute__((address_space(3))) void*)l, 16, 0, 0);
}

// ---------------- f32 -> bf16 convert (8 elems/thread) ----------------
__global__ __launch_bounds__(256) void cvt_k(const float* __restrict__ in,
                                             u16* __restrict__ out, int n8){
  int i = blockIdx.x * 256 + threadIdx.x;
  if (i >= n8) return;
  const float4* p = (const float4*)in;
  float4 a = p[(size_t)i*2], b = p[(size_t)i*2+1];
  bf16x8_t o;
  o[0]=(short)f2bf(a.x); o[1]=(short)f2bf(a.y); o[2]=(short)f2bf(a.z); o[3]=(short)f2bf(a.w);
  o[4]=(short)f2bf(b.x); o[5]=(short)f2bf(b.y); o[6]=(short)f2bf(b.z); o[7]=(short)f2bf(b.w);
  *(bf16x8_t*)(out + (size_t)i*8) = o;
}

// ---------------- RMSNorm: fp32 row (D=2048) -> bf16 ----------------
__global__ __launch_bounds__(256) void rmsnorm_k(const float* __restrict__ x,
                                                 const float* __restrict__ w,
                                                 u16* __restrict__ y){
  int row = blockIdx.x, t = threadIdx.x;
  const float4* xr = (const float4*)(x + (size_t)row*2048);
  float4 a = xr[t*2], b = xr[t*2+1];
  float ss = a.x*a.x+a.y*a.y+a.z*a.z+a.w*a.w + b.x*b.x+b.y*b.y+b.z*b.z+b.w*b.w;
  #pragma unroll
  for (int m = 32; m; m >>= 1) ss += __shfl_xor(ss, m, 64);
  __shared__ float red[4];
  if ((t & 63) == 0) red[t >> 6] = ss;
  __syncthreads();
  float tot = red[0]+red[1]+red[2]+red[3];
  float rs = rsqrtf(tot * (1.0f/2048.0f) + 1e-6f);
  const float4* wr = (const float4*)w;
  float4 wa = wr[t*2], wb = wr[t*2+1];
  bf16x8_t o;
  o[0]=(short)f2bf(a.x*rs*wa.x); o[1]=(short)f2bf(a.y*rs*wa.y);
  o[2]=(short)f2bf(a.z*rs*wa.z); o[3]=(short)f2bf(a.w*rs*wa.w);
  o[4]=(short)f2bf(b.x*rs*wb.x); o[5]=(short)f2bf(b.y*rs*wb.y);
  o[6]=(short)f2bf(b.z*rs*wb.z); o[7]=(short)f2bf(b.w*rs*wb.w);
  *(bf16x8_t*)(y + (size_t)row*2048 + t*8) = o;
}

// ---- RMSNorm2: h = x(f32) + t1(bf16); y = rmsnorm(h)*w -> bf16 ----
__global__ __launch_bounds__(256) void rmsnorm2_k(const float* __restrict__ x,
                                                  const u16* __restrict__ t1,
                                                  const float* __restrict__ w,
                                                  u16* __restrict__ y){
  int row = blockIdx.x, t = threadIdx.x;
  const float4* xr = (const float4*)(x + (size_t)row*2048);
  float4 a = xr[t*2], b = xr[t*2+1];
  bf16x8_t tv = *(const bf16x8_t*)(t1 + (size_t)row*2048 + t*8);
  float h[8];
  h[0]=a.x+bf2f((u16)tv[0]); h[1]=a.y+bf2f((u16)tv[1]);
  h[2]=a.z+bf2f((u16)tv[2]); h[3]=a.w+bf2f((u16)tv[3]);
  h[4]=b.x+bf2f((u16)tv[4]); h[5]=b.y+bf2f((u16)tv[5]);
  h[6]=b.z+bf2f((u16)tv[6]); h[7]=b.w+bf2f((u16)tv[7]);
  float ss = 0.f;
  #pragma unroll
  for (int j=0;j<8;j++) ss += h[j]*h[j];
  #pragma unroll
  for (int m = 32; m; m >>= 1) ss += __shfl_xor(ss, m, 64);
  __shared__ float red[4];
  if ((t & 63) == 0) red[t >> 6] = ss;
  __syncthreads();
  float tot = red[0]+red[1]+red[2]+red[3];
  float rs = rsqrtf(tot * (1.0f/2048.0f) + 1e-6f);
  const float4* wr = (const float4*)w;
  float4 wa = wr[t*2], wb = wr[t*2+1];
  bf16x8_t o;
  o[0]=(short)f2bf(h[0]*rs*wa.x); o[1]=(short)f2bf(h[1]*rs*wa.y);
  o[2]=(short)f2bf(h[2]*rs*wa.z); o[3]=(short)f2bf(h[3]*rs*wa.w);
  o[4]=(short)f2bf(h[4]*rs*wb.x); o[5]=(short)f2bf(h[5]*rs*wb.y);
  o[6]=(short)f2bf(h[6]*rs*wb.z); o[7]=(short)f2bf(h[7]*rs*wb.w);
  *(bf16x8_t*)(y + (size_t)row*2048 + t*8) = o;
}

// ---------------- RoPE in-place on q,k (bf16, B,S,H,HD) ----------------
__global__ __launch_bounds__(256) void rope_k(u16* __restrict__ q, u16* __restrict__ k,
                                              const float* __restrict__ fc,
                                              const float* __restrict__ fs){
  int i = blockIdx.x * 256 + threadIdx.x;   // 0 .. B*S*H*64-1 (exact)
  int ii = i & 63; int h = (i >> 6) & 15; int bs = i >> 10;
  int s = bs & 2047;
  size_t off = (size_t)bs*2048 + h*128 + 2*ii;
  float c = fc[s*64+ii], sn = fs[s*64+ii];
  u32 qq = *(u32*)(q + off);
  float xr = bf2f((u16)(qq & 0xffff)), xi = bf2f((u16)(qq >> 16));
  *(u32*)(q + off) = (u32)f2bf(xr*c - xi*sn) | ((u32)f2bf(xr*sn + xi*c) << 16);
  u32 kk = *(u32*)(k + off);
  xr = bf2f((u16)(kk & 0xffff)); xi = bf2f((u16)(kk >> 16));
  *(u32*)(k + off) = (u32)f2bf(xr*c - xi*sn) | ((u32)f2bf(xr*sn + xi*c) << 16);
}

// ---------------- GEMM: C(MxN) = A(MxK,bf16) * B(NxK,bf16)^T (+epilogue) ----
// EPI: 0 = bf16 out; 1 = silu -> bf16; 2 = v*aux(bf16) -> bf16 (in-place ok);
//      4 = f32 out = v + aux(f32) + aux2(bf16)
#define GBM 128
#define GBN 128
#define GBK 32

template<int EPI>
__global__ __launch_bounds__(256) void gemm_bt(const u16* __restrict__ A,
                                               const u16* __restrict__ B,
                                               void* __restrict__ C,
                                               const void* __restrict__ aux,
                                               const void* __restrict__ aux2,
                                               int M, int N, int K){
  __shared__ __align__(16) u16 sA[2][GBM*GBK];
  __shared__ __align__(16) u16 sB[2][GBN*GBK];
  int tid = threadIdx.x, lane = tid & 63, wave = tid >> 6;
  int nbn = N / GBN;
  int nwg = gridDim.x, bid = blockIdx.x;
  // bijective XCD swizzle (m204)
  int qq = nwg >> 3, rr = nwg & 7;
  int xc = bid & 7, yy = bid >> 3;
  int wg = (xc < rr ? xc*(qq+1) : rr*(qq+1) + (xc-rr)*qq) + yy;
  int tm = wg / nbn, tn = wg % nbn;
  size_t m0 = (size_t)tm * GBM, n0 = (size_t)tn * GBN;
  const u16* Ag = A + m0 * K;
  const u16* Bg = B + n0 * K;
  int wm = wave >> 1, wn = wave & 1;

  f32x4_t acc[4][4];
  #pragma unroll
  for (int i=0;i<4;i++)
    #pragma unroll
    for (int j=0;j<4;j++)
      acc[i][j] = (f32x4_t){0.f,0.f,0.f,0.f};

  auto STAGE = [&](int buf, int kt){
    #pragma unroll
    for (int i=0;i<2;i++){
      int c = i*256 + tid;
      gl16(Ag + (size_t)(c>>2)*K + kt + (c&3)*8, &sA[buf][c*8]);
    }
    #pragma unroll
    for (int i=0;i<2;i++){
      int c = i*256 + tid;
      gl16(Bg + (size_t)(c>>2)*K + kt + (c&3)*8, &sB[buf][c*8]);
    }
  };

  STAGE(0, 0);
  __syncthreads();
  int nk = K / GBK, cur = 0;
  int rowA = wm*64 + (lane & 15);
  int rowB = wn*64 + (lane & 15);
  int koff = (lane >> 4) * 8;
  for (int t=0; t<nk; ++t){
    if (t+1 < nk) STAGE(cur^1, (t+1)*GBK);
    bf16x8_t af[4], bfr[4];
    #pragma unroll
    for (int m=0;m<4;m++) af[m]  = *(const bf16x8_t*)&sA[cur][(rowA + m*16)*GBK + koff];
    #pragma unroll
    for (int n=0;n<4;n++) bfr[n] = *(const bf16x8_t*)&sB[cur][(rowB + n*16)*GBK + koff];
    #pragma unroll
    for (int m=0;m<4;m++)
      #pragma unroll
      for (int n=0;n<4;n++)
        acc[m][n] = __builtin_amdgcn_mfma_f32_16x16x32_bf16(af[m], bfr[n], acc[m][n], 0,0,0);
    __syncthreads();
    cur ^= 1;
  }

  int crow0 = wm*64 + (lane>>4)*4;
  int ccol0 = wn*64 + (lane & 15);
  #pragma unroll
  for (int m=0;m<4;m++)
    #pragma unroll
    for (int n=0;n<4;n++)
      #pragma unroll
      for (int r=0;r<4;r++){
        float v = acc[m][n][r];
        size_t rowg = m0 + crow0 + m*16 + r;
        size_t colg = n0 + ccol0 + n*16;
        size_t idx = rowg * (size_t)N + colg;
        if constexpr (EPI == 0){
          ((u16*)C)[idx] = f2bf(v);
        } else if constexpr (EPI == 1){
          float s = v / (1.0f + __expf(-v));
          ((u16*)C)[idx] = f2bf(s);
        } else if constexpr (EPI == 2){
          float a = bf2f(((const u16*)aux)[idx]);
          ((u16*)C)[idx] = f2bf(v * a);
        } else {
          float a = ((const float*)aux)[idx];
          float b2 = bf2f(((const u16*)aux2)[idx]);
          ((float*)C)[idx] = v + a + b2;
        }
      }
}

// ---------------- causal flash attention ----------------
// grid: b*512 + h*32 + qt ; block 256 (4 waves x 16 q-rows), K-tile 32
__global__ __launch_bounds__(256) void attn_k(const u16* __restrict__ Q,
                                              const u16* __restrict__ K,
                                              const u16* __restrict__ V,
                                              u16* __restrict__ O){
  __shared__ __align__(16) u16 sK[32*128];     // [kc 32][hd 128]
  __shared__ __align__(16) u16 sVT[128*48];    // [d 128][kc stride 48]
  __shared__ __align__(16) u16 sP[4][16*32];   // per-wave P [q 16][kc 32]
  int tid = threadIdx.x, lane = tid & 63, wave = tid >> 6;
  int bid = blockIdx.x;
  int qt = bid & 31, h = (bid >> 5) & 15, b = bid >> 9;
  int l15 = lane & 15, l4 = lane >> 4;
  size_t base = ((size_t)b*2048)*2048 + (size_t)h*128;
  int qr0 = qt*64 + wave*16;
  bf16x8_t qf[4];
  #pragma unroll
  for (int s=0;s<4;s++)
    qf[s] = *(const bf16x8_t*)(Q + base + (size_t)(qr0 + l15)*2048 + s*32 + l4*8);

  f32x4_t oacc[8];
  #pragma unroll
  for (int f=0;f<8;f++) oacc[f] = (f32x4_t){0.f,0.f,0.f,0.f};
  float mrun[4], lrun[4];
  #pragma unroll
  for (int r=0;r<4;r++){ mrun[r] = -1e30f; lrun[r] = 0.f; }

  const float scale = 0.08838834764831845f;   // 1/sqrt(128)
  int nkt = (qt + 1) * 2;
  for (int kt=0; kt<nkt; ++kt){
    __syncthreads();          // prior tile's LDS reads done
    const u16* Kg = K + base + (size_t)kt*32*2048;
    const u16* Vg = V + base + (size_t)kt*32*2048;
    #pragma unroll
    for (int i=0;i<2;i++){
      int c = i*256 + tid;    // tile chunk: row=c>>4, col8=(c&15)
      gl16(Kg + (size_t)(c>>4)*2048 + (c&15)*8, &sK[c*8]);
    }
    #pragma unroll
    for (int i=0;i<2;i++){
      int c = i*256 + tid; int vr = c>>4; int c0 = (c&15)*8;
      bf16x8_t vv = *(const bf16x8_t*)(Vg + (size_t)vr*2048 + c0);
      #pragma unroll
      for (int j=0;j<8;j++) sVT[(c0+j)*48 + vr] = (u16)vv[j];
    }
    __syncthreads();          // staged data visible (drains vmcnt+lgkm)

    f32x4_t sacc[2];
    sacc[0] = (f32x4_t){0.f,0.f,0.f,0.f};
    sacc[1] = (f32x4_t){0.f,0.f,0.f,0.f};
    #pragma unroll
    for (int n=0;n<2;n++)
      #pragma unroll
      for (int s=0;s<4;s++){
        bf16x8_t kf = *(const bf16x8_t*)&sK[(n*16 + l15)*128 + s*32 + l4*8];
        sacc[n] = __builtin_amdgcn_mfma_f32_16x16x32_bf16(qf[s], kf, sacc[n], 0,0,0);
      }

    float pv0[4], pv1[4], tmax[4];
    #pragma unroll
    for (int r=0;r<4;r++){
      int qrow = qr0 + l4*4 + r;
      int kc0 = kt*32 + l15;
      float v0 = sacc[0][r] * scale;
      float v1 = sacc[1][r] * scale;
      if (kc0      > qrow) v0 = -1e30f;
      if (kc0 + 16 > qrow) v1 = -1e30f;
      pv0[r] = v0; pv1[r] = v1;
      float mx = fmaxf(v0, v1);
      mx = fmaxf(mx, __shfl_xor(mx, 1, 64));
      mx = fmaxf(mx, __shfl_xor(mx, 2, 64));
      mx = fmaxf(mx, __shfl_xor(mx, 4, 64));
      mx = fmaxf(mx, __shfl_xor(mx, 8, 64));
      tmax[r] = mx;
    }
    #pragma unroll
    for (int r=0;r<4;r++){
      float mnew = fmaxf(mrun[r], tmax[r]);
      float fr = __expf(mrun[r] - mnew);
      mrun[r] = mnew;
      float p0 = __expf(pv0[r] - mnew);
      float p1 = __expf(pv1[r] - mnew);
      float rs = p0 + p1;
      rs += __shfl_xor(rs, 1, 64);
      rs += __shfl_xor(rs, 2, 64);
      rs += __shfl_xor(rs, 4, 64);
      rs += __shfl_xor(rs, 8, 64);
      lrun[r] = lrun[r]*fr + rs;
      #pragma unroll
      for (int f=0;f<8;f++) oacc[f][r] *= fr;
      sP[wave][(l4*4+r)*32 + l15]      = f2bf(p0);
      sP[wave][(l4*4+r)*32 + 16 + l15] = f2bf(p1);
    }
    bf16x8_t pa = *(const bf16x8_t*)&sP[wave][l15*32 + l4*8];
    #pragma unroll
    for (int f=0;f<8;f++){
      bf16x8_t vbf = *(const bf16x8_t*)&sVT[(f*16 + l15)*48 + l4*8];
      oacc[f] = __builtin_amdgcn_mfma_f32_16x16x32_bf16(pa, vbf, oacc[f], 0,0,0);
    }
  }
  #pragma unroll
  for (int r=0;r<4;r++){
    float inv = 1.0f / lrun[r];
    size_t rowg = (size_t)b*2048 + qr0 + l4*4 + r;
    #pragma unroll
    for (int f=0;f<8;f++)
      O[rowg*2048 + h*128 + f*16 + l15] = f2bf(oacc[f][r] * inv);
  }
}

// ---------------- host ----------------
extern "C" void kernel_launch(void* const* d_in, const int* in_sizes, int n_in,
                              void* d_out, int out_size, void* d_ws, size_t ws_size,
                              hipStream_t stream){
  (void)in_sizes; (void)n_in; (void)out_size; (void)ws_size;
  const float* x   = (const float*)d_in[0];
  const float* fc  = (const float*)d_in[1];
  const float* fs  = (const float*)d_in[2];
  const float* wq  = (const float*)d_in[4];
  const float* wk  = (const float*)d_in[5];
  const float* wv  = (const float*)d_in[6];
  const float* wo  = (const float*)d_in[7];
  const float* w1  = (const float*)d_in[8];
  const float* w2  = (const float*)d_in[9];
  const float* w3  = (const float*)d_in[10];
  const float* anw = (const float*)d_in[11];
  const float* fnw = (const float*)d_in[12];
  float* out = (float*)d_out;
  char* ws = (char*)d_ws;

  const int M = 8192, D = 2048, HID = 5632;
  const size_t WB   = 23068672ull;   // 5632*2048*2 (reused weight buf)
  const size_t ACT2 = 33554432ull;   // 8192*2048*2

  // ws layout (total ~238 MiB):
  u16* wbuf = (u16*)(ws);
  u16* xa   = (u16*)(ws + WB);                // rmsnorm(x); later attn O
  u16* qb   = (u16*)(ws + WB + ACT2);         // Q; later t1 = o@wo^T
  u16* kb   = (u16*)(ws + WB + 2*ACT2);       // K; later hf
  u16* vb   = (u16*)(ws + WB + 3*ACT2);       // V
  u16* g1   = (u16*)(ws + WB + 4*ACT2);       // 8192x5632 bf16 (88 MiB)
  u16* t1 = qb;
  u16* hf = kb;

  rmsnorm_k<<<M, 256, 0, stream>>>(x, anw, xa);

  cvt_k<<<D*D/8/256, 256, 0, stream>>>(wq, wbuf, D*D/8);
  gemm_bt<0><<<(M/128)*(D/128), 256, 0, stream>>>(xa, wbuf, qb, nullptr, nullptr, M, D, D);
  cvt_k<<<D*D/8/256, 256, 0, stream>>>(wk, wbuf, D*D/8);
  gemm_bt<0><<<(M/128)*(D/128), 256, 0, stream>>>(xa, wbuf, kb, nullptr, nullptr, M, D, D);
  cvt_k<<<D*D/8/256, 256, 0, stream>>>(wv, wbuf, D*D/8);
  gemm_bt<0><<<(M/128)*(D/128), 256, 0, stream>>>(xa, wbuf, vb, nullptr, nullptr, M, D, D);

  rope_k<<<32768, 256, 0, stream>>>(qb, kb, fc, fs);

  attn_k<<<2048, 256, 0, stream>>>(qb, kb, vb, xa);   // O -> xa

  cvt_k<<<D*D/8/256, 256, 0, stream>>>(wo, wbuf, D*D/8);
  gemm_bt<0><<<(M/128)*(D/128), 256, 0, stream>>>(xa, wbuf, t1, nullptr, nullptr, M, D, D);

  rmsnorm2_k<<<M, 256, 0, stream>>>(x, t1, fnw, hf);

  cvt_k<<<HID*D/8/256, 256, 0, stream>>>(w1, wbuf, HID*D/8);
  gemm_bt<1><<<(M/128)*(HID/128), 256, 0, stream>>>(hf, wbuf, g1, nullptr, nullptr, M, HID, D);
  cvt_k<<<HID*D/8/256, 256, 0, stream>>>(w3, wbuf, HID*D/8);
  gemm_bt<2><<<(M/128)*(HID/128), 256, 0, stream>>>(hf, wbuf, g1, g1, nullptr, M, HID, D);
  cvt_k<<<HID*D/8/256, 256, 0, stream>>>(w2, wbuf, HID*D/8);
  gemm_bt<4><<<(M/128)*(D/128), 256, 0, stream>>>(g1, wbuf, out, x, t1, M, D, HID);
}

// Round 4
// 1613.472 us; speedup vs baseline: 1.4190x; 1.4190x over previous
//
#include <hip/hip_runtime.h>
#include <hip/hip_bf16.h>
#include <stdint.h>

typedef short  bf16x8_t __attribute__((ext_vector_type(8)));
typedef short  bf16x4_t __attribute__((ext_vector_type(4)));
typedef float  f32x4_t  __attribute__((ext_vector_type(4)));
typedef unsigned short u16;
typedef unsigned int   u32;

#define DEV __device__ __forceinline__

DEV u16 f2bf(float f){
  u32 u = __float_as_uint(f);
  u += 0x7fffu + ((u >> 16) & 1u);     // RNE
  return (u16)(u >> 16);
}
DEV float bf2f(u16 h){ return __uint_as_float(((u32)h) << 16); }

DEV void gl16(const void* g, void* l){
  __builtin_amdgcn_global_load_lds(
      (const __attribute__((address_space(1))) void*)g,
      (__attribute__((address_space(3))) void*)l, 16, 0, 0);
}

// ---------------- f32 -> bf16 convert (8 elems/thread) ----------------
__global__ __launch_bounds__(256) void cvt_k(const float* __restrict__ in,
                                             u16* __restrict__ out, int n8){
  int i = blockIdx.x * 256 + threadIdx.x;
  if (i >= n8) return;
  const float4* p = (const float4*)in;
  float4 a = p[(size_t)i*2], b = p[(size_t)i*2+1];
  bf16x8_t o;
  o[0]=(short)f2bf(a.x); o[1]=(short)f2bf(a.y); o[2]=(short)f2bf(a.z); o[3]=(short)f2bf(a.w);
  o[4]=(short)f2bf(b.x); o[5]=(short)f2bf(b.y); o[6]=(short)f2bf(b.z); o[7]=(short)f2bf(b.w);
  *(bf16x8_t*)(out + (size_t)i*8) = o;
}

// ---------------- RMSNorm: fp32 row (D=2048) -> bf16 ----------------
__global__ __launch_bounds__(256) void rmsnorm_k(const float* __restrict__ x,
                                                 const float* __restrict__ w,
                                                 u16* __restrict__ y){
  int row = blockIdx.x, t = threadIdx.x;
  const float4* xr = (const float4*)(x + (size_t)row*2048);
  float4 a = xr[t*2], b = xr[t*2+1];
  float ss = a.x*a.x+a.y*a.y+a.z*a.z+a.w*a.w + b.x*b.x+b.y*b.y+b.z*b.z+b.w*b.w;
  #pragma unroll
  for (int m = 32; m; m >>= 1) ss += __shfl_xor(ss, m, 64);
  __shared__ float red[4];
  if ((t & 63) == 0) red[t >> 6] = ss;
  __syncthreads();
  float tot = red[0]+red[1]+red[2]+red[3];
  float rs = rsqrtf(tot * (1.0f/2048.0f) + 1e-6f);
  const float4* wr = (const float4*)w;
  float4 wa = wr[t*2], wb = wr[t*2+1];
  bf16x8_t o;
  o[0]=(short)f2bf(a.x*rs*wa.x); o[1]=(short)f2bf(a.y*rs*wa.y);
  o[2]=(short)f2bf(a.z*rs*wa.z); o[3]=(short)f2bf(a.w*rs*wa.w);
  o[4]=(short)f2bf(b.x*rs*wb.x); o[5]=(short)f2bf(b.y*rs*wb.y);
  o[6]=(short)f2bf(b.z*rs*wb.z); o[7]=(short)f2bf(b.w*rs*wb.w);
  *(bf16x8_t*)(y + (size_t)row*2048 + t*8) = o;
}

// ---- RMSNorm2: h = x(f32) + t1(bf16); y = rmsnorm(h)*w -> bf16 ----
__global__ __launch_bounds__(256) void rmsnorm2_k(const float* __restrict__ x,
                                                  const u16* __restrict__ t1,
                                                  const float* __restrict__ w,
                                                  u16* __restrict__ y){
  int row = blockIdx.x, t = threadIdx.x;
  const float4* xr = (const float4*)(x + (size_t)row*2048);
  float4 a = xr[t*2], b = xr[t*2+1];
  bf16x8_t tv = *(const bf16x8_t*)(t1 + (size_t)row*2048 + t*8);
  float h[8];
  h[0]=a.x+bf2f((u16)tv[0]); h[1]=a.y+bf2f((u16)tv[1]);
  h[2]=a.z+bf2f((u16)tv[2]); h[3]=a.w+bf2f((u16)tv[3]);
  h[4]=b.x+bf2f((u16)tv[4]); h[5]=b.y+bf2f((u16)tv[5]);
  h[6]=b.z+bf2f((u16)tv[6]); h[7]=b.w+bf2f((u16)tv[7]);
  float ss = 0.f;
  #pragma unroll
  for (int j=0;j<8;j++) ss += h[j]*h[j];
  #pragma unroll
  for (int m = 32; m; m >>= 1) ss += __shfl_xor(ss, m, 64);
  __shared__ float red[4];
  if ((t & 63) == 0) red[t >> 6] = ss;
  __syncthreads();
  float tot = red[0]+red[1]+red[2]+red[3];
  float rs = rsqrtf(tot * (1.0f/2048.0f) + 1e-6f);
  const float4* wr = (const float4*)w;
  float4 wa = wr[t*2], wb = wr[t*2+1];
  bf16x8_t o;
  o[0]=(short)f2bf(h[0]*rs*wa.x); o[1]=(short)f2bf(h[1]*rs*wa.y);
  o[2]=(short)f2bf(h[2]*rs*wa.z); o[3]=(short)f2bf(h[3]*rs*wa.w);
  o[4]=(short)f2bf(h[4]*rs*wb.x); o[5]=(short)f2bf(h[5]*rs*wb.y);
  o[6]=(short)f2bf(h[6]*rs*wb.z); o[7]=(short)f2bf(h[7]*rs*wb.w);
  *(bf16x8_t*)(y + (size_t)row*2048 + t*8) = o;
}

// ---------------- RoPE in-place on q,k (bf16, B,S,H,HD) ----------------
__global__ __launch_bounds__(256) void rope_k(u16* __restrict__ q, u16* __restrict__ k,
                                              const float* __restrict__ fc,
                                              const float* __restrict__ fs){
  int i = blockIdx.x * 256 + threadIdx.x;
  int ii = i & 63; int h = (i >> 6) & 15; int bs = i >> 10;
  int s = bs & 2047;
  size_t off = (size_t)bs*2048 + h*128 + 2*ii;
  float c = fc[s*64+ii], sn = fs[s*64+ii];
  u32 qq = *(u32*)(q + off);
  float xr = bf2f((u16)(qq & 0xffff)), xi = bf2f((u16)(qq >> 16));
  *(u32*)(q + off) = (u32)f2bf(xr*c - xi*sn) | ((u32)f2bf(xr*sn + xi*c) << 16);
  u32 kk = *(u32*)(k + off);
  xr = bf2f((u16)(kk & 0xffff)); xi = bf2f((u16)(kk >> 16));
  *(u32*)(k + off) = (u32)f2bf(xr*c - xi*sn) | ((u32)f2bf(xr*sn + xi*c) << 16);
}

// ---------------- 2048x8192 transpose (V -> V^T), 64x64 tiles ----------------
__global__ __launch_bounds__(256) void transpose_k(const u16* __restrict__ in,
                                                   u16* __restrict__ out){
  __shared__ u16 tile[64*68];
  int tid = threadIdx.x;
  int tm = blockIdx.x >> 5, tn = blockIdx.x & 31;   // in: [8192][2048]
  const u16* src = in + (size_t)(tm*64)*2048 + tn*64;
  #pragma unroll
  for (int i=0;i<2;i++){
    int idx = i*256 + tid;
    int r = idx >> 3, c8 = (idx & 7)*8;
    *(bf16x8_t*)&tile[r*68 + c8] = *(const bf16x8_t*)(src + (size_t)r*2048 + c8);
  }
  __syncthreads();
  u16* dst = out + (size_t)(tn*64)*8192 + tm*64;
  #pragma unroll
  for (int i=0;i<2;i++){
    int idx = i*256 + tid;
    int oc = idx >> 3, r8 = (idx & 7)*8;
    bf16x8_t v;
    #pragma unroll
    for (int j=0;j<8;j++) v[j] = tile[(r8+j)*68 + oc];
    *(bf16x8_t*)(dst + (size_t)oc*8192 + r8) = v;
  }
}

// ---------------- GEMM: C(MxN) = A(MxK,bf16) * B(NxK,bf16)^T (+epilogue) ----
#define GBM 128
#define GBN 128
#define GBK 32

template<int EPI>
__global__ __launch_bounds__(256) void gemm_bt(const u16* __restrict__ A,
                                               const u16* __restrict__ B,
                                               void* __restrict__ C,
                                               const void* __restrict__ aux,
                                               const void* __restrict__ aux2,
                                               int M, int N, int K){
  __shared__ __align__(16) u16 sA[2][GBM*GBK];
  __shared__ __align__(16) u16 sB[2][GBN*GBK];
  int tid = threadIdx.x, lane = tid & 63, wave = tid >> 6;
  int nbn = N / GBN;
  int nwg = gridDim.x, bid = blockIdx.x;
  int qq = nwg >> 3, rr = nwg & 7;
  int xc = bid & 7, yy = bid >> 3;
  int wg = (xc < rr ? xc*(qq+1) : rr*(qq+1) + (xc-rr)*qq) + yy;
  int tm = wg / nbn, tn = wg % nbn;
  size_t m0 = (size_t)tm * GBM, n0 = (size_t)tn * GBN;
  const u16* Ag = A + m0 * K;
  const u16* Bg = B + n0 * K;
  int wm = wave >> 1, wn = wave & 1;

  f32x4_t acc[4][4];
  #pragma unroll
  for (int i=0;i<4;i++)
    #pragma unroll
    for (int j=0;j<4;j++)
      acc[i][j] = (f32x4_t){0.f,0.f,0.f,0.f};

  auto STAGE = [&](int buf, int kt){
    #pragma unroll
    for (int i=0;i<2;i++){
      int c = i*256 + tid;
      gl16(Ag + (size_t)(c>>2)*K + kt + (c&3)*8, &sA[buf][c*8]);
    }
    #pragma unroll
    for (int i=0;i<2;i++){
      int c = i*256 + tid;
      gl16(Bg + (size_t)(c>>2)*K + kt + (c&3)*8, &sB[buf][c*8]);
    }
  };

  STAGE(0, 0);
  __syncthreads();
  int nk = K / GBK, cur = 0;
  int rowA = wm*64 + (lane & 15);
  int rowB = wn*64 + (lane & 15);
  int koff = (lane >> 4) * 8;
  for (int t=0; t<nk; ++t){
    if (t+1 < nk) STAGE(cur^1, (t+1)*GBK);
    bf16x8_t af[4], bfr[4];
    #pragma unroll
    for (int m=0;m<4;m++) af[m]  = *(const bf16x8_t*)&sA[cur][(rowA + m*16)*GBK + koff];
    #pragma unroll
    for (int n=0;n<4;n++) bfr[n] = *(const bf16x8_t*)&sB[cur][(rowB + n*16)*GBK + koff];
    #pragma unroll
    for (int m=0;m<4;m++)
      #pragma unroll
      for (int n=0;n<4;n++)
        acc[m][n] = __builtin_amdgcn_mfma_f32_16x16x32_bf16(af[m], bfr[n], acc[m][n], 0,0,0);
    __syncthreads();
    cur ^= 1;
  }

  int crow0 = wm*64 + (lane>>4)*4;
  int ccol0 = wn*64 + (lane & 15);
  #pragma unroll
  for (int m=0;m<4;m++)
    #pragma unroll
    for (int n=0;n<4;n++)
      #pragma unroll
      for (int r=0;r<4;r++){
        float v = acc[m][n][r];
        size_t rowg = m0 + crow0 + m*16 + r;
        size_t colg = n0 + ccol0 + n*16;
        size_t idx = rowg * (size_t)N + colg;
        if constexpr (EPI == 0){
          ((u16*)C)[idx] = f2bf(v);
        } else if constexpr (EPI == 1){
          float s = v / (1.0f + __expf(-v));
          ((u16*)C)[idx] = f2bf(s);
        } else if constexpr (EPI == 2){
          float a = bf2f(((const u16*)aux)[idx]);
          ((u16*)C)[idx] = f2bf(v * a);
        } else {
          float a = ((const float*)aux)[idx];
          float b2 = bf2f(((const u16*)aux2)[idx]);
          ((float*)C)[idx] = v + a + b2;
        }
      }
}

// ---------------- causal flash attention (swapped QK^T, V^T input) ----------
// grid: b*512 + h*32 + qt ; block 256 (4 waves x 16 q-rows), K-tile 32
// sK  [32 k][128 d], 16B chunks XOR-swizzled by (row&7) via global source
// sVT [128 d][32 k], 16B chunks XOR-swizzled by ((d>>1)&3) via global source
__global__ __launch_bounds__(256) void attn_k(const u16* __restrict__ Q,
                                              const u16* __restrict__ K,
                                              const u16* __restrict__ VT,
                                              u16* __restrict__ O){
  __shared__ __align__(16) u16 sK[32*128];
  __shared__ __align__(16) u16 sVT[128*32];
  int tid = threadIdx.x, lane = tid & 63, wave = tid >> 6;
  int bid = blockIdx.x;
  int qt = bid & 31, h = (bid >> 5) & 15, b = bid >> 9;
  int l15 = lane & 15, l4 = lane >> 4;
  size_t base = ((size_t)b*2048)*2048 + (size_t)h*128;
  const u16* VTg0 = VT + ((size_t)h*128)*8192 + (size_t)b*2048;
  int qr0 = qt*64 + wave*16;
  int qrow = qr0 + l15;                       // this lane's single q row
  bf16x8_t qf[4];
  #pragma unroll
  for (int s=0;s<4;s++)
    qf[s] = *(const bf16x8_t*)(Q + base + (size_t)qrow*2048 + s*32 + l4*8);

  f32x4_t oaccT[8];                           // O^T: d = f*16 + l4*4 + r, q = l15
  #pragma unroll
  for (int f=0;f<8;f++) oaccT[f] = (f32x4_t){0.f,0.f,0.f,0.f};
  float mrun = -1e30f, lrun = 0.f;

  const float scale = 0.08838834764831845f;   // 1/sqrt(128)
  int nkt = (qt + 1) * 2;
  for (int kt=0; kt<nkt; ++kt){
    __syncthreads();          // prior tile's LDS reads done
    const u16* Kg = K + base + (size_t)kt*32*2048;
    // stage K: 512 chunks of 16B; dest chunk c (byte c*16) -> row c>>4, phys chunk c&15
    // content = logical chunk (c&15)^(row&7)
    #pragma unroll
    for (int i=0;i<2;i++){
      int c = i*256 + tid; int row = c>>4;
      gl16(Kg + (size_t)row*2048 + (size_t)(((c&15) ^ (row&7))*8), &sK[c*8]);
    }
    // stage V^T: 512 chunks; dest chunk c (byte c*16) -> d = c>>2, phys chunk c&3
    // content = logical chunk (c&3)^((d>>1)&3); global row d, tokens kt*32..
    #pragma unroll
    for (int i=0;i<2;i++){
      int c = i*256 + tid; int d = c>>2;
      gl16(VTg0 + (size_t)d*8192 + kt*32 + (size_t)((((c&3) ^ ((d>>1)&3)))*8),
           &sVT[c*8]);
    }
    __syncthreads();          // drains vmcnt before barrier

    if (kt*32 <= qr0 + 15){   // wave-uniform skip of fully-masked tiles
      // QK^T swapped: sacc[n] = S^T, rows k = n*16+l4*4+r, col q = l15
      f32x4_t sacc[2];
      sacc[0] = (f32x4_t){0.f,0.f,0.f,0.f};
      sacc[1] = (f32x4_t){0.f,0.f,0.f,0.f};
      #pragma unroll
      for (int n=0;n<2;n++)
        #pragma unroll
        for (int s=0;s<4;s++){
          bf16x8_t kf = *(const bf16x8_t*)
              &sK[(n*16 + l15)*128 + (((s*4 + l4) ^ (l15 & 7))*8)];
          sacc[n] = __builtin_amdgcn_mfma_f32_16x16x32_bf16(kf, qf[s], sacc[n], 0,0,0);
        }
      // mask + softmax (per-lane single q)
      float pv[8];
      float mloc = -1e30f;
      #pragma unroll
      for (int n=0;n<2;n++)
        #pragma unroll
        for (int r=0;r<4;r++){
          int kg = kt*32 + n*16 + l4*4 + r;
          float v = sacc[n][r] * scale;
          if (kg > qrow) v = -1e30f;
          pv[n*4+r] = v;
          mloc = fmaxf(mloc, v);
        }
      mloc = fmaxf(mloc, __shfl_xor(mloc, 16, 64));
      mloc = fmaxf(mloc, __shfl_xor(mloc, 32, 64));
      float mnew = fmaxf(mrun, mloc);
      float fr = __expf(mrun - mnew);
      mrun = mnew;
      float sloc = 0.f;
      bf16x8_t pa;
      #pragma unroll
      for (int j=0;j<8;j++){
        float p = __expf(pv[j] - mnew);
        sloc += p;
        pa[j] = (short)f2bf(p);
      }
      sloc += __shfl_xor(sloc, 16, 64);
      sloc += __shfl_xor(sloc, 32, 64);
      lrun = lrun * fr + sloc;
      #pragma unroll
      for (int f=0;f<8;f++){
        oaccT[f][0] *= fr; oaccT[f][1] *= fr; oaccT[f][2] *= fr; oaccT[f][3] *= fr;
      }
      // PV: O^T = mfma(A=V^T, B=P^T); slot j -> logical k = (j>>2)*16 + l4*4 + (j&3)
      #pragma unroll
      for (int f=0;f<8;f++){
        int d = f*16 + l15;
        bf16x4_t lo = *(const bf16x4_t*)&sVT[d*32 + (((0*4 + l4) ^ (d & 6))*4)];
        bf16x4_t hi = *(const bf16x4_t*)&sVT[d*32 + (((1*4 + l4) ^ (d & 6))*4)];
        bf16x8_t va;
        va[0]=lo[0]; va[1]=lo[1]; va[2]=lo[2]; va[3]=lo[3];
        va[4]=hi[0]; va[5]=hi[1]; va[6]=hi[2]; va[7]=hi[3];
        oaccT[f] = __builtin_amdgcn_mfma_f32_16x16x32_bf16(va, pa, oaccT[f], 0,0,0);
      }
    }
  }
  float inv = 1.0f / lrun;
  size_t orow = (size_t)b*2048 + qrow;
  #pragma unroll
  for (int f=0;f<8;f++){
    bf16x4_t ov;
    ov[0]=(short)f2bf(oaccT[f][0]*inv); ov[1]=(short)f2bf(oaccT[f][1]*inv);
    ov[2]=(short)f2bf(oaccT[f][2]*inv); ov[3]=(short)f2bf(oaccT[f][3]*inv);
    *(bf16x4_t*)(O + orow*2048 + h*128 + f*16 + l4*4) = ov;
  }
}

// ---------------- host ----------------
extern "C" void kernel_launch(void* const* d_in, const int* in_sizes, int n_in,
                              void* d_out, int out_size, void* d_ws, size_t ws_size,
                              hipStream_t stream){
  (void)in_sizes; (void)n_in; (void)out_size; (void)ws_size;
  const float* x   = (const float*)d_in[0];
  const float* fc  = (const float*)d_in[1];
  const float* fs  = (const float*)d_in[2];
  const float* wq  = (const float*)d_in[4];
  const float* wk  = (const float*)d_in[5];
  const float* wv  = (const float*)d_in[6];
  const float* wo  = (const float*)d_in[7];
  const float* w1  = (const float*)d_in[8];
  const float* w2  = (const float*)d_in[9];
  const float* w3  = (const float*)d_in[10];
  const float* anw = (const float*)d_in[11];
  const float* fnw = (const float*)d_in[12];
  float* out = (float*)d_out;
  char* ws = (char*)d_ws;

  const int M = 8192, D = 2048, HID = 5632;
  const size_t WB   = 23068672ull;   // 5632*2048*2 (reused weight buf)
  const size_t ACT2 = 33554432ull;   // 8192*2048*2

  u16* wbuf = (u16*)(ws);
  u16* xa   = (u16*)(ws + WB);                // rmsnorm(x); later attn O
  u16* qb   = (u16*)(ws + WB + ACT2);         // Q; later t1 = o@wo^T
  u16* kb   = (u16*)(ws + WB + 2*ACT2);       // K; later hf
  u16* vb   = (u16*)(ws + WB + 3*ACT2);       // V
  u16* g1   = (u16*)(ws + WB + 4*ACT2);       // VT (32MB) then g1 (88 MiB)
  u16* vt = g1;
  u16* t1 = qb;
  u16* hf = kb;

  rmsnorm_k<<<M, 256, 0, stream>>>(x, anw, xa);

  cvt_k<<<D*D/8/256, 256, 0, stream>>>(wq, wbuf, D*D/8);
  gemm_bt<0><<<(M/128)*(D/128), 256, 0, stream>>>(xa, wbuf, qb, nullptr, nullptr, M, D, D);
  cvt_k<<<D*D/8/256, 256, 0, stream>>>(wk, wbuf, D*D/8);
  gemm_bt<0><<<(M/128)*(D/128), 256, 0, stream>>>(xa, wbuf, kb, nullptr, nullptr, M, D, D);
  cvt_k<<<D*D/8/256, 256, 0, stream>>>(wv, wbuf, D*D/8);
  gemm_bt<0><<<(M/128)*(D/128), 256, 0, stream>>>(xa, wbuf, vb, nullptr, nullptr, M, D, D);

  rope_k<<<32768, 256, 0, stream>>>(qb, kb, fc, fs);
  transpose_k<<<4096, 256, 0, stream>>>(vb, vt);      // V[8192][2048] -> VT[2048][8192]

  attn_k<<<2048, 256, 0, stream>>>(qb, kb, vt, xa);   // O -> xa

  cvt_k<<<D*D/8/256, 256, 0, stream>>>(wo, wbuf, D*D/8);
  gemm_bt<0><<<(M/128)*(D/128), 256, 0, stream>>>(xa, wbuf, t1, nullptr, nullptr, M, D, D);

  rmsnorm2_k<<<M, 256, 0, stream>>>(x, t1, fnw, hf);

  cvt_k<<<HID*D/8/256, 256, 0, stream>>>(w1, wbuf, HID*D/8);
  gemm_bt<1><<<(M/128)*(HID/128), 256, 0, stream>>>(hf, wbuf, g1, nullptr, nullptr, M, HID, D);
  cvt_k<<<HID*D/8/256, 256, 0, stream>>>(w3, wbuf, HID*D/8);
  gemm_bt<2><<<(M/128)*(HID/128), 256, 0, stream>>>(hf, wbuf, g1, g1, nullptr, M, HID, D);
  cvt_k<<<HID*D/8/256, 256, 0, stream>>>(w2, wbuf, HID*D/8);
  gemm_bt<4><<<(M/128)*(D/128), 256, 0, stream>>>(g1, wbuf, out, x, t1, M, D, HID);
}

// Round 5
// 1476.696 us; speedup vs baseline: 1.5505x; 1.0926x over previous
//
#include <hip/hip_runtime.h>
#include <hip/hip_bf16.h>
#include <stdint.h>

typedef short  bf16x8_t __attribute__((ext_vector_type(8)));
typedef short  bf16x4_t __attribute__((ext_vector_type(4)));
typedef float  f32x4_t  __attribute__((ext_vector_type(4)));
typedef unsigned short u16;
typedef unsigned int   u32;

#define DEV __device__ __forceinline__

DEV u16 f2bf(float f){
  u32 u = __float_as_uint(f);
  u += 0x7fffu + ((u >> 16) & 1u);     // RNE
  return (u16)(u >> 16);
}
DEV float bf2f(u16 h){ return __uint_as_float(((u32)h) << 16); }

DEV void gl16(const void* g, void* l){
  __builtin_amdgcn_global_load_lds(
      (const __attribute__((address_space(1))) void*)g,
      (__attribute__((address_space(3))) void*)l, 16, 0, 0);
}

// ---------------- f32 -> bf16 convert (8 elems/thread) ----------------
__global__ __launch_bounds__(256) void cvt_k(const float* __restrict__ in,
                                             u16* __restrict__ out, int n8){
  int i = blockIdx.x * 256 + threadIdx.x;
  if (i >= n8) return;
  const float4* p = (const float4*)in;
  float4 a = p[(size_t)i*2], b = p[(size_t)i*2+1];
  bf16x8_t o;
  o[0]=(short)f2bf(a.x); o[1]=(short)f2bf(a.y); o[2]=(short)f2bf(a.z); o[3]=(short)f2bf(a.w);
  o[4]=(short)f2bf(b.x); o[5]=(short)f2bf(b.y); o[6]=(short)f2bf(b.z); o[7]=(short)f2bf(b.w);
  *(bf16x8_t*)(out + (size_t)i*8) = o;
}

// ---------------- RMSNorm: fp32 row (D=2048) -> bf16 ----------------
__global__ __launch_bounds__(256) void rmsnorm_k(const float* __restrict__ x,
                                                 const float* __restrict__ w,
                                                 u16* __restrict__ y){
  int row = blockIdx.x, t = threadIdx.x;
  const float4* xr = (const float4*)(x + (size_t)row*2048);
  float4 a = xr[t*2], b = xr[t*2+1];
  float ss = a.x*a.x+a.y*a.y+a.z*a.z+a.w*a.w + b.x*b.x+b.y*b.y+b.z*b.z+b.w*b.w;
  #pragma unroll
  for (int m = 32; m; m >>= 1) ss += __shfl_xor(ss, m, 64);
  __shared__ float red[4];
  if ((t & 63) == 0) red[t >> 6] = ss;
  __syncthreads();
  float tot = red[0]+red[1]+red[2]+red[3];
  float rs = rsqrtf(tot * (1.0f/2048.0f) + 1e-6f);
  const float4* wr = (const float4*)w;
  float4 wa = wr[t*2], wb = wr[t*2+1];
  bf16x8_t o;
  o[0]=(short)f2bf(a.x*rs*wa.x); o[1]=(short)f2bf(a.y*rs*wa.y);
  o[2]=(short)f2bf(a.z*rs*wa.z); o[3]=(short)f2bf(a.w*rs*wa.w);
  o[4]=(short)f2bf(b.x*rs*wb.x); o[5]=(short)f2bf(b.y*rs*wb.y);
  o[6]=(short)f2bf(b.z*rs*wb.z); o[7]=(short)f2bf(b.w*rs*wb.w);
  *(bf16x8_t*)(y + (size_t)row*2048 + t*8) = o;
}

// ---- RMSNorm2: h = x(f32) + t1(bf16); y = rmsnorm(h)*w -> bf16 ----
__global__ __launch_bounds__(256) void rmsnorm2_k(const float* __restrict__ x,
                                                  const u16* __restrict__ t1,
                                                  const float* __restrict__ w,
                                                  u16* __restrict__ y){
  int row = blockIdx.x, t = threadIdx.x;
  const float4* xr = (const float4*)(x + (size_t)row*2048);
  float4 a = xr[t*2], b = xr[t*2+1];
  bf16x8_t tv = *(const bf16x8_t*)(t1 + (size_t)row*2048 + t*8);
  float h[8];
  h[0]=a.x+bf2f((u16)tv[0]); h[1]=a.y+bf2f((u16)tv[1]);
  h[2]=a.z+bf2f((u16)tv[2]); h[3]=a.w+bf2f((u16)tv[3]);
  h[4]=b.x+bf2f((u16)tv[4]); h[5]=b.y+bf2f((u16)tv[5]);
  h[6]=b.z+bf2f((u16)tv[6]); h[7]=b.w+bf2f((u16)tv[7]);
  float ss = 0.f;
  #pragma unroll
  for (int j=0;j<8;j++) ss += h[j]*h[j];
  #pragma unroll
  for (int m = 32; m; m >>= 1) ss += __shfl_xor(ss, m, 64);
  __shared__ float red[4];
  if ((t & 63) == 0) red[t >> 6] = ss;
  __syncthreads();
  float tot = red[0]+red[1]+red[2]+red[3];
  float rs = rsqrtf(tot * (1.0f/2048.0f) + 1e-6f);
  const float4* wr = (const float4*)w;
  float4 wa = wr[t*2], wb = wr[t*2+1];
  bf16x8_t o;
  o[0]=(short)f2bf(h[0]*rs*wa.x); o[1]=(short)f2bf(h[1]*rs*wa.y);
  o[2]=(short)f2bf(h[2]*rs*wa.z); o[3]=(short)f2bf(h[3]*rs*wa.w);
  o[4]=(short)f2bf(h[4]*rs*wb.x); o[5]=(short)f2bf(h[5]*rs*wb.y);
  o[6]=(short)f2bf(h[6]*rs*wb.z); o[7]=(short)f2bf(h[7]*rs*wb.w);
  *(bf16x8_t*)(y + (size_t)row*2048 + t*8) = o;
}

// ---------------- RoPE in-place on q,k (bf16, B,S,H,HD) ----------------
__global__ __launch_bounds__(256) void rope_k(u16* __restrict__ q, u16* __restrict__ k,
                                              const float* __restrict__ fc,
                                              const float* __restrict__ fs){
  int i = blockIdx.x * 256 + threadIdx.x;
  int ii = i & 63; int h = (i >> 6) & 15; int bs = i >> 10;
  int s = bs & 2047;
  size_t off = (size_t)bs*2048 + h*128 + 2*ii;
  float c = fc[s*64+ii], sn = fs[s*64+ii];
  u32 qq = *(u32*)(q + off);
  float xr = bf2f((u16)(qq & 0xffff)), xi = bf2f((u16)(qq >> 16));
  *(u32*)(q + off) = (u32)f2bf(xr*c - xi*sn) | ((u32)f2bf(xr*sn + xi*c) << 16);
  u32 kk = *(u32*)(k + off);
  xr = bf2f((u16)(kk & 0xffff)); xi = bf2f((u16)(kk >> 16));
  *(u32*)(k + off) = (u32)f2bf(xr*c - xi*sn) | ((u32)f2bf(xr*sn + xi*c) << 16);
}

// ---------------- 2048x8192 transpose (V -> V^T), 64x64 tiles ----------------
__global__ __launch_bounds__(256) void transpose_k(const u16* __restrict__ in,
                                                   u16* __restrict__ out){
  __shared__ u16 tile[64*68];
  int tid = threadIdx.x;
  int tm = blockIdx.x >> 5, tn = blockIdx.x & 31;   // in: [8192][2048]
  const u16* src = in + (size_t)(tm*64)*2048 + tn*64;
  #pragma unroll
  for (int i=0;i<2;i++){
    int idx = i*256 + tid;
    int r = idx >> 3, c8 = (idx & 7)*8;
    *(bf16x8_t*)&tile[r*68 + c8] = *(const bf16x8_t*)(src + (size_t)r*2048 + c8);
  }
  __syncthreads();
  u16* dst = out + (size_t)(tn*64)*8192 + tm*64;
  #pragma unroll
  for (int i=0;i<2;i++){
    int idx = i*256 + tid;
    int oc = idx >> 3, r8 = (idx & 7)*8;
    bf16x8_t v;
    #pragma unroll
    for (int j=0;j<8;j++) v[j] = tile[(r8+j)*68 + oc];
    *(bf16x8_t*)(dst + (size_t)oc*8192 + r8) = v;
  }
}

// ---------------- GEMM: C(MxN) = A(MxK,bf16) * B(NxK,bf16)^T (+epilogue) ----
// 256x128 tile, BK=64, 8 waves (4m x 2n, 64x64 each), triple-buffer LDS,
// counted vmcnt(6) pipeline (prefetch-2), (row&7) XOR chunk swizzle.
#define TBM 256
#define TBN 128
#define TBK 64

template<int EPI>
__global__ __launch_bounds__(512) void gemm_bt(const u16* __restrict__ A,
                                               const u16* __restrict__ B,
                                               void* __restrict__ C,
                                               const void* __restrict__ aux,
                                               const void* __restrict__ aux2,
                                               int M, int N, int K){
  __shared__ __align__(16) u16 sA[3][TBM*TBK];   // 3 x 32 KB
  __shared__ __align__(16) u16 sB[3][TBN*TBK];   // 3 x 16 KB
  int tid = threadIdx.x, lane = tid & 63, wave = tid >> 6;
  int l15 = lane & 15, l4 = lane >> 4;
  int nbn = N / TBN;
  int nwg = gridDim.x, bid = blockIdx.x;
  // bijective XCD swizzle (m204); all grids here are %8==0
  int qq = nwg >> 3, rr = nwg & 7;
  int xc = bid & 7, yy = bid >> 3;
  int wg = (xc < rr ? xc*(qq+1) : rr*(qq+1) + (xc-rr)*qq) + yy;
  int tm = wg / nbn, tn = wg % nbn;
  size_t m0 = (size_t)tm * TBM, n0 = (size_t)tn * TBN;
  const u16* Ag = A + m0 * K;
  const u16* Bg = B + n0 * K;
  int wm = wave >> 1, wn = wave & 1;     // 4 x 2 wave grid

  f32x4_t acc[4][4];
  #pragma unroll
  for (int i=0;i<4;i++)
    #pragma unroll
    for (int j=0;j<4;j++)
      acc[i][j] = (f32x4_t){0.f,0.f,0.f,0.f};

  // stage one K-tile: A 2048 chunks (4/thread), B 1024 chunks (2/thread).
  // chunk c -> LDS row c>>3, chunk-in-row c&7 (linear dest);
  // global source chunk = (c&7) ^ (row&7)  [involution, rule #21]
  auto STAGE = [&](int buf, int kt){
    #pragma unroll
    for (int i=0;i<4;i++){
      int c = i*512 + tid; int row = c>>3;
      gl16(Ag + (size_t)row*K + kt + (((c&7) ^ (row&7))*8), &sA[buf][c*8]);
    }
    #pragma unroll
    for (int i=0;i<2;i++){
      int c = i*512 + tid; int row = c>>3;
      gl16(Bg + (size_t)row*K + kt + (((c&7) ^ (row&7))*8), &sB[buf][c*8]);
    }
  };

  int nk = K / TBK;
  STAGE(0, 0);
  STAGE(1, TBK);
  // ledger: at iter t, outstanding ≤6 newest = tile t+1 -> tile t landed (per
  // wave); barrier makes it block-wide before any ds_read of buf t%3.
  // STAGE(t+2) -> buf (t+2)%3 = (t-1)%3, consumed last iter (reads completed
  // before its MFMAs' lgkm waits, which precede this barrier).
  for (int t=0; t<nk; ++t){
    if (t < nk-1){ asm volatile("s_waitcnt vmcnt(6)" ::: "memory"); }
    else         { asm volatile("s_waitcnt vmcnt(0)" ::: "memory"); }
    __builtin_amdgcn_sched_barrier(0);
    __builtin_amdgcn_s_barrier();
    __builtin_amdgcn_sched_barrier(0);
    if (t+2 < nk) STAGE((t+2)%3, (t+2)*TBK);
    __builtin_amdgcn_sched_barrier(0);
    const u16* bufA = sA[t%3];
    const u16* bufB = sB[t%3];
    #pragma unroll
    for (int kk=0;kk<2;kk++){
      bf16x8_t af[4], bfr[4];
      #pragma unroll
      for (int mi=0;mi<4;mi++){
        int ra = wm*64 + mi*16 + l15;
        af[mi] = *(const bf16x8_t*)&bufA[ra*64 + (((kk*4 + l4) ^ (ra&7))*8)];
      }
      #pragma unroll
      for (int ni=0;ni<4;ni++){
        int rb = wn*64 + ni*16 + l15;
        bfr[ni] = *(const bf16x8_t*)&bufB[rb*64 + (((kk*4 + l4) ^ (rb&7))*8)];
      }
      __builtin_amdgcn_s_setprio(1);
      #pragma unroll
      for (int mi=0;mi<4;mi++)
        #pragma unroll
        for (int ni=0;ni<4;ni++)
          acc[mi][ni] = __builtin_amdgcn_mfma_f32_16x16x32_bf16(af[mi], bfr[ni], acc[mi][ni], 0,0,0);
      __builtin_amdgcn_s_setprio(0);
    }
  }

  #pragma unroll
  for (int mi=0;mi<4;mi++)
    #pragma unroll
    for (int ni=0;ni<4;ni++)
      #pragma unroll
      for (int r=0;r<4;r++){
        float v = acc[mi][ni][r];
        size_t rowg = m0 + wm*64 + mi*16 + l4*4 + r;
        size_t colg = n0 + wn*64 + ni*16 + l15;
        size_t idx = rowg * (size_t)N + colg;
        if constexpr (EPI == 0){
          ((u16*)C)[idx] = f2bf(v);
        } else if constexpr (EPI == 1){
          float s = v / (1.0f + __expf(-v));
          ((u16*)C)[idx] = f2bf(s);
        } else if constexpr (EPI == 2){
          float a = bf2f(((const u16*)aux)[idx]);
          ((u16*)C)[idx] = f2bf(v * a);
        } else {
          float a = ((const float*)aux)[idx];
          float b2 = bf2f(((const u16*)aux2)[idx]);
          ((float*)C)[idx] = v + a + b2;
        }
      }
}

// ---------------- causal flash attention (swapped QK^T, V^T input) ----------
// longest-first grid: qt = 31 - (bid>>6), (b,h) = bid&63
__global__ __launch_bounds__(256) void attn_k(const u16* __restrict__ Q,
                                              const u16* __restrict__ K,
                                              const u16* __restrict__ VT,
                                              u16* __restrict__ O){
  __shared__ __align__(16) u16 sK[32*128];
  __shared__ __align__(16) u16 sVT[128*32];
  int tid = threadIdx.x, lane = tid & 63, wave = tid >> 6;
  int bid = blockIdx.x;
  int qt = 31 - (bid >> 6);
  int bh = bid & 63; int b = bh >> 4, h = bh & 15;
  int l15 = lane & 15, l4 = lane >> 4;
  size_t base = ((size_t)b*2048)*2048 + (size_t)h*128;
  const u16* VTg0 = VT + ((size_t)h*128)*8192 + (size_t)b*2048;
  int qr0 = qt*64 + wave*16;
  int qrow = qr0 + l15;                       // this lane's single q row
  bf16x8_t qf[4];
  #pragma unroll
  for (int s=0;s<4;s++)
    qf[s] = *(const bf16x8_t*)(Q + base + (size_t)qrow*2048 + s*32 + l4*8);

  f32x4_t oaccT[8];                           // O^T: d = f*16 + l4*4 + r, q = l15
  #pragma unroll
  for (int f=0;f<8;f++) oaccT[f] = (f32x4_t){0.f,0.f,0.f,0.f};
  float mrun = -1e30f, lrun = 0.f;

  const float scale = 0.08838834764831845f;   // 1/sqrt(128)
  int nkt = (qt + 1) * 2;
  for (int kt=0; kt<nkt; ++kt){
    __syncthreads();          // prior tile's LDS reads done
    const u16* Kg = K + base + (size_t)kt*32*2048;
    #pragma unroll
    for (int i=0;i<2;i++){
      int c = i*256 + tid; int row = c>>4;
      gl16(Kg + (size_t)row*2048 + (size_t)(((c&15) ^ (row&7))*8), &sK[c*8]);
    }
    #pragma unroll
    for (int i=0;i<2;i++){
      int c = i*256 + tid; int d = c>>2;
      gl16(VTg0 + (size_t)d*8192 + kt*32 + (size_t)((((c&3) ^ ((d>>1)&3)))*8),
           &sVT[c*8]);
    }
    __syncthreads();          // staged data visible

    if (kt*32 <= qr0 + 15){   // wave-uniform skip of fully-masked tiles
      f32x4_t sacc[2];
      sacc[0] = (f32x4_t){0.f,0.f,0.f,0.f};
      sacc[1] = (f32x4_t){0.f,0.f,0.f,0.f};
      __builtin_amdgcn_s_setprio(1);
      #pragma unroll
      for (int n=0;n<2;n++)
        #pragma unroll
        for (int s=0;s<4;s++){
          bf16x8_t kf = *(const bf16x8_t*)
              &sK[(n*16 + l15)*128 + (((s*4 + l4) ^ (l15 & 7))*8)];
          sacc[n] = __builtin_amdgcn_mfma_f32_16x16x32_bf16(kf, qf[s], sacc[n], 0,0,0);
        }
      __builtin_amdgcn_s_setprio(0);
      float pv[8];
      float mloc = -1e30f;
      #pragma unroll
      for (int n=0;n<2;n++)
        #pragma unroll
        for (int r=0;r<4;r++){
          int kg = kt*32 + n*16 + l4*4 + r;
          float v = sacc[n][r] * scale;
          if (kg > qrow) v = -1e30f;
          pv[n*4+r] = v;
          mloc = fmaxf(mloc, v);
        }
      mloc = fmaxf(mloc, __shfl_xor(mloc, 16, 64));
      mloc = fmaxf(mloc, __shfl_xor(mloc, 32, 64));
      float mnew = fmaxf(mrun, mloc);
      float fr = __expf(mrun - mnew);
      mrun = mnew;
      float sloc = 0.f;
      bf16x8_t pa;
      #pragma unroll
      for (int j=0;j<8;j++){
        float p = __expf(pv[j] - mnew);
        sloc += p;
        pa[j] = (short)f2bf(p);
      }
      sloc += __shfl_xor(sloc, 16, 64);
      sloc += __shfl_xor(sloc, 32, 64);
      lrun = lrun * fr + sloc;
      #pragma unroll
      for (int f=0;f<8;f++){
        oaccT[f][0] *= fr; oaccT[f][1] *= fr; oaccT[f][2] *= fr; oaccT[f][3] *= fr;
      }
      __builtin_amdgcn_s_setprio(1);
      #pragma unroll
      for (int f=0;f<8;f++){
        int d = f*16 + l15;
        bf16x4_t lo = *(const bf16x4_t*)&sVT[d*32 + (((0*4 + l4) ^ (d & 6))*4)];
        bf16x4_t hi = *(const bf16x4_t*)&sVT[d*32 + (((1*4 + l4) ^ (d & 6))*4)];
        bf16x8_t va;
        va[0]=lo[0]; va[1]=lo[1]; va[2]=lo[2]; va[3]=lo[3];
        va[4]=hi[0]; va[5]=hi[1]; va[6]=hi[2]; va[7]=hi[3];
        oaccT[f] = __builtin_amdgcn_mfma_f32_16x16x32_bf16(va, pa, oaccT[f], 0,0,0);
      }
      __builtin_amdgcn_s_setprio(0);
    }
  }
  float inv = 1.0f / lrun;
  size_t orow = (size_t)b*2048 + qrow;
  #pragma unroll
  for (int f=0;f<8;f++){
    bf16x4_t ov;
    ov[0]=(short)f2bf(oaccT[f][0]*inv); ov[1]=(short)f2bf(oaccT[f][1]*inv);
    ov[2]=(short)f2bf(oaccT[f][2]*inv); ov[3]=(short)f2bf(oaccT[f][3]*inv);
    *(bf16x4_t*)(O + orow*2048 + h*128 + f*16 + l4*4) = ov;
  }
}

// ---------------- host ----------------
extern "C" void kernel_launch(void* const* d_in, const int* in_sizes, int n_in,
                              void* d_out, int out_size, void* d_ws, size_t ws_size,
                              hipStream_t stream){
  (void)in_sizes; (void)n_in; (void)out_size; (void)ws_size;
  const float* x   = (const float*)d_in[0];
  const float* fc  = (const float*)d_in[1];
  const float* fs  = (const float*)d_in[2];
  const float* wq  = (const float*)d_in[4];
  const float* wk  = (const float*)d_in[5];
  const float* wv  = (const float*)d_in[6];
  const float* wo  = (const float*)d_in[7];
  const float* w1  = (const float*)d_in[8];
  const float* w2  = (const float*)d_in[9];
  const float* w3  = (const float*)d_in[10];
  const float* anw = (const float*)d_in[11];
  const float* fnw = (const float*)d_in[12];
  float* out = (float*)d_out;
  char* ws = (char*)d_ws;

  const int M = 8192, D = 2048, HID = 5632;
  const size_t WB   = 23068672ull;   // 5632*2048*2 (reused weight buf)
  const size_t ACT2 = 33554432ull;   // 8192*2048*2

  u16* wbuf = (u16*)(ws);
  u16* xa   = (u16*)(ws + WB);                // rmsnorm(x); later attn O
  u16* qb   = (u16*)(ws + WB + ACT2);         // Q; later t1 = o@wo^T
  u16* kb   = (u16*)(ws + WB + 2*ACT2);       // K; later hf
  u16* vb   = (u16*)(ws + WB + 3*ACT2);       // V
  u16* g1   = (u16*)(ws + WB + 4*ACT2);       // VT (32MB) then g1 (88 MiB)
  u16* vt = g1;
  u16* t1 = qb;
  u16* hf = kb;

  rmsnorm_k<<<M, 256, 0, stream>>>(x, anw, xa);

  cvt_k<<<D*D/8/256, 256, 0, stream>>>(wq, wbuf, D*D/8);
  gemm_bt<0><<<(M/TBM)*(D/TBN), 512, 0, stream>>>(xa, wbuf, qb, nullptr, nullptr, M, D, D);
  cvt_k<<<D*D/8/256, 256, 0, stream>>>(wk, wbuf, D*D/8);
  gemm_bt<0><<<(M/TBM)*(D/TBN), 512, 0, stream>>>(xa, wbuf, kb, nullptr, nullptr, M, D, D);
  cvt_k<<<D*D/8/256, 256, 0, stream>>>(wv, wbuf, D*D/8);
  gemm_bt<0><<<(M/TBM)*(D/TBN), 512, 0, stream>>>(xa, wbuf, vb, nullptr, nullptr, M, D, D);

  rope_k<<<32768, 256, 0, stream>>>(qb, kb, fc, fs);
  transpose_k<<<4096, 256, 0, stream>>>(vb, vt);      // V[8192][2048] -> VT[2048][8192]

  attn_k<<<2048, 256, 0, stream>>>(qb, kb, vt, xa);   // O -> xa

  cvt_k<<<D*D/8/256, 256, 0, stream>>>(wo, wbuf, D*D/8);
  gemm_bt<0><<<(M/TBM)*(D/TBN), 512, 0, stream>>>(xa, wbuf, t1, nullptr, nullptr, M, D, D);

  rmsnorm2_k<<<M, 256, 0, stream>>>(x, t1, fnw, hf);

  cvt_k<<<HID*D/8/256, 256, 0, stream>>>(w1, wbuf, HID*D/8);
  gemm_bt<1><<<(M/TBM)*(HID/TBN), 512, 0, stream>>>(hf, wbuf, g1, nullptr, nullptr, M, HID, D);
  cvt_k<<<HID*D/8/256, 256, 0, stream>>>(w3, wbuf, HID*D/8);
  gemm_bt<2><<<(M/TBM)*(HID/TBN), 512, 0, stream>>>(hf, wbuf, g1, g1, nullptr, M, HID, D);
  cvt_k<<<HID*D/8/256, 256, 0, stream>>>(w2, wbuf, HID*D/8);
  gemm_bt<4><<<(M/TBM)*(D/TBN), 512, 0, stream>>>(g1, wbuf, out, x, t1, M, D, HID);
}

// Round 6
// 1323.281 us; speedup vs baseline: 1.7302x; 1.1159x over previous
//
#include <hip/hip_runtime.h>
#include <hip/hip_bf16.h>
#include <stdint.h>

typedef short  bf16x8_t __attribute__((ext_vector_type(8)));
typedef short  bf16x4_t __attribute__((ext_vector_type(4)));
typedef float  f32x4_t  __attribute__((ext_vector_type(4)));
typedef unsigned short u16;
typedef unsigned int   u32;

#define DEV __device__ __forceinline__

DEV u16 f2bf(float f){
  u32 u = __float_as_uint(f);
  u += 0x7fffu + ((u >> 16) & 1u);     // RNE
  return (u16)(u >> 16);
}
DEV float bf2f(u16 h){ return __uint_as_float(((u32)h) << 16); }

DEV void gl16(const void* g, void* l){
  __builtin_amdgcn_global_load_lds(
      (const __attribute__((address_space(1))) void*)g,
      (__attribute__((address_space(3))) void*)l, 16, 0, 0);
}

#define SBAR() do{ __builtin_amdgcn_sched_barrier(0); __builtin_amdgcn_s_barrier(); \
                   __builtin_amdgcn_sched_barrier(0); }while(0)

// ---------------- f32 -> bf16 convert (8 elems/thread) ----------------
__global__ __launch_bounds__(256) void cvt_k(const float* __restrict__ in,
                                             u16* __restrict__ out, int n8){
  int i = blockIdx.x * 256 + threadIdx.x;
  if (i >= n8) return;
  const float4* p = (const float4*)in;
  float4 a = p[(size_t)i*2], b = p[(size_t)i*2+1];
  bf16x8_t o;
  o[0]=(short)f2bf(a.x); o[1]=(short)f2bf(a.y); o[2]=(short)f2bf(a.z); o[3]=(short)f2bf(a.w);
  o[4]=(short)f2bf(b.x); o[5]=(short)f2bf(b.y); o[6]=(short)f2bf(b.z); o[7]=(short)f2bf(b.w);
  *(bf16x8_t*)(out + (size_t)i*8) = o;
}

// ---------------- RMSNorm: fp32 row (D=2048) -> bf16 ----------------
__global__ __launch_bounds__(256) void rmsnorm_k(const float* __restrict__ x,
                                                 const float* __restrict__ w,
                                                 u16* __restrict__ y){
  int row = blockIdx.x, t = threadIdx.x;
  const float4* xr = (const float4*)(x + (size_t)row*2048);
  float4 a = xr[t*2], b = xr[t*2+1];
  float ss = a.x*a.x+a.y*a.y+a.z*a.z+a.w*a.w + b.x*b.x+b.y*b.y+b.z*b.z+b.w*b.w;
  #pragma unroll
  for (int m = 32; m; m >>= 1) ss += __shfl_xor(ss, m, 64);
  __shared__ float red[4];
  if ((t & 63) == 0) red[t >> 6] = ss;
  __syncthreads();
  float tot = red[0]+red[1]+red[2]+red[3];
  float rs = rsqrtf(tot * (1.0f/2048.0f) + 1e-6f);
  const float4* wr = (const float4*)w;
  float4 wa = wr[t*2], wb = wr[t*2+1];
  bf16x8_t o;
  o[0]=(short)f2bf(a.x*rs*wa.x); o[1]=(short)f2bf(a.y*rs*wa.y);
  o[2]=(short)f2bf(a.z*rs*wa.z); o[3]=(short)f2bf(a.w*rs*wa.w);
  o[4]=(short)f2bf(b.x*rs*wb.x); o[5]=(short)f2bf(b.y*rs*wb.y);
  o[6]=(short)f2bf(b.z*rs*wb.z); o[7]=(short)f2bf(b.w*rs*wb.w);
  *(bf16x8_t*)(y + (size_t)row*2048 + t*8) = o;
}

// ---- RMSNorm2: h = x(f32) + t1(bf16); y = rmsnorm(h)*w -> bf16 ----
__global__ __launch_bounds__(256) void rmsnorm2_k(const float* __restrict__ x,
                                                  const u16* __restrict__ t1,
                                                  const float* __restrict__ w,
                                                  u16* __restrict__ y){
  int row = blockIdx.x, t = threadIdx.x;
  const float4* xr = (const float4*)(x + (size_t)row*2048);
  float4 a = xr[t*2], b = xr[t*2+1];
  bf16x8_t tv = *(const bf16x8_t*)(t1 + (size_t)row*2048 + t*8);
  float h[8];
  h[0]=a.x+bf2f((u16)tv[0]); h[1]=a.y+bf2f((u16)tv[1]);
  h[2]=a.z+bf2f((u16)tv[2]); h[3]=a.w+bf2f((u16)tv[3]);
  h[4]=b.x+bf2f((u16)tv[4]); h[5]=b.y+bf2f((u16)tv[5]);
  h[6]=b.z+bf2f((u16)tv[6]); h[7]=b.w+bf2f((u16)tv[7]);
  float ss = 0.f;
  #pragma unroll
  for (int j=0;j<8;j++) ss += h[j]*h[j];
  #pragma unroll
  for (int m = 32; m; m >>= 1) ss += __shfl_xor(ss, m, 64);
  __shared__ float red[4];
  if ((t & 63) == 0) red[t >> 6] = ss;
  __syncthreads();
  float tot = red[0]+red[1]+red[2]+red[3];
  float rs = rsqrtf(tot * (1.0f/2048.0f) + 1e-6f);
  const float4* wr = (const float4*)w;
  float4 wa = wr[t*2], wb = wr[t*2+1];
  bf16x8_t o;
  o[0]=(short)f2bf(h[0]*rs*wa.x); o[1]=(short)f2bf(h[1]*rs*wa.y);
  o[2]=(short)f2bf(h[2]*rs*wa.z); o[3]=(short)f2bf(h[3]*rs*wa.w);
  o[4]=(short)f2bf(h[4]*rs*wb.x); o[5]=(short)f2bf(h[5]*rs*wb.y);
  o[6]=(short)f2bf(h[6]*rs*wb.z); o[7]=(short)f2bf(h[7]*rs*wb.w);
  *(bf16x8_t*)(y + (size_t)row*2048 + t*8) = o;
}

// ---------------- RoPE in-place on q,k (bf16, B,S,H,HD) ----------------
__global__ __launch_bounds__(256) void rope_k(u16* __restrict__ q, u16* __restrict__ k,
                                              const float* __restrict__ fc,
                                              const float* __restrict__ fs){
  int i = blockIdx.x * 256 + threadIdx.x;
  int ii = i & 63; int h = (i >> 6) & 15; int bs = i >> 10;
  int s = bs & 2047;
  size_t off = (size_t)bs*2048 + h*128 + 2*ii;
  float c = fc[s*64+ii], sn = fs[s*64+ii];
  u32 qq = *(u32*)(q + off);
  float xr = bf2f((u16)(qq & 0xffff)), xi = bf2f((u16)(qq >> 16));
  *(u32*)(q + off) = (u32)f2bf(xr*c - xi*sn) | ((u32)f2bf(xr*sn + xi*c) << 16);
  u32 kk = *(u32*)(k + off);
  xr = bf2f((u16)(kk & 0xffff)); xi = bf2f((u16)(kk >> 16));
  *(u32*)(k + off) = (u32)f2bf(xr*c - xi*sn) | ((u32)f2bf(xr*sn + xi*c) << 16);
}

// ---------------- 2048x8192 transpose (V -> V^T), 64x64 tiles ----------------
__global__ __launch_bounds__(256) void transpose_k(const u16* __restrict__ in,
                                                   u16* __restrict__ out){
  __shared__ u16 tile[64*68];
  int tid = threadIdx.x;
  int tm = blockIdx.x >> 5, tn = blockIdx.x & 31;   // in: [8192][2048]
  const u16* src = in + (size_t)(tm*64)*2048 + tn*64;
  #pragma unroll
  for (int i=0;i<2;i++){
    int idx = i*256 + tid;
    int r = idx >> 3, c8 = (idx & 7)*8;
    *(bf16x8_t*)&tile[r*68 + c8] = *(const bf16x8_t*)(src + (size_t)r*2048 + c8);
  }
  __syncthreads();
  u16* dst = out + (size_t)(tn*64)*8192 + tm*64;
  #pragma unroll
  for (int i=0;i<2;i++){
    int idx = i*256 + tid;
    int oc = idx >> 3, r8 = (idx & 7)*8;
    bf16x8_t v;
    #pragma unroll
    for (int j=0;j<8;j++) v[j] = tile[(r8+j)*68 + oc];
    *(bf16x8_t*)(dst + (size_t)oc*8192 + r8) = v;
  }
}

// ---------------- GEMM: C(MxN) = A(MxK,bf16) * B(NxK,bf16)^T (+epilogue) ----
// 256x256 tile, BK=64, 8 waves (2M x 4N, 128x64 each), 2 LDS K-tile buffers
// staged in K-halves (Kh0/Kh1), counted vmcnt(8) ledger, 4 phases per K-tile:
//   q0:(mh0,kk0)+stage A-Kh1(T+1)  q1:(mh1,kk0)+stage B-Kh1(T+1)
//   q2:(mh0,kk1)+stage A-Kh0(T+2)  q3:(mh1,kk1)+stage B-Kh0(T+2)
// In-half swizzle: phys chunk = l4 ^ ((row>>1)&3) -> 2-way (free) bank aliasing.

// stage one K-half: 1024 16B chunks; dst chunk c -> row c>>2, phys p=c&3;
// source logical chunk = p ^ ((row>>1)&3). Toff = T*64 + kh*32 (elements).
DEV void stg(const u16* __restrict__ G, int K, u16* dst, int tid, int Toff){
  #pragma unroll
  for (int j=0;j<2;j++){
    int c = j*512 + tid;
    int row = c >> 2;
    int l = (c&3) ^ ((row>>1)&3);
    gl16(G + (size_t)row*K + Toff + l*8, dst + (size_t)c*8);
  }
}

template<int MH, bool LOADB>
DEV void phase_mm(const u16* baseA, const u16* baseB, int l15, int pc,
                  int wm, int wn, bf16x8_t (&bf)[4], f32x4_t (&acc)[8][4]){
  bf16x8_t af[4];
  #pragma unroll
  for (int mi=0; mi<4; mi++){
    int R = wm*128 + MH*64 + mi*16 + l15;
    af[mi] = *(const bf16x8_t*)&baseA[R*32 + pc];
  }
  if (LOADB){
    #pragma unroll
    for (int ni=0; ni<4; ni++){
      int Rb = wn*64 + ni*16 + l15;
      bf[ni] = *(const bf16x8_t*)&baseB[Rb*32 + pc];
    }
  }
  asm volatile("s_waitcnt lgkmcnt(0)" ::: "memory");
  __builtin_amdgcn_sched_barrier(0);
  __builtin_amdgcn_s_setprio(1);
  #pragma unroll
  for (int mi=0; mi<4; mi++)
    #pragma unroll
    for (int ni=0; ni<4; ni++)
      acc[MH*4+mi][ni] =
        __builtin_amdgcn_mfma_f32_16x16x32_bf16(af[mi], bf[ni], acc[MH*4+mi][ni], 0,0,0);
  __builtin_amdgcn_s_setprio(0);
}

template<int EPI>
__global__ __launch_bounds__(512, 2) void gemm_bt(const u16* __restrict__ A,
                                                  const u16* __restrict__ B,
                                                  void* __restrict__ C,
                                                  const void* __restrict__ aux,
                                                  const void* __restrict__ aux2,
                                                  int M, int N, int K){
  __shared__ __align__(16) u16 sA[2*2*8192];   // [buf][kh][256 rows x 32 elems] = 64KB
  __shared__ __align__(16) u16 sB[2*2*8192];   // 64KB
  int tid = threadIdx.x, lane = tid & 63, wave = tid >> 6;
  int l15 = lane & 15, l4 = lane >> 4;
  int pc = (l4 ^ ((l15 >> 1) & 3)) * 8;        // phys chunk offset within row
  int nbn = N / 256;
  int nwg = gridDim.x, bid = blockIdx.x;
  int qq = nwg >> 3, rr = nwg & 7;
  int xc = bid & 7, yy = bid >> 3;
  int wg = (xc < rr ? xc*(qq+1) : rr*(qq+1) + (xc-rr)*qq) + yy;
  int tm = wg / nbn, tn = wg % nbn;
  size_t m0 = (size_t)tm*256, n0 = (size_t)tn*256;
  const u16* Ag = A + m0*K;
  const u16* Bg = B + n0*K;
  int wm = wave >> 2, wn = wave & 3;           // 2 x 4 wave grid

  f32x4_t acc[8][4];
  #pragma unroll
  for (int i=0;i<8;i++)
    #pragma unroll
    for (int j=0;j<4;j++)
      acc[i][j] = (f32x4_t){0.f,0.f,0.f,0.f};
  bf16x8_t bf[4];

  int nk = K / 64;
  // prologue: Kh0(0), Kh1(0), Kh0(1)  (A then B each) -> 12 loads/thread
  stg(Ag, K, &sA[0],     tid, 0);
  stg(Bg, K, &sB[0],     tid, 0);
  stg(Ag, K, &sA[8192],  tid, 32);
  stg(Bg, K, &sB[8192],  tid, 32);
  stg(Ag, K, &sA[16384], tid, 64);
  stg(Bg, K, &sB[16384], tid, 64);

  for (int T=0; T<nk; ++T){
    int buf = T & 1, bufn = buf ^ 1;
    const u16* A0 = &sA[buf*16384];
    const u16* B0 = &sB[buf*16384];
    // ---- q0: (mh0,kk0); needs Kh0(T); stage A-Kh1(T+1)
    if (T+1 < nk) asm volatile("s_waitcnt vmcnt(8)" ::: "memory");
    else          asm volatile("s_waitcnt vmcnt(4)" ::: "memory");
    SBAR();
    if (T+1 < nk) stg(Ag, K, &sA[bufn*16384 + 8192], tid, (T+1)*64 + 32);
    phase_mm<0,true >(A0,        B0,        l15, pc, wm, wn, bf, acc);
    // ---- q1: (mh1,kk0); stage B-Kh1(T+1)
    SBAR();
    if (T+1 < nk) stg(Bg, K, &sB[bufn*16384 + 8192], tid, (T+1)*64 + 32);
    phase_mm<1,false>(A0,        B0,        l15, pc, wm, wn, bf, acc);
    // ---- q2: (mh0,kk1); needs Kh1(T); stage A-Kh0(T+2)
    if (T+1 < nk) asm volatile("s_waitcnt vmcnt(8)" ::: "memory");
    else          asm volatile("s_waitcnt vmcnt(0)" ::: "memory");
    SBAR();
    if (T+2 < nk) stg(Ag, K, &sA[buf*16384], tid, (T+2)*64);
    phase_mm<0,true >(A0+8192,   B0+8192,   l15, pc, wm, wn, bf, acc);
    // ---- q3: (mh1,kk1); stage B-Kh0(T+2)
    SBAR();
    if (T+2 < nk) stg(Bg, K, &sB[buf*16384], tid, (T+2)*64);
    phase_mm<1,false>(A0+8192,   B0+8192,   l15, pc, wm, wn, bf, acc);
  }

  #pragma unroll
  for (int am=0; am<8; am++)
    #pragma unroll
    for (int ni=0; ni<4; ni++)
      #pragma unroll
      for (int r=0; r<4; r++){
        float v = acc[am][ni][r];
        size_t rowg = m0 + am*16 + wm*128 + l4*4 + r;
        size_t colg = n0 + wn*64 + ni*16 + l15;
        size_t idx = rowg * (size_t)N + colg;
        if constexpr (EPI == 0){
          ((u16*)C)[idx] = f2bf(v);
        } else if constexpr (EPI == 1){
          float s = v / (1.0f + __expf(-v));
          ((u16*)C)[idx] = f2bf(s);
        } else if constexpr (EPI == 2){
          float a = bf2f(((const u16*)aux)[idx]);
          ((u16*)C)[idx] = f2bf(v * a);
        } else {
          float a = ((const float*)aux)[idx];
          float b2 = bf2f(((const u16*)aux2)[idx]);
          ((float*)C)[idx] = v + a + b2;
        }
      }
}

// ---------------- causal flash attention (swapped QK^T, V^T input) ----------
// longest-first grid: qt = 31 - (bid>>6), (b,h) = bid&63
__global__ __launch_bounds__(256) void attn_k(const u16* __restrict__ Q,
                                              const u16* __restrict__ K,
                                              const u16* __restrict__ VT,
                                              u16* __restrict__ O){
  __shared__ __align__(16) u16 sK[32*128];
  __shared__ __align__(16) u16 sVT[128*32];
  int tid = threadIdx.x, lane = tid & 63, wave = tid >> 6;
  int bid = blockIdx.x;
  int qt = 31 - (bid >> 6);
  int bh = bid & 63; int b = bh >> 4, h = bh & 15;
  int l15 = lane & 15, l4 = lane >> 4;
  size_t base = ((size_t)b*2048)*2048 + (size_t)h*128;
  const u16* VTg0 = VT + ((size_t)h*128)*8192 + (size_t)b*2048;
  int qr0 = qt*64 + wave*16;
  int qrow = qr0 + l15;                       // this lane's single q row
  bf16x8_t qf[4];
  #pragma unroll
  for (int s=0;s<4;s++)
    qf[s] = *(const bf16x8_t*)(Q + base + (size_t)qrow*2048 + s*32 + l4*8);

  f32x4_t oaccT[8];                           // O^T: d = f*16 + l4*4 + r, q = l15
  #pragma unroll
  for (int f=0;f<8;f++) oaccT[f] = (f32x4_t){0.f,0.f,0.f,0.f};
  float mrun = -1e30f, lrun = 0.f;

  const float scale = 0.08838834764831845f;   // 1/sqrt(128)
  int nkt = (qt + 1) * 2;
  for (int kt=0; kt<nkt; ++kt){
    __syncthreads();          // prior tile's LDS reads done
    const u16* Kg = K + base + (size_t)kt*32*2048;
    #pragma unroll
    for (int i=0;i<2;i++){
      int c = i*256 + tid; int row = c>>4;
      gl16(Kg + (size_t)row*2048 + (size_t)(((c&15) ^ (row&7))*8), &sK[c*8]);
    }
    #pragma unroll
    for (int i=0;i<2;i++){
      int c = i*256 + tid; int d = c>>2;
      gl16(VTg0 + (size_t)d*8192 + kt*32 + (size_t)((((c&3) ^ ((d>>1)&3)))*8),
           &sVT[c*8]);
    }
    __syncthreads();          // staged data visible

    if (kt*32 <= qr0 + 15){   // wave-uniform skip of fully-masked tiles
      f32x4_t sacc[2];
      sacc[0] = (f32x4_t){0.f,0.f,0.f,0.f};
      sacc[1] = (f32x4_t){0.f,0.f,0.f,0.f};
      __builtin_amdgcn_s_setprio(1);
      #pragma unroll
      for (int n=0;n<2;n++)
        #pragma unroll
        for (int s=0;s<4;s++){
          bf16x8_t kf = *(const bf16x8_t*)
              &sK[(n*16 + l15)*128 + (((s*4 + l4) ^ (l15 & 7))*8)];
          sacc[n] = __builtin_amdgcn_mfma_f32_16x16x32_bf16(kf, qf[s], sacc[n], 0,0,0);
        }
      __builtin_amdgcn_s_setprio(0);
      float pv[8];
      float mloc = -1e30f;
      #pragma unroll
      for (int n=0;n<2;n++)
        #pragma unroll
        for (int r=0;r<4;r++){
          int kg = kt*32 + n*16 + l4*4 + r;
          float v = sacc[n][r] * scale;
          if (kg > qrow) v = -1e30f;
          pv[n*4+r] = v;
          mloc = fmaxf(mloc, v);
        }
      mloc = fmaxf(mloc, __shfl_xor(mloc, 16, 64));
      mloc = fmaxf(mloc, __shfl_xor(mloc, 32, 64));
      float mnew = fmaxf(mrun, mloc);
      float fr = __expf(mrun - mnew);
      mrun = mnew;
      float sloc = 0.f;
      bf16x8_t pa;
      #pragma unroll
      for (int j=0;j<8;j++){
        float p = __expf(pv[j] - mnew);
        sloc += p;
        pa[j] = (short)f2bf(p);
      }
      sloc += __shfl_xor(sloc, 16, 64);
      sloc += __shfl_xor(sloc, 32, 64);
      lrun = lrun * fr + sloc;
      #pragma unroll
      for (int f=0;f<8;f++){
        oaccT[f][0] *= fr; oaccT[f][1] *= fr; oaccT[f][2] *= fr; oaccT[f][3] *= fr;
      }
      __builtin_amdgcn_s_setprio(1);
      #pragma unroll
      for (int f=0;f<8;f++){
        int d = f*16 + l15;
        bf16x4_t lo = *(const bf16x4_t*)&sVT[d*32 + (((0*4 + l4) ^ (d & 6))*4)];
        bf16x4_t hi = *(const bf16x4_t*)&sVT[d*32 + (((1*4 + l4) ^ (d & 6))*4)];
        bf16x8_t va;
        va[0]=lo[0]; va[1]=lo[1]; va[2]=lo[2]; va[3]=lo[3];
        va[4]=hi[0]; va[5]=hi[1]; va[6]=hi[2]; va[7]=hi[3];
        oaccT[f] = __builtin_amdgcn_mfma_f32_16x16x32_bf16(va, pa, oaccT[f], 0,0,0);
      }
      __builtin_amdgcn_s_setprio(0);
    }
  }
  float inv = 1.0f / lrun;
  size_t orow = (size_t)b*2048 + qrow;
  #pragma unroll
  for (int f=0;f<8;f++){
    bf16x4_t ov;
    ov[0]=(short)f2bf(oaccT[f][0]*inv); ov[1]=(short)f2bf(oaccT[f][1]*inv);
    ov[2]=(short)f2bf(oaccT[f][2]*inv); ov[3]=(short)f2bf(oaccT[f][3]*inv);
    *(bf16x4_t*)(O + orow*2048 + h*128 + f*16 + l4*4) = ov;
  }
}

// ---------------- host ----------------
extern "C" void kernel_launch(void* const* d_in, const int* in_sizes, int n_in,
                              void* d_out, int out_size, void* d_ws, size_t ws_size,
                              hipStream_t stream){
  (void)in_sizes; (void)n_in; (void)out_size; (void)ws_size;
  const float* x   = (const float*)d_in[0];
  const float* fc  = (const float*)d_in[1];
  const float* fs  = (const float*)d_in[2];
  const float* wq  = (const float*)d_in[4];
  const float* wk  = (const float*)d_in[5];
  const float* wv  = (const float*)d_in[6];
  const float* wo  = (const float*)d_in[7];
  const float* w1  = (const float*)d_in[8];
  const float* w2  = (const float*)d_in[9];
  const float* w3  = (const float*)d_in[10];
  const float* anw = (const float*)d_in[11];
  const float* fnw = (const float*)d_in[12];
  float* out = (float*)d_out;
  char* ws = (char*)d_ws;

  const int M = 8192, D = 2048, HID = 5632;
  const size_t WB   = 23068672ull;   // 5632*2048*2 (reused weight buf)
  const size_t ACT2 = 33554432ull;   // 8192*2048*2

  u16* wbuf = (u16*)(ws);
  u16* xa   = (u16*)(ws + WB);                // rmsnorm(x); later attn O
  u16* qb   = (u16*)(ws + WB + ACT2);         // Q; later t1 = o@wo^T
  u16* kb   = (u16*)(ws + WB + 2*ACT2);       // K; later hf
  u16* vb   = (u16*)(ws + WB + 3*ACT2);       // V
  u16* g1   = (u16*)(ws + WB + 4*ACT2);       // VT (32MB) then g1 (88 MiB)
  u16* vt = g1;
  u16* t1 = qb;
  u16* hf = kb;

  rmsnorm_k<<<M, 256, 0, stream>>>(x, anw, xa);

  cvt_k<<<D*D/8/256, 256, 0, stream>>>(wq, wbuf, D*D/8);
  gemm_bt<0><<<(M/256)*(D/256), 512, 0, stream>>>(xa, wbuf, qb, nullptr, nullptr, M, D, D);
  cvt_k<<<D*D/8/256, 256, 0, stream>>>(wk, wbuf, D*D/8);
  gemm_bt<0><<<(M/256)*(D/256), 512, 0, stream>>>(xa, wbuf, kb, nullptr, nullptr, M, D, D);
  cvt_k<<<D*D/8/256, 256, 0, stream>>>(wv, wbuf, D*D/8);
  gemm_bt<0><<<(M/256)*(D/256), 512, 0, stream>>>(xa, wbuf, vb, nullptr, nullptr, M, D, D);

  rope_k<<<32768, 256, 0, stream>>>(qb, kb, fc, fs);
  transpose_k<<<4096, 256, 0, stream>>>(vb, vt);      // V[8192][2048] -> VT[2048][8192]

  attn_k<<<2048, 256, 0, stream>>>(qb, kb, vt, xa);   // O -> xa

  cvt_k<<<D*D/8/256, 256, 0, stream>>>(wo, wbuf, D*D/8);
  gemm_bt<0><<<(M/256)*(D/256), 512, 0, stream>>>(xa, wbuf, t1, nullptr, nullptr, M, D, D);

  rmsnorm2_k<<<M, 256, 0, stream>>>(x, t1, fnw, hf);

  cvt_k<<<HID*D/8/256, 256, 0, stream>>>(w1, wbuf, HID*D/8);
  gemm_bt<1><<<(M/256)*(HID/256), 512, 0, stream>>>(hf, wbuf, g1, nullptr, nullptr, M, HID, D);
  cvt_k<<<HID*D/8/256, 256, 0, stream>>>(w3, wbuf, HID*D/8);
  gemm_bt<2><<<(M/256)*(HID/256), 512, 0, stream>>>(hf, wbuf, g1, g1, nullptr, M, HID, D);
  cvt_k<<<HID*D/8/256, 256, 0, stream>>>(w2, wbuf, HID*D/8);
  gemm_bt<4><<<(M/256)*(D/256), 512, 0, stream>>>(g1, wbuf, out, x, t1, M, D, HID);
}

// Round 7
// 1317.998 us; speedup vs baseline: 1.7371x; 1.0040x over previous
//
#include <hip/hip_runtime.h>
#include <hip/hip_bf16.h>
#include <stdint.h>

typedef short  bf16x8_t __attribute__((ext_vector_type(8)));
typedef short  bf16x4_t __attribute__((ext_vector_type(4)));
typedef float  f32x4_t  __attribute__((ext_vector_type(4)));
typedef unsigned short u16;
typedef unsigned int   u32;

#define DEV __device__ __forceinline__

DEV u16 f2bf(float f){
  u32 u = __float_as_uint(f);
  u += 0x7fffu + ((u >> 16) & 1u);     // RNE
  return (u16)(u >> 16);
}
DEV float bf2f(u16 h){ return __uint_as_float(((u32)h) << 16); }

DEV void gl16(const void* g, void* l){
  __builtin_amdgcn_global_load_lds(
      (const __attribute__((address_space(1))) void*)g,
      (__attribute__((address_space(3))) void*)l, 16, 0, 0);
}

#define SB0() __builtin_amdgcn_sched_barrier(0)
#define BARF() do{ SB0(); __builtin_amdgcn_s_barrier(); SB0(); }while(0)

// ---------------- f32 -> bf16 convert (8 elems/thread) ----------------
__global__ __launch_bounds__(256) void cvt_k(const float* __restrict__ in,
                                             u16* __restrict__ out, int n8){
  int i = blockIdx.x * 256 + threadIdx.x;
  if (i >= n8) return;
  const float4* p = (const float4*)in;
  float4 a = p[(size_t)i*2], b = p[(size_t)i*2+1];
  bf16x8_t o;
  o[0]=(short)f2bf(a.x); o[1]=(short)f2bf(a.y); o[2]=(short)f2bf(a.z); o[3]=(short)f2bf(a.w);
  o[4]=(short)f2bf(b.x); o[5]=(short)f2bf(b.y); o[6]=(short)f2bf(b.z); o[7]=(short)f2bf(b.w);
  *(bf16x8_t*)(out + (size_t)i*8) = o;
}

// ---------------- RMSNorm: fp32 row (D=2048) -> bf16 ----------------
__global__ __launch_bounds__(256) void rmsnorm_k(const float* __restrict__ x,
                                                 const float* __restrict__ w,
                                                 u16* __restrict__ y){
  int row = blockIdx.x, t = threadIdx.x;
  const float4* xr = (const float4*)(x + (size_t)row*2048);
  float4 a = xr[t*2], b = xr[t*2+1];
  float ss = a.x*a.x+a.y*a.y+a.z*a.z+a.w*a.w + b.x*b.x+b.y*b.y+b.z*b.z+b.w*b.w;
  #pragma unroll
  for (int m = 32; m; m >>= 1) ss += __shfl_xor(ss, m, 64);
  __shared__ float red[4];
  if ((t & 63) == 0) red[t >> 6] = ss;
  __syncthreads();
  float tot = red[0]+red[1]+red[2]+red[3];
  float rs = rsqrtf(tot * (1.0f/2048.0f) + 1e-6f);
  const float4* wr = (const float4*)w;
  float4 wa = wr[t*2], wb = wr[t*2+1];
  bf16x8_t o;
  o[0]=(short)f2bf(a.x*rs*wa.x); o[1]=(short)f2bf(a.y*rs*wa.y);
  o[2]=(short)f2bf(a.z*rs*wa.z); o[3]=(short)f2bf(a.w*rs*wa.w);
  o[4]=(short)f2bf(b.x*rs*wb.x); o[5]=(short)f2bf(b.y*rs*wb.y);
  o[6]=(short)f2bf(b.z*rs*wb.z); o[7]=(short)f2bf(b.w*rs*wb.w);
  *(bf16x8_t*)(y + (size_t)row*2048 + t*8) = o;
}

// ---- RMSNorm2: h = x(f32) + t1(bf16); y = rmsnorm(h)*w -> bf16 ----
__global__ __launch_bounds__(256) void rmsnorm2_k(const float* __restrict__ x,
                                                  const u16* __restrict__ t1,
                                                  const float* __restrict__ w,
                                                  u16* __restrict__ y){
  int row = blockIdx.x, t = threadIdx.x;
  const float4* xr = (const float4*)(x + (size_t)row*2048);
  float4 a = xr[t*2], b = xr[t*2+1];
  bf16x8_t tv = *(const bf16x8_t*)(t1 + (size_t)row*2048 + t*8);
  float h[8];
  h[0]=a.x+bf2f((u16)tv[0]); h[1]=a.y+bf2f((u16)tv[1]);
  h[2]=a.z+bf2f((u16)tv[2]); h[3]=a.w+bf2f((u16)tv[3]);
  h[4]=b.x+bf2f((u16)tv[4]); h[5]=b.y+bf2f((u16)tv[5]);
  h[6]=b.z+bf2f((u16)tv[6]); h[7]=b.w+bf2f((u16)tv[7]);
  float ss = 0.f;
  #pragma unroll
  for (int j=0;j<8;j++) ss += h[j]*h[j];
  #pragma unroll
  for (int m = 32; m; m >>= 1) ss += __shfl_xor(ss, m, 64);
  __shared__ float red[4];
  if ((t & 63) == 0) red[t >> 6] = ss;
  __syncthreads();
  float tot = red[0]+red[1]+red[2]+red[3];
  float rs = rsqrtf(tot * (1.0f/2048.0f) + 1e-6f);
  const float4* wr = (const float4*)w;
  float4 wa = wr[t*2], wb = wr[t*2+1];
  bf16x8_t o;
  o[0]=(short)f2bf(h[0]*rs*wa.x); o[1]=(short)f2bf(h[1]*rs*wa.y);
  o[2]=(short)f2bf(h[2]*rs*wa.z); o[3]=(short)f2bf(h[3]*rs*wa.w);
  o[4]=(short)f2bf(h[4]*rs*wb.x); o[5]=(short)f2bf(h[5]*rs*wb.y);
  o[6]=(short)f2bf(h[6]*rs*wb.z); o[7]=(short)f2bf(h[7]*rs*wb.w);
  *(bf16x8_t*)(y + (size_t)row*2048 + t*8) = o;
}

// ---------------- RoPE in-place on q,k (bf16, B,S,H,HD) ----------------
__global__ __launch_bounds__(256) void rope_k(u16* __restrict__ q, u16* __restrict__ k,
                                              const float* __restrict__ fc,
                                              const float* __restrict__ fs){
  int i = blockIdx.x * 256 + threadIdx.x;
  int ii = i & 63; int h = (i >> 6) & 15; int bs = i >> 10;
  int s = bs & 2047;
  size_t off = (size_t)bs*2048 + h*128 + 2*ii;
  float c = fc[s*64+ii], sn = fs[s*64+ii];
  u32 qq = *(u32*)(q + off);
  float xr = bf2f((u16)(qq & 0xffff)), xi = bf2f((u16)(qq >> 16));
  *(u32*)(q + off) = (u32)f2bf(xr*c - xi*sn) | ((u32)f2bf(xr*sn + xi*c) << 16);
  u32 kk = *(u32*)(k + off);
  xr = bf2f((u16)(kk & 0xffff)); xi = bf2f((u16)(kk >> 16));
  *(u32*)(k + off) = (u32)f2bf(xr*c - xi*sn) | ((u32)f2bf(xr*sn + xi*c) << 16);
}

// ---------------- 2048x8192 transpose (V -> V^T), 64x64 tiles ----------------
__global__ __launch_bounds__(256) void transpose_k(const u16* __restrict__ in,
                                                   u16* __restrict__ out){
  __shared__ u16 tile[64*68];
  int tid = threadIdx.x;
  int tm = blockIdx.x >> 5, tn = blockIdx.x & 31;   // in: [8192][2048]
  const u16* src = in + (size_t)(tm*64)*2048 + tn*64;
  #pragma unroll
  for (int i=0;i<2;i++){
    int idx = i*256 + tid;
    int r = idx >> 3, c8 = (idx & 7)*8;
    *(bf16x8_t*)&tile[r*68 + c8] = *(const bf16x8_t*)(src + (size_t)r*2048 + c8);
  }
  __syncthreads();
  u16* dst = out + (size_t)(tn*64)*8192 + tm*64;
  #pragma unroll
  for (int i=0;i<2;i++){
    int idx = i*256 + tid;
    int oc = idx >> 3, r8 = (idx & 7)*8;
    bf16x8_t v;
    #pragma unroll
    for (int j=0;j<8;j++) v[j] = tile[(r8+j)*68 + oc];
    *(bf16x8_t*)(dst + (size_t)oc*8192 + r8) = v;
  }
}

// ---------------- GEMM: C(MxN) = A(MxK,bf16) * B(NxK,bf16)^T (+epilogue) ----
// 256x256 tile, BK=64, 8 waves (2M x 4N, 128x64/wave), 2 LDS buffers of 2
// K-halves each. Software-pipelined: every ds_read cluster is issued one
// MFMA-cluster ahead; 2 barriers + 2 vmcnt(4) per K-tile; stages Kh1(T+1)@S1,
// Kh0(T+2)@S2. Swizzle: phys chunk = l4 ^ ((row>>1)&3) (measured 0 conflicts).

DEV void stg(const u16* __restrict__ G, int K, u16* dst, int tid, int Toff){
  #pragma unroll
  for (int j=0;j<2;j++){
    int c = j*512 + tid;
    int row = c >> 2;
    int l = (c&3) ^ ((row>>1)&3);
    gl16(G + (size_t)row*K + Toff + l*8, dst + (size_t)c*8);
  }
}

DEV void rdA(const u16* base, int wm, int mh, int l15, int pc, bf16x8_t (&r)[4]){
  #pragma unroll
  for (int mi=0;mi<4;mi++){
    int R = wm*128 + mh*64 + mi*16 + l15;
    r[mi] = *(const bf16x8_t*)&base[R*32 + pc];
  }
}
DEV void rdB(const u16* base, int wn, int l15, int pc, bf16x8_t (&r)[4]){
  #pragma unroll
  for (int ni=0;ni<4;ni++){
    int R = wn*64 + ni*16 + l15;
    r[ni] = *(const bf16x8_t*)&base[R*32 + pc];
  }
}

template<int MH>
DEV void MM16(bf16x8_t (&a)[4], bf16x8_t (&b)[4], f32x4_t (&acc)[8][4]){
  __builtin_amdgcn_s_setprio(1);
  #pragma unroll
  for (int mi=0;mi<4;mi++)
    #pragma unroll
    for (int ni=0;ni<4;ni++)
      acc[MH*4+mi][ni] =
        __builtin_amdgcn_mfma_f32_16x16x32_bf16(a[mi], b[ni], acc[MH*4+mi][ni], 0,0,0);
  __builtin_amdgcn_s_setprio(0);
}

template<int EPI>
__global__ __launch_bounds__(512, 2) void gemm_bt(const u16* __restrict__ A,
                                                  const u16* __restrict__ B,
                                                  void* __restrict__ C,
                                                  const void* __restrict__ aux,
                                                  const void* __restrict__ aux2,
                                                  int M, int N, int K){
  __shared__ __align__(16) u16 sA[2*2*8192];   // [buf][kh][256 rows x 32] = 64KB
  __shared__ __align__(16) u16 sB[2*2*8192];   // 64KB
  int tid = threadIdx.x, lane = tid & 63, wave = tid >> 6;
  int l15 = lane & 15, l4 = lane >> 4;
  int pc = (l4 ^ ((l15 >> 1) & 3)) * 8;
  int nbn = N / 256;
  int nwg = gridDim.x, bid = blockIdx.x;
  int qq = nwg >> 3, rr = nwg & 7;
  int xc = bid & 7, yy = bid >> 3;
  int wg = (xc < rr ? xc*(qq+1) : rr*(qq+1) + (xc-rr)*qq) + yy;
  int tm = wg / nbn, tn = wg % nbn;
  size_t m0 = (size_t)tm*256, n0 = (size_t)tn*256;
  const u16* Ag = A + m0*K;
  const u16* Bg = B + n0*K;
  int wm = wave >> 2, wn = wave & 3;           // 2 x 4 wave grid

  f32x4_t acc[8][4];
  #pragma unroll
  for (int i=0;i<8;i++)
    #pragma unroll
    for (int j=0;j<4;j++)
      acc[i][j] = (f32x4_t){0.f,0.f,0.f,0.f};

  int nk = K / 64;
  // prologue: Kh0(0), Kh1(0), Kh0(1)
  stg(Ag, K, &sA[0],     tid, 0);  stg(Bg, K, &sB[0],     tid, 0);
  stg(Ag, K, &sA[8192],  tid, 32); stg(Bg, K, &sB[8192],  tid, 32);
  stg(Ag, K, &sA[16384], tid, 64); stg(Bg, K, &sB[16384], tid, 64);
  asm volatile("s_waitcnt vmcnt(8)" ::: "memory");
  BARF();
  bf16x8_t aA[4], bA[4], aB[4], aC[4], aD[4], bB[4];
  rdA(&sA[0], wm, 0, l15, pc, aA);             // q0 reads, tile 0
  rdB(&sB[0], wn, l15, pc, bA);
  SB0();

  for (int T=0; T<nk; ++T){
    int cb = T & 1, nb = cb ^ 1;
    const u16* Ac0 = &sA[cb*16384]; const u16* Ac1 = Ac0 + 8192;
    const u16* Bc0 = &sB[cb*16384]; const u16* Bc1 = Bc0 + 8192;
    // ---- S1: Kh1(T) + older done; newest 4 = Kh0(T+1)
    if (T < nk-1) asm volatile("s_waitcnt vmcnt(4)" ::: "memory");
    else          asm volatile("s_waitcnt vmcnt(0)" ::: "memory");
    BARF();
    if (T+1 < nk){
      stg(Ag, K, &sA[nb*16384 + 8192], tid, (T+1)*64 + 32);
      stg(Bg, K, &sB[nb*16384 + 8192], tid, (T+1)*64 + 32);
    }
    SB0();
    rdA(Ac0, wm, 1, l15, pc, aB); SB0();       // q1 reads fly under q0 MFMA
    MM16<0>(aA, bA, acc);                       // q0: mh0 x kk0
    rdA(Ac1, wm, 0, l15, pc, aC);
    rdB(Bc1, wn, l15, pc, bB); SB0();          // q2 reads fly under q1 MFMA
    MM16<1>(aB, bA, acc);                       // q1: mh1 x kk0
    rdA(Ac1, wm, 1, l15, pc, aD); SB0();       // q3 reads fly under q2 MFMA
    MM16<0>(aC, bB, acc);                       // q2: mh0 x kk1
    // ---- S2: Kh0(T+1) + older done; newest 4 = Kh1(T+1)
    if (T < nk-1) asm volatile("s_waitcnt vmcnt(4)" ::: "memory");
    else          asm volatile("s_waitcnt vmcnt(0)" ::: "memory");
    BARF();
    if (T+2 < nk){
      stg(Ag, K, &sA[cb*16384], tid, (T+2)*64);
      stg(Bg, K, &sB[cb*16384], tid, (T+2)*64);
    }
    SB0();
    MM16<1>(aD, bB, acc);                       // q3: mh1 x kk1
    if (T+1 < nk){                              // next tile q0 reads (Kh0(T+1)
      rdA(&sA[nb*16384], wm, 0, l15, pc, aA);   //  visible since S2's vmcnt+bar)
      rdB(&sB[nb*16384], wn, l15, pc, bA);
    }
    SB0();
  }

  #pragma unroll
  for (int am=0; am<8; am++)
    #pragma unroll
    for (int ni=0; ni<4; ni++)
      #pragma unroll
      for (int r=0; r<4; r++){
        float v = acc[am][ni][r];
        size_t rowg = m0 + (am&3)*16 + (am>>2)*64 + wm*128 + l4*4 + r;
        size_t colg = n0 + wn*64 + ni*16 + l15;
        size_t idx = rowg * (size_t)N + colg;
        if constexpr (EPI == 0){
          ((u16*)C)[idx] = f2bf(v);
        } else if constexpr (EPI == 1){
          float s = v / (1.0f + __expf(-v));
          ((u16*)C)[idx] = f2bf(s);
        } else if constexpr (EPI == 2){
          float a = bf2f(((const u16*)aux)[idx]);
          ((u16*)C)[idx] = f2bf(v * a);
        } else {
          float a = ((const float*)aux)[idx];
          float b2 = bf2f(((const u16*)aux2)[idx]);
          ((float*)C)[idx] = v + a + b2;
        }
      }
}

// ---------------- causal flash attention (swapped QK^T, V^T input) ----------
// longest-first grid: qt = 31 - (bid>>6), (b,h) = bid&63
__global__ __launch_bounds__(256) void attn_k(const u16* __restrict__ Q,
                                              const u16* __restrict__ K,
                                              const u16* __restrict__ VT,
                                              u16* __restrict__ O){
  __shared__ __align__(16) u16 sK[32*128];
  __shared__ __align__(16) u16 sVT[128*32];
  int tid = threadIdx.x, lane = tid & 63, wave = tid >> 6;
  int bid = blockIdx.x;
  int qt = 31 - (bid >> 6);
  int bh = bid & 63; int b = bh >> 4, h = bh & 15;
  int l15 = lane & 15, l4 = lane >> 4;
  size_t base = ((size_t)b*2048)*2048 + (size_t)h*128;
  const u16* VTg0 = VT + ((size_t)h*128)*8192 + (size_t)b*2048;
  int qr0 = qt*64 + wave*16;
  int qrow = qr0 + l15;                       // this lane's single q row
  bf16x8_t qf[4];
  #pragma unroll
  for (int s=0;s<4;s++)
    qf[s] = *(const bf16x8_t*)(Q + base + (size_t)qrow*2048 + s*32 + l4*8);

  f32x4_t oaccT[8];                           // O^T: d = f*16 + l4*4 + r, q = l15
  #pragma unroll
  for (int f=0;f<8;f++) oaccT[f] = (f32x4_t){0.f,0.f,0.f,0.f};
  float mrun = -1e30f, lrun = 0.f;

  const float scale = 0.08838834764831845f;   // 1/sqrt(128)
  int nkt = (qt + 1) * 2;
  for (int kt=0; kt<nkt; ++kt){
    __syncthreads();          // prior tile's LDS reads done
    const u16* Kg = K + base + (size_t)kt*32*2048;
    #pragma unroll
    for (int i=0;i<2;i++){
      int c = i*256 + tid; int row = c>>4;
      gl16(Kg + (size_t)row*2048 + (size_t)(((c&15) ^ (row&7))*8), &sK[c*8]);
    }
    #pragma unroll
    for (int i=0;i<2;i++){
      int c = i*256 + tid; int d = c>>2;
      gl16(VTg0 + (size_t)d*8192 + kt*32 + (size_t)((((c&3) ^ ((d>>1)&3)))*8),
           &sVT[c*8]);
    }
    __syncthreads();          // staged data visible

    if (kt*32 <= qr0 + 15){   // wave-uniform skip of fully-masked tiles
      f32x4_t sacc[2];
      sacc[0] = (f32x4_t){0.f,0.f,0.f,0.f};
      sacc[1] = (f32x4_t){0.f,0.f,0.f,0.f};
      __builtin_amdgcn_s_setprio(1);
      #pragma unroll
      for (int n=0;n<2;n++)
        #pragma unroll
        for (int s=0;s<4;s++){
          bf16x8_t kf = *(const bf16x8_t*)
              &sK[(n*16 + l15)*128 + (((s*4 + l4) ^ (l15 & 7))*8)];
          sacc[n] = __builtin_amdgcn_mfma_f32_16x16x32_bf16(kf, qf[s], sacc[n], 0,0,0);
        }
      __builtin_amdgcn_s_setprio(0);
      float pv[8];
      float mloc = -1e30f;
      #pragma unroll
      for (int n=0;n<2;n++)
        #pragma unroll
        for (int r=0;r<4;r++){
          int kg = kt*32 + n*16 + l4*4 + r;
          float v = sacc[n][r] * scale;
          if (kg > qrow) v = -1e30f;
          pv[n*4+r] = v;
          mloc = fmaxf(mloc, v);
        }
      mloc = fmaxf(mloc, __shfl_xor(mloc, 16, 64));
      mloc = fmaxf(mloc, __shfl_xor(mloc, 32, 64));
      float mnew = fmaxf(mrun, mloc);
      float fr = __expf(mrun - mnew);
      mrun = mnew;
      float sloc = 0.f;
      bf16x8_t pa;
      #pragma unroll
      for (int j=0;j<8;j++){
        float p = __expf(pv[j] - mnew);
        sloc += p;
        pa[j] = (short)f2bf(p);
      }
      sloc += __shfl_xor(sloc, 16, 64);
      sloc += __shfl_xor(sloc, 32, 64);
      lrun = lrun * fr + sloc;
      #pragma unroll
      for (int f=0;f<8;f++){
        oaccT[f][0] *= fr; oaccT[f][1] *= fr; oaccT[f][2] *= fr; oaccT[f][3] *= fr;
      }
      __builtin_amdgcn_s_setprio(1);
      #pragma unroll
      for (int f=0;f<8;f++){
        int d = f*16 + l15;
        bf16x4_t lo = *(const bf16x4_t*)&sVT[d*32 + (((0*4 + l4) ^ (d & 6))*4)];
        bf16x4_t hi = *(const bf16x4_t*)&sVT[d*32 + (((1*4 + l4) ^ (d & 6))*4)];
        bf16x8_t va;
        va[0]=lo[0]; va[1]=lo[1]; va[2]=lo[2]; va[3]=lo[3];
        va[4]=hi[0]; va[5]=hi[1]; va[6]=hi[2]; va[7]=hi[3];
        oaccT[f] = __builtin_amdgcn_mfma_f32_16x16x32_bf16(va, pa, oaccT[f], 0,0,0);
      }
      __builtin_amdgcn_s_setprio(0);
    }
  }
  float inv = 1.0f / lrun;
  size_t orow = (size_t)b*2048 + qrow;
  #pragma unroll
  for (int f=0;f<8;f++){
    bf16x4_t ov;
    ov[0]=(short)f2bf(oaccT[f][0]*inv); ov[1]=(short)f2bf(oaccT[f][1]*inv);
    ov[2]=(short)f2bf(oaccT[f][2]*inv); ov[3]=(short)f2bf(oaccT[f][3]*inv);
    *(bf16x4_t*)(O + orow*2048 + h*128 + f*16 + l4*4) = ov;
  }
}

// ---------------- host ----------------
extern "C" void kernel_launch(void* const* d_in, const int* in_sizes, int n_in,
                              void* d_out, int out_size, void* d_ws, size_t ws_size,
                              hipStream_t stream){
  (void)in_sizes; (void)n_in; (void)out_size; (void)ws_size;
  const float* x   = (const float*)d_in[0];
  const float* fc  = (const float*)d_in[1];
  const float* fs  = (const float*)d_in[2];
  const float* wq  = (const float*)d_in[4];
  const float* wk  = (const float*)d_in[5];
  const float* wv  = (const float*)d_in[6];
  const float* wo  = (const float*)d_in[7];
  const float* w1  = (const float*)d_in[8];
  const float* w2  = (const float*)d_in[9];
  const float* w3  = (const float*)d_in[10];
  const float* anw = (const float*)d_in[11];
  const float* fnw = (const float*)d_in[12];
  float* out = (float*)d_out;
  char* ws = (char*)d_ws;

  const int M = 8192, D = 2048, HID = 5632;
  const size_t WB   = 23068672ull;   // 5632*2048*2 (reused weight buf)
  const size_t ACT2 = 33554432ull;   // 8192*2048*2

  u16* wbuf = (u16*)(ws);
  u16* xa   = (u16*)(ws + WB);                // rmsnorm(x); later attn O
  u16* qb   = (u16*)(ws + WB + ACT2);         // Q; later t1 = o@wo^T
  u16* kb   = (u16*)(ws + WB + 2*ACT2);       // K; later hf
  u16* vb   = (u16*)(ws + WB + 3*ACT2);       // V
  u16* g1   = (u16*)(ws + WB + 4*ACT2);       // VT (32MB) then g1 (88 MiB)
  u16* vt = g1;
  u16* t1 = qb;
  u16* hf = kb;

  rmsnorm_k<<<M, 256, 0, stream>>>(x, anw, xa);

  cvt_k<<<D*D/8/256, 256, 0, stream>>>(wq, wbuf, D*D/8);
  gemm_bt<0><<<(M/256)*(D/256), 512, 0, stream>>>(xa, wbuf, qb, nullptr, nullptr, M, D, D);
  cvt_k<<<D*D/8/256, 256, 0, stream>>>(wk, wbuf, D*D/8);
  gemm_bt<0><<<(M/256)*(D/256), 512, 0, stream>>>(xa, wbuf, kb, nullptr, nullptr, M, D, D);
  cvt_k<<<D*D/8/256, 256, 0, stream>>>(wv, wbuf, D*D/8);
  gemm_bt<0><<<(M/256)*(D/256), 512, 0, stream>>>(xa, wbuf, vb, nullptr, nullptr, M, D, D);

  rope_k<<<32768, 256, 0, stream>>>(qb, kb, fc, fs);
  transpose_k<<<4096, 256, 0, stream>>>(vb, vt);      // V[8192][2048] -> VT[2048][8192]

  attn_k<<<2048, 256, 0, stream>>>(qb, kb, vt, xa);   // O -> xa

  cvt_k<<<D*D/8/256, 256, 0, stream>>>(wo, wbuf, D*D/8);
  gemm_bt<0><<<(M/256)*(D/256), 512, 0, stream>>>(xa, wbuf, t1, nullptr, nullptr, M, D, D);

  rmsnorm2_k<<<M, 256, 0, stream>>>(x, t1, fnw, hf);

  cvt_k<<<HID*D/8/256, 256, 0, stream>>>(w1, wbuf, HID*D/8);
  gemm_bt<1><<<(M/256)*(HID/256), 512, 0, stream>>>(hf, wbuf, g1, nullptr, nullptr, M, HID, D);
  cvt_k<<<HID*D/8/256, 256, 0, stream>>>(w3, wbuf, HID*D/8);
  gemm_bt<2><<<(M/256)*(HID/256), 512, 0, stream>>>(hf, wbuf, g1, g1, nullptr, M, HID, D);
  cvt_k<<<HID*D/8/256, 256, 0, stream>>>(w2, wbuf, HID*D/8);
  gemm_bt<4><<<(M/256)*(D/256), 512, 0, stream>>>(g1, wbuf, out, x, t1, M, D, HID);
}

// Round 8
// 1293.802 us; speedup vs baseline: 1.7696x; 1.0187x over previous
//
#include <hip/hip_runtime.h>
#include <hip/hip_bf16.h>
#include <stdint.h>

typedef short  bf16x8_t __attribute__((ext_vector_type(8)));
typedef short  bf16x4_t __attribute__((ext_vector_type(4)));
typedef float  f32x4_t  __attribute__((ext_vector_type(4)));
typedef unsigned short u16;
typedef unsigned int   u32;

#define DEV __device__ __forceinline__

DEV u16 f2bf(float f){
  u32 u = __float_as_uint(f);
  u += 0x7fffu + ((u >> 16) & 1u);     // RNE
  return (u16)(u >> 16);
}
DEV float bf2f(u16 h){ return __uint_as_float(((u32)h) << 16); }

DEV void gl16(const void* g, void* l){
  __builtin_amdgcn_global_load_lds(
      (const __attribute__((address_space(1))) void*)g,
      (__attribute__((address_space(3))) void*)l, 16, 0, 0);
}

#define SB0() __builtin_amdgcn_sched_barrier(0)
#define BARF() do{ SB0(); __builtin_amdgcn_s_barrier(); SB0(); }while(0)

// ---------------- f32 -> bf16 convert (8 elems/thread) ----------------
__global__ __launch_bounds__(256) void cvt_k(const float* __restrict__ in,
                                             u16* __restrict__ out, int n8){
  int i = blockIdx.x * 256 + threadIdx.x;
  if (i >= n8) return;
  const float4* p = (const float4*)in;
  float4 a = p[(size_t)i*2], b = p[(size_t)i*2+1];
  bf16x8_t o;
  o[0]=(short)f2bf(a.x); o[1]=(short)f2bf(a.y); o[2]=(short)f2bf(a.z); o[3]=(short)f2bf(a.w);
  o[4]=(short)f2bf(b.x); o[5]=(short)f2bf(b.y); o[6]=(short)f2bf(b.z); o[7]=(short)f2bf(b.w);
  *(bf16x8_t*)(out + (size_t)i*8) = o;
}

// ---------------- RMSNorm: fp32 row (D=2048) -> bf16 ----------------
__global__ __launch_bounds__(256) void rmsnorm_k(const float* __restrict__ x,
                                                 const float* __restrict__ w,
                                                 u16* __restrict__ y){
  int row = blockIdx.x, t = threadIdx.x;
  const float4* xr = (const float4*)(x + (size_t)row*2048);
  float4 a = xr[t*2], b = xr[t*2+1];
  float ss = a.x*a.x+a.y*a.y+a.z*a.z+a.w*a.w + b.x*b.x+b.y*b.y+b.z*b.z+b.w*b.w;
  #pragma unroll
  for (int m = 32; m; m >>= 1) ss += __shfl_xor(ss, m, 64);
  __shared__ float red[4];
  if ((t & 63) == 0) red[t >> 6] = ss;
  __syncthreads();
  float tot = red[0]+red[1]+red[2]+red[3];
  float rs = rsqrtf(tot * (1.0f/2048.0f) + 1e-6f);
  const float4* wr = (const float4*)w;
  float4 wa = wr[t*2], wb = wr[t*2+1];
  bf16x8_t o;
  o[0]=(short)f2bf(a.x*rs*wa.x); o[1]=(short)f2bf(a.y*rs*wa.y);
  o[2]=(short)f2bf(a.z*rs*wa.z); o[3]=(short)f2bf(a.w*rs*wa.w);
  o[4]=(short)f2bf(b.x*rs*wb.x); o[5]=(short)f2bf(b.y*rs*wb.y);
  o[6]=(short)f2bf(b.z*rs*wb.z); o[7]=(short)f2bf(b.w*rs*wb.w);
  *(bf16x8_t*)(y + (size_t)row*2048 + t*8) = o;
}

// ---- RMSNorm2: h = x(f32) + t1(bf16); y = rmsnorm(h)*w -> bf16 ----
__global__ __launch_bounds__(256) void rmsnorm2_k(const float* __restrict__ x,
                                                  const u16* __restrict__ t1,
                                                  const float* __restrict__ w,
                                                  u16* __restrict__ y){
  int row = blockIdx.x, t = threadIdx.x;
  const float4* xr = (const float4*)(x + (size_t)row*2048);
  float4 a = xr[t*2], b = xr[t*2+1];
  bf16x8_t tv = *(const bf16x8_t*)(t1 + (size_t)row*2048 + t*8);
  float h[8];
  h[0]=a.x+bf2f((u16)tv[0]); h[1]=a.y+bf2f((u16)tv[1]);
  h[2]=a.z+bf2f((u16)tv[2]); h[3]=a.w+bf2f((u16)tv[3]);
  h[4]=b.x+bf2f((u16)tv[4]); h[5]=b.y+bf2f((u16)tv[5]);
  h[6]=b.z+bf2f((u16)tv[6]); h[7]=b.w+bf2f((u16)tv[7]);
  float ss = 0.f;
  #pragma unroll
  for (int j=0;j<8;j++) ss += h[j]*h[j];
  #pragma unroll
  for (int m = 32; m; m >>= 1) ss += __shfl_xor(ss, m, 64);
  __shared__ float red[4];
  if ((t & 63) == 0) red[t >> 6] = ss;
  __syncthreads();
  float tot = red[0]+red[1]+red[2]+red[3];
  float rs = rsqrtf(tot * (1.0f/2048.0f) + 1e-6f);
  const float4* wr = (const float4*)w;
  float4 wa = wr[t*2], wb = wr[t*2+1];
  bf16x8_t o;
  o[0]=(short)f2bf(h[0]*rs*wa.x); o[1]=(short)f2bf(h[1]*rs*wa.y);
  o[2]=(short)f2bf(h[2]*rs*wa.z); o[3]=(short)f2bf(h[3]*rs*wa.w);
  o[4]=(short)f2bf(h[4]*rs*wb.x); o[5]=(short)f2bf(h[5]*rs*wb.y);
  o[6]=(short)f2bf(h[6]*rs*wb.z); o[7]=(short)f2bf(h[7]*rs*wb.w);
  *(bf16x8_t*)(y + (size_t)row*2048 + t*8) = o;
}

// ---------------- RoPE in-place on q,k (bf16, B,S,H,HD) ----------------
__global__ __launch_bounds__(256) void rope_k(u16* __restrict__ q, u16* __restrict__ k,
                                              const float* __restrict__ fc,
                                              const float* __restrict__ fs){
  int i = blockIdx.x * 256 + threadIdx.x;
  int ii = i & 63; int h = (i >> 6) & 15; int bs = i >> 10;
  int s = bs & 2047;
  size_t off = (size_t)bs*2048 + h*128 + 2*ii;
  float c = fc[s*64+ii], sn = fs[s*64+ii];
  u32 qq = *(u32*)(q + off);
  float xr = bf2f((u16)(qq & 0xffff)), xi = bf2f((u16)(qq >> 16));
  *(u32*)(q + off) = (u32)f2bf(xr*c - xi*sn) | ((u32)f2bf(xr*sn + xi*c) << 16);
  u32 kk = *(u32*)(k + off);
  xr = bf2f((u16)(kk & 0xffff)); xi = bf2f((u16)(kk >> 16));
  *(u32*)(k + off) = (u32)f2bf(xr*c - xi*sn) | ((u32)f2bf(xr*sn + xi*c) << 16);
}

// ---------------- 2048x8192 transpose (V -> V^T), 64x64 tiles ----------------
__global__ __launch_bounds__(256) void transpose_k(const u16* __restrict__ in,
                                                   u16* __restrict__ out){
  __shared__ u16 tile[64*68];
  int tid = threadIdx.x;
  int tm = blockIdx.x >> 5, tn = blockIdx.x & 31;   // in: [8192][2048]
  const u16* src = in + (size_t)(tm*64)*2048 + tn*64;
  #pragma unroll
  for (int i=0;i<2;i++){
    int idx = i*256 + tid;
    int r = idx >> 3, c8 = (idx & 7)*8;
    *(bf16x8_t*)&tile[r*68 + c8] = *(const bf16x8_t*)(src + (size_t)r*2048 + c8);
  }
  __syncthreads();
  u16* dst = out + (size_t)(tn*64)*8192 + tm*64;
  #pragma unroll
  for (int i=0;i<2;i++){
    int idx = i*256 + tid;
    int oc = idx >> 3, r8 = (idx & 7)*8;
    bf16x8_t v;
    #pragma unroll
    for (int j=0;j<8;j++) v[j] = tile[(r8+j)*68 + oc];
    *(bf16x8_t*)(dst + (size_t)oc*8192 + r8) = v;
  }
}

// ---------------- GEMM: C(MxN) = A(MxK,bf16) * B(NxK,bf16)^T (+epilogue) ----
// 256x256 tile, BK=64, 8 waves (2M x 4N, 128x64/wave). Distance-2 pipeline:
// after S1 barrier read {q2,q3} frags, run q0,q1,q2; after S2 barrier read
// next tile's {q0,q1} frags, run q3. Stages: Kh1(T+1)@S1, Kh0(T+2)@S2;
// vmcnt(4) ledger. Swizzle: phys chunk = l4 ^ ((row>>1)&3) (0 conflicts).

DEV void stg(const u16* __restrict__ G, int K, u16* dst, int tid, int Toff){
  #pragma unroll
  for (int j=0;j<2;j++){
    int c = j*512 + tid;
    int row = c >> 2;
    int l = (c&3) ^ ((row>>1)&3);
    gl16(G + (size_t)row*K + Toff + l*8, dst + (size_t)c*8);
  }
}

DEV void rdA(const u16* base, int wm, int mh, int l15, int pc, bf16x8_t (&r)[4]){
  #pragma unroll
  for (int mi=0;mi<4;mi++){
    int R = wm*128 + mh*64 + mi*16 + l15;
    r[mi] = *(const bf16x8_t*)&base[R*32 + pc];
  }
}
DEV void rdB(const u16* base, int wn, int l15, int pc, bf16x8_t (&r)[4]){
  #pragma unroll
  for (int ni=0;ni<4;ni++){
    int R = wn*64 + ni*16 + l15;
    r[ni] = *(const bf16x8_t*)&base[R*32 + pc];
  }
}

template<int MH>
DEV void MM16(bf16x8_t (&a)[4], bf16x8_t (&b)[4], f32x4_t (&acc)[8][4]){
  __builtin_amdgcn_s_setprio(1);
  #pragma unroll
  for (int mi=0;mi<4;mi++)
    #pragma unroll
    for (int ni=0;ni<4;ni++)
      acc[MH*4+mi][ni] =
        __builtin_amdgcn_mfma_f32_16x16x32_bf16(a[mi], b[ni], acc[MH*4+mi][ni], 0,0,0);
  __builtin_amdgcn_s_setprio(0);
}

template<int EPI>
__global__ __launch_bounds__(512, 2) void gemm_bt(const u16* __restrict__ A,
                                                  const u16* __restrict__ B,
                                                  void* __restrict__ C,
                                                  const void* __restrict__ aux,
                                                  const void* __restrict__ aux2,
                                                  int M, int N, int K){
  __shared__ __align__(16) u16 sA[2*2*8192];   // [buf][kh][256 rows x 32] = 64KB
  __shared__ __align__(16) u16 sB[2*2*8192];   // 64KB
  int tid = threadIdx.x, lane = tid & 63, wave = tid >> 6;
  int l15 = lane & 15, l4 = lane >> 4;
  int pc = (l4 ^ ((l15 >> 1) & 3)) * 8;
  int nbn = N / 256;
  int nwg = gridDim.x, bid = blockIdx.x;
  int qq = nwg >> 3, rr = nwg & 7;
  int xc = bid & 7, yy = bid >> 3;
  int wg = (xc < rr ? xc*(qq+1) : rr*(qq+1) + (xc-rr)*qq) + yy;
  int tm = wg / nbn, tn = wg % nbn;
  size_t m0 = (size_t)tm*256, n0 = (size_t)tn*256;
  const u16* Ag = A + m0*K;
  const u16* Bg = B + n0*K;
  int wm = wave >> 2, wn = wave & 3;           // 2 x 4 wave grid

  f32x4_t acc[8][4];
  #pragma unroll
  for (int i=0;i<8;i++)
    #pragma unroll
    for (int j=0;j<4;j++)
      acc[i][j] = (f32x4_t){0.f,0.f,0.f,0.f};

  int nk = K / 64;
  // prologue: Kh0(0), Kh1(0), Kh0(1)
  stg(Ag, K, &sA[0],     tid, 0);  stg(Bg, K, &sB[0],     tid, 0);
  stg(Ag, K, &sA[8192],  tid, 32); stg(Bg, K, &sB[8192],  tid, 32);
  stg(Ag, K, &sA[16384], tid, 64); stg(Bg, K, &sB[16384], tid, 64);
  asm volatile("s_waitcnt vmcnt(8)" ::: "memory");
  BARF();
  bf16x8_t A0[4], A1[4], C0[4], D0[4], B0[4], B1[4];
  rdA(&sA[0], wm, 0, l15, pc, A0);             // q0/q1 frags, tile 0 (Kh0(0))
  rdB(&sB[0], wn, l15, pc, B0);
  rdA(&sA[0], wm, 1, l15, pc, A1);
  SB0();

  for (int T=0; T<nk; ++T){
    int cb = T & 1, nb = cb ^ 1;
    const u16* Ac1 = &sA[cb*16384 + 8192];
    const u16* Bc1 = &sB[cb*16384 + 8192];
    // ---- S1: Kh1(T) landed (vmcnt: newest 4 = Kh0(T+1) may fly)
    if (T < nk-1) asm volatile("s_waitcnt vmcnt(4)" ::: "memory");
    else          asm volatile("s_waitcnt vmcnt(0)" ::: "memory");
    BARF();
    if (T+1 < nk){
      stg(Ag, K, &sA[nb*16384 + 8192], tid, (T+1)*64 + 32);
      stg(Bg, K, &sB[nb*16384 + 8192], tid, (T+1)*64 + 32);
    }
    SB0();
    rdA(Ac1, wm, 0, l15, pc, C0);              // q2 frags (Kh1(T))
    rdB(Bc1, wn, l15, pc, B1);
    rdA(Ac1, wm, 1, l15, pc, D0);              // q3 frags
    SB0();
    MM16<0>(A0, B0, acc);                       // q0: mh0 x kk0
    MM16<1>(A1, B0, acc);                       // q1: mh1 x kk0
    MM16<0>(C0, B1, acc);                       // q2: mh0 x kk1
    // ---- S2: Kh0(T+1) landed (newest 4 = Kh1(T+1))
    if (T < nk-1) asm volatile("s_waitcnt vmcnt(4)" ::: "memory");
    else          asm volatile("s_waitcnt vmcnt(0)" ::: "memory");
    BARF();
    if (T+2 < nk){
      stg(Ag, K, &sA[cb*16384], tid, (T+2)*64);
      stg(Bg, K, &sB[cb*16384], tid, (T+2)*64);
    }
    SB0();
    if (T+1 < nk){                              // next-tile q0/q1 frags (Kh0(T+1))
      rdA(&sA[nb*16384], wm, 0, l15, pc, A0);
      rdB(&sB[nb*16384], wn, l15, pc, B0);
      rdA(&sA[nb*16384], wm, 1, l15, pc, A1);
    }
    SB0();
    MM16<1>(D0, B1, acc);                       // q3: mh1 x kk1
  }

  #pragma unroll
  for (int am=0; am<8; am++)
    #pragma unroll
    for (int ni=0; ni<4; ni++)
      #pragma unroll
      for (int r=0; r<4; r++){
        float v = acc[am][ni][r];
        size_t rowg = m0 + (am&3)*16 + (am>>2)*64 + wm*128 + l4*4 + r;
        size_t colg = n0 + wn*64 + ni*16 + l15;
        size_t idx = rowg * (size_t)N + colg;
        if constexpr (EPI == 0){
          ((u16*)C)[idx] = f2bf(v);
        } else if constexpr (EPI == 1){
          float s = v / (1.0f + __expf(-v));
          ((u16*)C)[idx] = f2bf(s);
        } else if constexpr (EPI == 2){
          float a = bf2f(((const u16*)aux)[idx]);
          ((u16*)C)[idx] = f2bf(v * a);
        } else {
          float a = ((const float*)aux)[idx];
          float b2 = bf2f(((const u16*)aux2)[idx]);
          ((float*)C)[idx] = v + a + b2;
        }
      }
}

// ---------------- causal flash attention (swapped QK^T, V^T input) ----------
// Fixed-reference softmax: |s| <= |q||k|/sqrt(128) ~ 10 (hard bound ~25),
// exp2 overflow at 128 -> p = exp2(s*c) safe in f32; no running max/rescale.
// longest-first grid: qt = 31 - (bid>>6), (b,h) = bid&63
__global__ __launch_bounds__(256) void attn_k(const u16* __restrict__ Q,
                                              const u16* __restrict__ K,
                                              const u16* __restrict__ VT,
                                              u16* __restrict__ O){
  __shared__ __align__(16) u16 sK[32*128];
  __shared__ __align__(16) u16 sVT[128*32];
  int tid = threadIdx.x, lane = tid & 63, wave = tid >> 6;
  int bid = blockIdx.x;
  int qt = 31 - (bid >> 6);
  int bh = bid & 63; int b = bh >> 4, h = bh & 15;
  int l15 = lane & 15, l4 = lane >> 4;
  size_t base = ((size_t)b*2048)*2048 + (size_t)h*128;
  const u16* VTg0 = VT + ((size_t)h*128)*8192 + (size_t)b*2048;
  int qr0 = qt*64 + wave*16;
  int qrow = qr0 + l15;                       // this lane's single q row
  bf16x8_t qf[4];
  #pragma unroll
  for (int s=0;s<4;s++)
    qf[s] = *(const bf16x8_t*)(Q + base + (size_t)qrow*2048 + s*32 + l4*8);

  f32x4_t oaccT[8];                           // O^T: d = f*16 + l4*4 + r, q = l15
  #pragma unroll
  for (int f=0;f<8;f++) oaccT[f] = (f32x4_t){0.f,0.f,0.f,0.f};
  float lrun = 0.f;

  const float cl2 = 0.08838834764831845f * 1.4426950408889634f; // scale*log2e
  int nkt = (qt + 1) * 2;
  for (int kt=0; kt<nkt; ++kt){
    __syncthreads();          // prior tile's LDS reads done
    const u16* Kg = K + base + (size_t)kt*32*2048;
    #pragma unroll
    for (int i=0;i<2;i++){
      int c = i*256 + tid; int row = c>>4;
      gl16(Kg + (size_t)row*2048 + (size_t)(((c&15) ^ (row&7))*8), &sK[c*8]);
    }
    #pragma unroll
    for (int i=0;i<2;i++){
      int c = i*256 + tid; int d = c>>2;
      gl16(VTg0 + (size_t)d*8192 + kt*32 + (size_t)((((c&3) ^ ((d>>1)&3)))*8),
           &sVT[c*8]);
    }
    __syncthreads();          // staged data visible

    if (kt*32 <= qr0 + 15){   // wave-uniform skip of fully-masked tiles
      f32x4_t sacc[2];
      sacc[0] = (f32x4_t){0.f,0.f,0.f,0.f};
      sacc[1] = (f32x4_t){0.f,0.f,0.f,0.f};
      __builtin_amdgcn_s_setprio(1);
      #pragma unroll
      for (int n=0;n<2;n++)
        #pragma unroll
        for (int s=0;s<4;s++){
          bf16x8_t kf = *(const bf16x8_t*)
              &sK[(n*16 + l15)*128 + (((s*4 + l4) ^ (l15 & 7))*8)];
          sacc[n] = __builtin_amdgcn_mfma_f32_16x16x32_bf16(kf, qf[s], sacc[n], 0,0,0);
        }
      __builtin_amdgcn_s_setprio(0);
      float sum = 0.f;
      bf16x8_t pa;
      bool diag = (kt*32 + 31 > qr0);         // wave-uniform
      if (diag){
        #pragma unroll
        for (int j=0;j<8;j++){
          int n = j>>2, r = j&3;
          float p = exp2f(sacc[n][r] * cl2);
          int kg = kt*32 + n*16 + l4*4 + r;
          if (kg > qrow) p = 0.f;
          sum += p;
          pa[j] = (short)f2bf(p);
        }
      } else {
        #pragma unroll
        for (int j=0;j<8;j++){
          float p = exp2f(sacc[j>>2][j&3] * cl2);
          sum += p;
          pa[j] = (short)f2bf(p);
        }
      }
      sum += __shfl_xor(sum, 16, 64);
      sum += __shfl_xor(sum, 32, 64);
      lrun += sum;
      __builtin_amdgcn_s_setprio(1);
      #pragma unroll
      for (int f=0;f<8;f++){
        int d = f*16 + l15;
        bf16x4_t lo = *(const bf16x4_t*)&sVT[d*32 + (((0*4 + l4) ^ (d & 6))*4)];
        bf16x4_t hi = *(const bf16x4_t*)&sVT[d*32 + (((1*4 + l4) ^ (d & 6))*4)];
        bf16x8_t va;
        va[0]=lo[0]; va[1]=lo[1]; va[2]=lo[2]; va[3]=lo[3];
        va[4]=hi[0]; va[5]=hi[1]; va[6]=hi[2]; va[7]=hi[3];
        oaccT[f] = __builtin_amdgcn_mfma_f32_16x16x32_bf16(va, pa, oaccT[f], 0,0,0);
      }
      __builtin_amdgcn_s_setprio(0);
    }
  }
  float inv = 1.0f / lrun;
  size_t orow = (size_t)b*2048 + qrow;
  #pragma unroll
  for (int f=0;f<8;f++){
    bf16x4_t ov;
    ov[0]=(short)f2bf(oaccT[f][0]*inv); ov[1]=(short)f2bf(oaccT[f][1]*inv);
    ov[2]=(short)f2bf(oaccT[f][2]*inv); ov[3]=(short)f2bf(oaccT[f][3]*inv);
    *(bf16x4_t*)(O + orow*2048 + h*128 + f*16 + l4*4) = ov;
  }
}

// ---------------- host ----------------
extern "C" void kernel_launch(void* const* d_in, const int* in_sizes, int n_in,
                              void* d_out, int out_size, void* d_ws, size_t ws_size,
                              hipStream_t stream){
  (void)in_sizes; (void)n_in; (void)out_size; (void)ws_size;
  const float* x   = (const float*)d_in[0];
  const float* fc  = (const float*)d_in[1];
  const float* fs  = (const float*)d_in[2];
  const float* wq  = (const float*)d_in[4];
  const float* wk  = (const float*)d_in[5];
  const float* wv  = (const float*)d_in[6];
  const float* wo  = (const float*)d_in[7];
  const float* w1  = (const float*)d_in[8];
  const float* w2  = (const float*)d_in[9];
  const float* w3  = (const float*)d_in[10];
  const float* anw = (const float*)d_in[11];
  const float* fnw = (const float*)d_in[12];
  float* out = (float*)d_out;
  char* ws = (char*)d_ws;

  const int M = 8192, D = 2048, HID = 5632;
  const size_t WB   = 23068672ull;   // 5632*2048*2 (reused weight buf)
  const size_t ACT2 = 33554432ull;   // 8192*2048*2

  u16* wbuf = (u16*)(ws);
  u16* xa   = (u16*)(ws + WB);                // rmsnorm(x); later attn O
  u16* qb   = (u16*)(ws + WB + ACT2);         // Q; later t1 = o@wo^T
  u16* kb   = (u16*)(ws + WB + 2*ACT2);       // K; later hf
  u16* vb   = (u16*)(ws + WB + 3*ACT2);       // V
  u16* g1   = (u16*)(ws + WB + 4*ACT2);       // VT (32MB) then g1 (88 MiB)
  u16* vt = g1;
  u16* t1 = qb;
  u16* hf = kb;

  rmsnorm_k<<<M, 256, 0, stream>>>(x, anw, xa);

  cvt_k<<<D*D/8/256, 256, 0, stream>>>(wq, wbuf, D*D/8);
  gemm_bt<0><<<(M/256)*(D/256), 512, 0, stream>>>(xa, wbuf, qb, nullptr, nullptr, M, D, D);
  cvt_k<<<D*D/8/256, 256, 0, stream>>>(wk, wbuf, D*D/8);
  gemm_bt<0><<<(M/256)*(D/256), 512, 0, stream>>>(xa, wbuf, kb, nullptr, nullptr, M, D, D);
  cvt_k<<<D*D/8/256, 256, 0, stream>>>(wv, wbuf, D*D/8);
  gemm_bt<0><<<(M/256)*(D/256), 512, 0, stream>>>(xa, wbuf, vb, nullptr, nullptr, M, D, D);

  rope_k<<<32768, 256, 0, stream>>>(qb, kb, fc, fs);
  transpose_k<<<4096, 256, 0, stream>>>(vb, vt);      // V[8192][2048] -> VT[2048][8192]

  attn_k<<<2048, 256, 0, stream>>>(qb, kb, vt, xa);   // O -> xa

  cvt_k<<<D*D/8/256, 256, 0, stream>>>(wo, wbuf, D*D/8);
  gemm_bt<0><<<(M/256)*(D/256), 512, 0, stream>>>(xa, wbuf, t1, nullptr, nullptr, M, D, D);

  rmsnorm2_k<<<M, 256, 0, stream>>>(x, t1, fnw, hf);

  cvt_k<<<HID*D/8/256, 256, 0, stream>>>(w1, wbuf, HID*D/8);
  gemm_bt<1><<<(M/256)*(HID/256), 512, 0, stream>>>(hf, wbuf, g1, nullptr, nullptr, M, HID, D);
  cvt_k<<<HID*D/8/256, 256, 0, stream>>>(w3, wbuf, HID*D/8);
  gemm_bt<2><<<(M/256)*(HID/256), 512, 0, stream>>>(hf, wbuf, g1, g1, nullptr, M, HID, D);
  cvt_k<<<HID*D/8/256, 256, 0, stream>>>(w2, wbuf, HID*D/8);
  gemm_bt<4><<<(M/256)*(D/256), 512, 0, stream>>>(g1, wbuf, out, x, t1, M, D, HID);
}

// Round 9
// 1137.764 us; speedup vs baseline: 2.0123x; 1.1371x over previous
//
#include <hip/hip_runtime.h>
#include <hip/hip_bf16.h>
#include <stdint.h>

typedef short  bf16x8_t __attribute__((ext_vector_type(8)));
typedef short  bf16x4_t __attribute__((ext_vector_type(4)));
typedef float  f32x4_t  __attribute__((ext_vector_type(4)));
typedef unsigned short u16;
typedef unsigned int   u32;

#define DEV __device__ __forceinline__

DEV u16 f2bf(float f){
  u32 u = __float_as_uint(f);
  u += 0x7fffu + ((u >> 16) & 1u);     // RNE
  return (u16)(u >> 16);
}
DEV float bf2f(u16 h){ return __uint_as_float(((u32)h) << 16); }

DEV void gl16(const void* g, void* l){
  __builtin_amdgcn_global_load_lds(
      (const __attribute__((address_space(1))) void*)g,
      (__attribute__((address_space(3))) void*)l, 16, 0, 0);
}

#define SB0() __builtin_amdgcn_sched_barrier(0)
#define BARF() do{ SB0(); __builtin_amdgcn_s_barrier(); SB0(); }while(0)
#define LGKM0() do{ asm volatile("s_waitcnt lgkmcnt(0)" ::: "memory"); SB0(); }while(0)

// ---------------- f32 -> bf16 convert (8 elems/thread) ----------------
__global__ __launch_bounds__(256) void cvt_k(const float* __restrict__ in,
                                             u16* __restrict__ out, int n8){
  int i = blockIdx.x * 256 + threadIdx.x;
  if (i >= n8) return;
  const float4* p = (const float4*)in;
  float4 a = p[(size_t)i*2], b = p[(size_t)i*2+1];
  bf16x8_t o;
  o[0]=(short)f2bf(a.x); o[1]=(short)f2bf(a.y); o[2]=(short)f2bf(a.z); o[3]=(short)f2bf(a.w);
  o[4]=(short)f2bf(b.x); o[5]=(short)f2bf(b.y); o[6]=(short)f2bf(b.z); o[7]=(short)f2bf(b.w);
  *(bf16x8_t*)(out + (size_t)i*8) = o;
}

// ---------------- RMSNorm: fp32 row (D=2048) -> bf16 ----------------
__global__ __launch_bounds__(256) void rmsnorm_k(const float* __restrict__ x,
                                                 const float* __restrict__ w,
                                                 u16* __restrict__ y){
  int row = blockIdx.x, t = threadIdx.x;
  const float4* xr = (const float4*)(x + (size_t)row*2048);
  float4 a = xr[t*2], b = xr[t*2+1];
  float ss = a.x*a.x+a.y*a.y+a.z*a.z+a.w*a.w + b.x*b.x+b.y*b.y+b.z*b.z+b.w*b.w;
  #pragma unroll
  for (int m = 32; m; m >>= 1) ss += __shfl_xor(ss, m, 64);
  __shared__ float red[4];
  if ((t & 63) == 0) red[t >> 6] = ss;
  __syncthreads();
  float tot = red[0]+red[1]+red[2]+red[3];
  float rs = rsqrtf(tot * (1.0f/2048.0f) + 1e-6f);
  const float4* wr = (const float4*)w;
  float4 wa = wr[t*2], wb = wr[t*2+1];
  bf16x8_t o;
  o[0]=(short)f2bf(a.x*rs*wa.x); o[1]=(short)f2bf(a.y*rs*wa.y);
  o[2]=(short)f2bf(a.z*rs*wa.z); o[3]=(short)f2bf(a.w*rs*wa.w);
  o[4]=(short)f2bf(b.x*rs*wb.x); o[5]=(short)f2bf(b.y*rs*wb.y);
  o[6]=(short)f2bf(b.z*rs*wb.z); o[7]=(short)f2bf(b.w*rs*wb.w);
  *(bf16x8_t*)(y + (size_t)row*2048 + t*8) = o;
}

// ---- RMSNorm2: h = x(f32) + t1(bf16); y = rmsnorm(h)*w -> bf16 ----
__global__ __launch_bounds__(256) void rmsnorm2_k(const float* __restrict__ x,
                                                  const u16* __restrict__ t1,
                                                  const float* __restrict__ w,
                                                  u16* __restrict__ y){
  int row = blockIdx.x, t = threadIdx.x;
  const float4* xr = (const float4*)(x + (size_t)row*2048);
  float4 a = xr[t*2], b = xr[t*2+1];
  bf16x8_t tv = *(const bf16x8_t*)(t1 + (size_t)row*2048 + t*8);
  float h[8];
  h[0]=a.x+bf2f((u16)tv[0]); h[1]=a.y+bf2f((u16)tv[1]);
  h[2]=a.z+bf2f((u16)tv[2]); h[3]=a.w+bf2f((u16)tv[3]);
  h[4]=b.x+bf2f((u16)tv[4]); h[5]=b.y+bf2f((u16)tv[5]);
  h[6]=b.z+bf2f((u16)tv[6]); h[7]=b.w+bf2f((u16)tv[7]);
  float ss = 0.f;
  #pragma unroll
  for (int j=0;j<8;j++) ss += h[j]*h[j];
  #pragma unroll
  for (int m = 32; m; m >>= 1) ss += __shfl_xor(ss, m, 64);
  __shared__ float red[4];
  if ((t & 63) == 0) red[t >> 6] = ss;
  __syncthreads();
  float tot = red[0]+red[1]+red[2]+red[3];
  float rs = rsqrtf(tot * (1.0f/2048.0f) + 1e-6f);
  const float4* wr = (const float4*)w;
  float4 wa = wr[t*2], wb = wr[t*2+1];
  bf16x8_t o;
  o[0]=(short)f2bf(h[0]*rs*wa.x); o[1]=(short)f2bf(h[1]*rs*wa.y);
  o[2]=(short)f2bf(h[2]*rs*wa.z); o[3]=(short)f2bf(h[3]*rs*wa.w);
  o[4]=(short)f2bf(h[4]*rs*wb.x); o[5]=(short)f2bf(h[5]*rs*wb.y);
  o[6]=(short)f2bf(h[6]*rs*wb.z); o[7]=(short)f2bf(h[7]*rs*wb.w);
  *(bf16x8_t*)(y + (size_t)row*2048 + t*8) = o;
}

// ---------------- RoPE in-place on q,k (bf16, B,S,H,HD) ----------------
__global__ __launch_bounds__(256) void rope_k(u16* __restrict__ q, u16* __restrict__ k,
                                              const float* __restrict__ fc,
                                              const float* __restrict__ fs){
  int i = blockIdx.x * 256 + threadIdx.x;
  int ii = i & 63; int h = (i >> 6) & 15; int bs = i >> 10;
  int s = bs & 2047;
  size_t off = (size_t)bs*2048 + h*128 + 2*ii;
  float c = fc[s*64+ii], sn = fs[s*64+ii];
  u32 qq = *(u32*)(q + off);
  float xr = bf2f((u16)(qq & 0xffff)), xi = bf2f((u16)(qq >> 16));
  *(u32*)(q + off) = (u32)f2bf(xr*c - xi*sn) | ((u32)f2bf(xr*sn + xi*c) << 16);
  u32 kk = *(u32*)(k + off);
  xr = bf2f((u16)(kk & 0xffff)); xi = bf2f((u16)(kk >> 16));
  *(u32*)(k + off) = (u32)f2bf(xr*c - xi*sn) | ((u32)f2bf(xr*sn + xi*c) << 16);
}

// ---------------- 2048x8192 transpose (V -> V^T), 64x64 tiles ----------------
__global__ __launch_bounds__(256) void transpose_k(const u16* __restrict__ in,
                                                   u16* __restrict__ out){
  __shared__ u16 tile[64*68];
  int tid = threadIdx.x;
  int tm = blockIdx.x >> 5, tn = blockIdx.x & 31;   // in: [8192][2048]
  const u16* src = in + (size_t)(tm*64)*2048 + tn*64;
  #pragma unroll
  for (int i=0;i<2;i++){
    int idx = i*256 + tid;
    int r = idx >> 3, c8 = (idx & 7)*8;
    *(bf16x8_t*)&tile[r*68 + c8] = *(const bf16x8_t*)(src + (size_t)r*2048 + c8);
  }
  __syncthreads();
  u16* dst = out + (size_t)(tn*64)*8192 + tm*64;
  #pragma unroll
  for (int i=0;i<2;i++){
    int idx = i*256 + tid;
    int oc = idx >> 3, r8 = (idx & 7)*8;
    bf16x8_t v;
    #pragma unroll
    for (int j=0;j<8;j++) v[j] = tile[(r8+j)*68 + oc];
    *(bf16x8_t*)(dst + (size_t)oc*8192 + r8) = v;
  }
}

// ---------------- GEMM: 256x256 tile, BK=64, m201-style 8-phase ----------
// 8 waves (2M x 4N; per-wave C 128x64). LDS [2 buf][2 half][128 x 64] A and B.
// Phase p: one 64x32 C-quadrant x K=64 (16 MFMA). p0-3: tile 2i (buf0);
// p4-7: tile 2i+1 (buf1). Stage 1 half-tile/phase (2 gl16/thread):
//  p0,p1: A(2i+1); p2,p3: B(2i+2); p4,p5: A(2i+2); p6,p7: B(2i+3).
// vmcnt(4) at p3,p7 only (FIFO: p3 => A(2i+1)+B(2i+1) landed; p7 => A,B(2i+2)).
// Tail: vmcnt(0) when the corresponding stages were skipped. Swizzle: 16B
// chunk ^ (row&7) within 8-chunk rows; linear gl16 dest, inverse-swz source.

DEV void stg(const u16* __restrict__ G, int K, u16* dst, int tid,
             int rowbase, int Tcol){
  #pragma unroll
  for (int j=0;j<2;j++){
    int c = j*512 + tid;              // 0..1023 chunks of the half-tile
    int row = c >> 3;                 // 0..127
    int lg = (c & 7) ^ (row & 7);     // source logical chunk
    gl16(G + (size_t)(rowbase + row)*K + Tcol + lg*8, dst + (size_t)c*8);
  }
}

DEV void rdA8(const u16* pane, int mh, int l15, int l4, bf16x8_t (&r)[4][2]){
  #pragma unroll
  for (int mi=0;mi<4;mi++)
    #pragma unroll
    for (int kk=0;kk<2;kk++){
      int row = mh*64 + mi*16 + l15;
      int ch = (kk*4 + l4) ^ (row & 7);
      r[mi][kk] = *(const bf16x8_t*)&pane[row*64 + ch*8];
    }
}
DEV void rdB4(const u16* pane, int nhl, int wn1, int l15, int l4, bf16x8_t (&r)[2][2]){
  #pragma unroll
  for (int nj=0;nj<2;nj++)
    #pragma unroll
    for (int kk=0;kk<2;kk++){
      int row = wn1*64 + (nhl*2+nj)*16 + l15;
      int ch = (kk*4 + l4) ^ (row & 7);
      r[nj][kk] = *(const bf16x8_t*)&pane[row*64 + ch*8];
    }
}

DEV void MMQ(bf16x8_t (&a)[4][2], bf16x8_t (&b)[2][2], int mh, int nhl,
             f32x4_t (&acc)[8][4]){
  __builtin_amdgcn_s_setprio(1);
  #pragma unroll
  for (int mi=0;mi<4;mi++)
    #pragma unroll
    for (int nj=0;nj<2;nj++)
      #pragma unroll
      for (int kk=0;kk<2;kk++)
        acc[mh*4+mi][nhl*2+nj] = __builtin_amdgcn_mfma_f32_16x16x32_bf16(
            a[mi][kk], b[nj][kk], acc[mh*4+mi][nhl*2+nj], 0,0,0);
  __builtin_amdgcn_s_setprio(0);
}

template<int EPI>
__global__ __launch_bounds__(512, 2) void gemm_bt(const u16* __restrict__ A,
                                                  const u16* __restrict__ B,
                                                  void* __restrict__ C,
                                                  const void* __restrict__ aux,
                                                  const void* __restrict__ aux2,
                                                  int M, int N, int K){
  __shared__ __align__(16) u16 sA[2][2][128*64];   // 64 KB
  __shared__ __align__(16) u16 sB[2][2][128*64];   // 64 KB
  int tid = threadIdx.x, lane = tid & 63, wave = tid >> 6;
  int l15 = lane & 15, l4 = lane >> 4;
  int nbn = N / 256;
  int nwg = gridDim.x, bid = blockIdx.x;
  int qq = nwg >> 3, rr = nwg & 7;
  int xc = bid & 7, yy = bid >> 3;
  int wg = (xc < rr ? xc*(qq+1) : rr*(qq+1) + (xc-rr)*qq) + yy;
  int tm = wg / nbn, tn = wg % nbn;
  size_t m0 = (size_t)tm*256, n0 = (size_t)tn*256;
  const u16* Ag = A + m0*K;
  const u16* Bg = B + n0*K;
  int wm = wave >> 2, wn = wave & 3;           // 2 x 4 wave grid
  int bh = wn >> 1, wn1 = wn & 1;              // B half, row-sub within half

  const u16* Ap0 = &sA[0][wm][0];  const u16* Ap1 = &sA[1][wm][0];
  const u16* Bp0 = &sB[0][bh][0];  const u16* Bp1 = &sB[1][bh][0];

  f32x4_t acc[8][4];
  #pragma unroll
  for (int i=0;i<8;i++)
    #pragma unroll
    for (int j=0;j<4;j++)
      acc[i][j] = (f32x4_t){0.f,0.f,0.f,0.f};

  bf16x8_t Ar[4][2], Br0[2][2], Br1[2][2];
  int nk = K / 64;

  // prologue: A(0), B(0) -> buf0 ; B(1) -> buf1   (12 loads/thread)
  stg(Ag, K, &sA[0][0][0], tid, 0,   0);
  stg(Ag, K, &sA[0][1][0], tid, 128, 0);
  stg(Bg, K, &sB[0][0][0], tid, 0,   0);
  stg(Bg, K, &sB[0][1][0], tid, 128, 0);
  stg(Bg, K, &sB[1][0][0], tid, 0,   64);
  stg(Bg, K, &sB[1][1][0], tid, 128, 64);
  asm volatile("s_waitcnt vmcnt(4)" ::: "memory");  // A(0),B(0) landed
  BARF();

  for (int i=0; i<nk/2; ++i){
    int T0 = 2*i;
    bool s2 = (T0+2 < nk), s3 = (T0+3 < nk);
    // ---- p0: tile T0, (mh0, ns0); stage A-h0(T0+1)
    rdA8(Ap0, 0, l15, l4, Ar);
    rdB4(Bp0, 0, wn1, l15, l4, Br0);
    stg(Ag, K, &sA[1][0][0], tid, 0, (T0+1)*64);
    BARF(); LGKM0();
    MMQ(Ar, Br0, 0, 0, acc);
    BARF();
    // ---- p1: (mh0, ns1); stage A-h1(T0+1)
    rdB4(Bp0, 1, wn1, l15, l4, Br1);
    stg(Ag, K, &sA[1][1][0], tid, 128, (T0+1)*64);
    BARF(); LGKM0();
    MMQ(Ar, Br1, 0, 1, acc);
    BARF();
    // ---- p2: (mh1, ns0); stage B-h0(T0+2)
    rdA8(Ap0, 1, l15, l4, Ar);
    if (s2) stg(Bg, K, &sB[0][0][0], tid, 0, (T0+2)*64);
    BARF(); LGKM0();
    MMQ(Ar, Br0, 1, 0, acc);
    BARF();
    // ---- p3: (mh1, ns1); stage B-h1(T0+2); vmcnt -> A(T0+1),B(T0+1) landed
    if (s2){
      stg(Bg, K, &sB[0][1][0], tid, 128, (T0+2)*64);
      asm volatile("s_waitcnt vmcnt(4)" ::: "memory");
    } else {
      asm volatile("s_waitcnt vmcnt(0)" ::: "memory");
    }
    BARF(); LGKM0();
    MMQ(Ar, Br1, 1, 1, acc);
    BARF();
    // ---- p4: tile T0+1, (mh0, ns0); stage A-h0(T0+2)
    rdA8(Ap1, 0, l15, l4, Ar);
    rdB4(Bp1, 0, wn1, l15, l4, Br0);
    if (s2) stg(Ag, K, &sA[0][0][0], tid, 0, (T0+2)*64);
    BARF(); LGKM0();
    MMQ(Ar, Br0, 0, 0, acc);
    BARF();
    // ---- p5: (mh0, ns1); stage A-h1(T0+2)
    rdB4(Bp1, 1, wn1, l15, l4, Br1);
    if (s2) stg(Ag, K, &sA[0][1][0], tid, 128, (T0+2)*64);
    BARF(); LGKM0();
    MMQ(Ar, Br1, 0, 1, acc);
    BARF();
    // ---- p6: (mh1, ns0); stage B-h0(T0+3)
    rdA8(Ap1, 1, l15, l4, Ar);
    if (s3) stg(Bg, K, &sB[1][0][0], tid, 0, (T0+3)*64);
    BARF(); LGKM0();
    MMQ(Ar, Br0, 1, 0, acc);
    BARF();
    // ---- p7: (mh1, ns1); stage B-h1(T0+3); vmcnt -> A(T0+2),B(T0+2) landed
    if (s3){
      stg(Bg, K, &sB[1][1][0], tid, 128, (T0+3)*64);
      asm volatile("s_waitcnt vmcnt(4)" ::: "memory");
    } else {
      asm volatile("s_waitcnt vmcnt(0)" ::: "memory");
    }
    BARF(); LGKM0();
    MMQ(Ar, Br1, 1, 1, acc);
    BARF();
  }

  #pragma unroll
  for (int am=0; am<8; am++)
    #pragma unroll
    for (int ni=0; ni<4; ni++)
      #pragma unroll
      for (int r=0; r<4; r++){
        float v = acc[am][ni][r];
        size_t rowg = m0 + (am&3)*16 + (am>>2)*64 + wm*128 + l4*4 + r;
        size_t colg = n0 + wn*64 + ni*16 + l15;
        size_t idx = rowg * (size_t)N + colg;
        if constexpr (EPI == 0){
          ((u16*)C)[idx] = f2bf(v);
        } else if constexpr (EPI == 1){
          float s = v / (1.0f + __expf(-v));
          ((u16*)C)[idx] = f2bf(s);
        } else if constexpr (EPI == 2){
          float a = bf2f(((const u16*)aux)[idx]);
          ((u16*)C)[idx] = f2bf(v * a);
        } else {
          float a = ((const float*)aux)[idx];
          float b2 = bf2f(((const u16*)aux2)[idx]);
          ((float*)C)[idx] = v + a + b2;
        }
      }
}

// ---------------- causal flash attention (swapped QK^T, V^T input) ----------
// Fixed-reference softmax (|s| bounded ~25 << exp2 overflow); longest-first.
__global__ __launch_bounds__(256) void attn_k(const u16* __restrict__ Q,
                                              const u16* __restrict__ K,
                                              const u16* __restrict__ VT,
                                              u16* __restrict__ O){
  __shared__ __align__(16) u16 sK[32*128];
  __shared__ __align__(16) u16 sVT[128*32];
  int tid = threadIdx.x, lane = tid & 63, wave = tid >> 6;
  int bid = blockIdx.x;
  int qt = 31 - (bid >> 6);
  int bh = bid & 63; int b = bh >> 4, h = bh & 15;
  int l15 = lane & 15, l4 = lane >> 4;
  size_t base = ((size_t)b*2048)*2048 + (size_t)h*128;
  const u16* VTg0 = VT + ((size_t)h*128)*8192 + (size_t)b*2048;
  int qr0 = qt*64 + wave*16;
  int qrow = qr0 + l15;                       // this lane's single q row
  bf16x8_t qf[4];
  #pragma unroll
  for (int s=0;s<4;s++)
    qf[s] = *(const bf16x8_t*)(Q + base + (size_t)qrow*2048 + s*32 + l4*8);

  f32x4_t oaccT[8];                           // O^T: d = f*16 + l4*4 + r, q = l15
  #pragma unroll
  for (int f=0;f<8;f++) oaccT[f] = (f32x4_t){0.f,0.f,0.f,0.f};
  float lrun = 0.f;

  const float cl2 = 0.08838834764831845f * 1.4426950408889634f; // scale*log2e
  int nkt = (qt + 1) * 2;
  for (int kt=0; kt<nkt; ++kt){
    __syncthreads();          // prior tile's LDS reads done
    const u16* Kg = K + base + (size_t)kt*32*2048;
    #pragma unroll
    for (int i=0;i<2;i++){
      int c = i*256 + tid; int row = c>>4;
      gl16(Kg + (size_t)row*2048 + (size_t)(((c&15) ^ (row&7))*8), &sK[c*8]);
    }
    #pragma unroll
    for (int i=0;i<2;i++){
      int c = i*256 + tid; int d = c>>2;
      gl16(VTg0 + (size_t)d*8192 + kt*32 + (size_t)((((c&3) ^ ((d>>1)&3)))*8),
           &sVT[c*8]);
    }
    __syncthreads();          // staged data visible

    if (kt*32 <= qr0 + 15){   // wave-uniform skip of fully-masked tiles
      f32x4_t sacc[2];
      sacc[0] = (f32x4_t){0.f,0.f,0.f,0.f};
      sacc[1] = (f32x4_t){0.f,0.f,0.f,0.f};
      __builtin_amdgcn_s_setprio(1);
      #pragma unroll
      for (int n=0;n<2;n++)
        #pragma unroll
        for (int s=0;s<4;s++){
          bf16x8_t kf = *(const bf16x8_t*)
              &sK[(n*16 + l15)*128 + (((s*4 + l4) ^ (l15 & 7))*8)];
          sacc[n] = __builtin_amdgcn_mfma_f32_16x16x32_bf16(kf, qf[s], sacc[n], 0,0,0);
        }
      __builtin_amdgcn_s_setprio(0);
      float sum = 0.f;
      bf16x8_t pa;
      bool diag = (kt*32 + 31 > qr0);         // wave-uniform
      if (diag){
        #pragma unroll
        for (int j=0;j<8;j++){
          int n = j>>2, r = j&3;
          float p = exp2f(sacc[n][r] * cl2);
          int kg = kt*32 + n*16 + l4*4 + r;
          if (kg > qrow) p = 0.f;
          sum += p;
          pa[j] = (short)f2bf(p);
        }
      } else {
        #pragma unroll
        for (int j=0;j<8;j++){
          float p = exp2f(sacc[j>>2][j&3] * cl2);
          sum += p;
          pa[j] = (short)f2bf(p);
        }
      }
      sum += __shfl_xor(sum, 16, 64);
      sum += __shfl_xor(sum, 32, 64);
      lrun += sum;
      __builtin_amdgcn_s_setprio(1);
      #pragma unroll
      for (int f=0;f<8;f++){
        int d = f*16 + l15;
        bf16x4_t lo = *(const bf16x4_t*)&sVT[d*32 + (((0*4 + l4) ^ (d & 6))*4)];
        bf16x4_t hi = *(const bf16x4_t*)&sVT[d*32 + (((1*4 + l4) ^ (d & 6))*4)];
        bf16x8_t va;
        va[0]=lo[0]; va[1]=lo[1]; va[2]=lo[2]; va[3]=lo[3];
        va[4]=hi[0]; va[5]=hi[1]; va[6]=hi[2]; va[7]=hi[3];
        oaccT[f] = __builtin_amdgcn_mfma_f32_16x16x32_bf16(va, pa, oaccT[f], 0,0,0);
      }
      __builtin_amdgcn_s_setprio(0);
    }
  }
  float inv = 1.0f / lrun;
  size_t orow = (size_t)b*2048 + qrow;
  #pragma unroll
  for (int f=0;f<8;f++){
    bf16x4_t ov;
    ov[0]=(short)f2bf(oaccT[f][0]*inv); ov[1]=(short)f2bf(oaccT[f][1]*inv);
    ov[2]=(short)f2bf(oaccT[f][2]*inv); ov[3]=(short)f2bf(oaccT[f][3]*inv);
    *(bf16x4_t*)(O + orow*2048 + h*128 + f*16 + l4*4) = ov;
  }
}

// ---------------- host ----------------
extern "C" void kernel_launch(void* const* d_in, const int* in_sizes, int n_in,
                              void* d_out, int out_size, void* d_ws, size_t ws_size,
                              hipStream_t stream){
  (void)in_sizes; (void)n_in; (void)out_size; (void)ws_size;
  const float* x   = (const float*)d_in[0];
  const float* fc  = (const float*)d_in[1];
  const float* fs  = (const float*)d_in[2];
  const float* wq  = (const float*)d_in[4];
  const float* wk  = (const float*)d_in[5];
  const float* wv  = (const float*)d_in[6];
  const float* wo  = (const float*)d_in[7];
  const float* w1  = (const float*)d_in[8];
  const float* w2  = (const float*)d_in[9];
  const float* w3  = (const float*)d_in[10];
  const float* anw = (const float*)d_in[11];
  const float* fnw = (const float*)d_in[12];
  float* out = (float*)d_out;
  char* ws = (char*)d_ws;

  const int M = 8192, D = 2048, HID = 5632;
  const size_t WB   = 23068672ull;   // 5632*2048*2 (reused weight buf)
  const size_t ACT2 = 33554432ull;   // 8192*2048*2

  u16* wbuf = (u16*)(ws);
  u16* xa   = (u16*)(ws + WB);                // rmsnorm(x); later attn O
  u16* qb   = (u16*)(ws + WB + ACT2);         // Q; later t1 = o@wo^T
  u16* kb   = (u16*)(ws + WB + 2*ACT2);       // K; later hf
  u16* vb   = (u16*)(ws + WB + 3*ACT2);       // V
  u16* g1   = (u16*)(ws + WB + 4*ACT2);       // VT (32MB) then g1 (88 MiB)
  u16* vt = g1;
  u16* t1 = qb;
  u16* hf = kb;

  rmsnorm_k<<<M, 256, 0, stream>>>(x, anw, xa);

  cvt_k<<<D*D/8/256, 256, 0, stream>>>(wq, wbuf, D*D/8);
  gemm_bt<0><<<(M/256)*(D/256), 512, 0, stream>>>(xa, wbuf, qb, nullptr, nullptr, M, D, D);
  cvt_k<<<D*D/8/256, 256, 0, stream>>>(wk, wbuf, D*D/8);
  gemm_bt<0><<<(M/256)*(D/256), 512, 0, stream>>>(xa, wbuf, kb, nullptr, nullptr, M, D, D);
  cvt_k<<<D*D/8/256, 256, 0, stream>>>(wv, wbuf, D*D/8);
  gemm_bt<0><<<(M/256)*(D/256), 512, 0, stream>>>(xa, wbuf, vb, nullptr, nullptr, M, D, D);

  rope_k<<<32768, 256, 0, stream>>>(qb, kb, fc, fs);
  transpose_k<<<4096, 256, 0, stream>>>(vb, vt);      // V[8192][2048] -> VT[2048][8192]

  attn_k<<<2048, 256, 0, stream>>>(qb, kb, vt, xa);   // O -> xa

  cvt_k<<<D*D/8/256, 256, 0, stream>>>(wo, wbuf, D*D/8);
  gemm_bt<0><<<(M/256)*(D/256), 512, 0, stream>>>(xa, wbuf, t1, nullptr, nullptr, M, D, D);

  rmsnorm2_k<<<M, 256, 0, stream>>>(x, t1, fnw, hf);

  cvt_k<<<HID*D/8/256, 256, 0, stream>>>(w1, wbuf, HID*D/8);
  gemm_bt<1><<<(M/256)*(HID/256), 512, 0, stream>>>(hf, wbuf, g1, nullptr, nullptr, M, HID, D);
  cvt_k<<<HID*D/8/256, 256, 0, stream>>>(w3, wbuf, HID*D/8);
  gemm_bt<2><<<(M/256)*(HID/256), 512, 0, stream>>>(hf, wbuf, g1, g1, nullptr, M, HID, D);
  cvt_k<<<HID*D/8/256, 256, 0, stream>>>(w2, wbuf, HID*D/8);
  gemm_bt<4><<<(M/256)*(D/256), 512, 0, stream>>>(g1, wbuf, out, x, t1, M, D, HID);
}

// Round 10
// 1117.124 us; speedup vs baseline: 2.0495x; 1.0185x over previous
//
#include <hip/hip_runtime.h>
#include <hip/hip_bf16.h>
#include <stdint.h>

typedef short  bf16x8_t __attribute__((ext_vector_type(8)));
typedef short  bf16x4_t __attribute__((ext_vector_type(4)));
typedef float  f32x4_t  __attribute__((ext_vector_type(4)));
typedef unsigned short u16;
typedef unsigned int   u32;

#define DEV __device__ __forceinline__

DEV u16 f2bf(float f){
  u32 u = __float_as_uint(f);
  u += 0x7fffu + ((u >> 16) & 1u);     // RNE
  return (u16)(u >> 16);
}
DEV float bf2f(u16 h){ return __uint_as_float(((u32)h) << 16); }

DEV void gl16(const void* g, void* l){
  __builtin_amdgcn_global_load_lds(
      (const __attribute__((address_space(1))) void*)g,
      (__attribute__((address_space(3))) void*)l, 16, 0, 0);
}

#define SB0() __builtin_amdgcn_sched_barrier(0)
#define BARF() do{ SB0(); __builtin_amdgcn_s_barrier(); SB0(); }while(0)
#define LGKM0() do{ asm volatile("s_waitcnt lgkmcnt(0)" ::: "memory"); SB0(); }while(0)

// ---------------- f32 -> bf16 convert (8 elems/thread) ----------------
__global__ __launch_bounds__(256) void cvt_k(const float* __restrict__ in,
                                             u16* __restrict__ out, int n8){
  int i = blockIdx.x * 256 + threadIdx.x;
  if (i >= n8) return;
  const float4* p = (const float4*)in;
  float4 a = p[(size_t)i*2], b = p[(size_t)i*2+1];
  bf16x8_t o;
  o[0]=(short)f2bf(a.x); o[1]=(short)f2bf(a.y); o[2]=(short)f2bf(a.z); o[3]=(short)f2bf(a.w);
  o[4]=(short)f2bf(b.x); o[5]=(short)f2bf(b.y); o[6]=(short)f2bf(b.z); o[7]=(short)f2bf(b.w);
  *(bf16x8_t*)(out + (size_t)i*8) = o;
}

// ---------------- RMSNorm: fp32 row (D=2048) -> bf16 ----------------
__global__ __launch_bounds__(256) void rmsnorm_k(const float* __restrict__ x,
                                                 const float* __restrict__ w,
                                                 u16* __restrict__ y){
  int row = blockIdx.x, t = threadIdx.x;
  const float4* xr = (const float4*)(x + (size_t)row*2048);
  float4 a = xr[t*2], b = xr[t*2+1];
  float ss = a.x*a.x+a.y*a.y+a.z*a.z+a.w*a.w + b.x*b.x+b.y*b.y+b.z*b.z+b.w*b.w;
  #pragma unroll
  for (int m = 32; m; m >>= 1) ss += __shfl_xor(ss, m, 64);
  __shared__ float red[4];
  if ((t & 63) == 0) red[t >> 6] = ss;
  __syncthreads();
  float tot = red[0]+red[1]+red[2]+red[3];
  float rs = rsqrtf(tot * (1.0f/2048.0f) + 1e-6f);
  const float4* wr = (const float4*)w;
  float4 wa = wr[t*2], wb = wr[t*2+1];
  bf16x8_t o;
  o[0]=(short)f2bf(a.x*rs*wa.x); o[1]=(short)f2bf(a.y*rs*wa.y);
  o[2]=(short)f2bf(a.z*rs*wa.z); o[3]=(short)f2bf(a.w*rs*wa.w);
  o[4]=(short)f2bf(b.x*rs*wb.x); o[5]=(short)f2bf(b.y*rs*wb.y);
  o[6]=(short)f2bf(b.z*rs*wb.z); o[7]=(short)f2bf(b.w*rs*wb.w);
  *(bf16x8_t*)(y + (size_t)row*2048 + t*8) = o;
}

// ---- RMSNorm2: h = x(f32) + t1(bf16); y = rmsnorm(h)*w -> bf16 ----
__global__ __launch_bounds__(256) void rmsnorm2_k(const float* __restrict__ x,
                                                  const u16* __restrict__ t1,
                                                  const float* __restrict__ w,
                                                  u16* __restrict__ y){
  int row = blockIdx.x, t = threadIdx.x;
  const float4* xr = (const float4*)(x + (size_t)row*2048);
  float4 a = xr[t*2], b = xr[t*2+1];
  bf16x8_t tv = *(const bf16x8_t*)(t1 + (size_t)row*2048 + t*8);
  float h[8];
  h[0]=a.x+bf2f((u16)tv[0]); h[1]=a.y+bf2f((u16)tv[1]);
  h[2]=a.z+bf2f((u16)tv[2]); h[3]=a.w+bf2f((u16)tv[3]);
  h[4]=b.x+bf2f((u16)tv[4]); h[5]=b.y+bf2f((u16)tv[5]);
  h[6]=b.z+bf2f((u16)tv[6]); h[7]=b.w+bf2f((u16)tv[7]);
  float ss = 0.f;
  #pragma unroll
  for (int j=0;j<8;j++) ss += h[j]*h[j];
  #pragma unroll
  for (int m = 32; m; m >>= 1) ss += __shfl_xor(ss, m, 64);
  __shared__ float red[4];
  if ((t & 63) == 0) red[t >> 6] = ss;
  __syncthreads();
  float tot = red[0]+red[1]+red[2]+red[3];
  float rs = rsqrtf(tot * (1.0f/2048.0f) + 1e-6f);
  const float4* wr = (const float4*)w;
  float4 wa = wr[t*2], wb = wr[t*2+1];
  bf16x8_t o;
  o[0]=(short)f2bf(h[0]*rs*wa.x); o[1]=(short)f2bf(h[1]*rs*wa.y);
  o[2]=(short)f2bf(h[2]*rs*wa.z); o[3]=(short)f2bf(h[3]*rs*wa.w);
  o[4]=(short)f2bf(h[4]*rs*wb.x); o[5]=(short)f2bf(h[5]*rs*wb.y);
  o[6]=(short)f2bf(h[6]*rs*wb.z); o[7]=(short)f2bf(h[7]*rs*wb.w);
  *(bf16x8_t*)(y + (size_t)row*2048 + t*8) = o;
}

// ---------------- RoPE in-place on q,k (bf16, B,S,H,HD) ----------------
__global__ __launch_bounds__(256) void rope_k(u16* __restrict__ q, u16* __restrict__ k,
                                              const float* __restrict__ fc,
                                              const float* __restrict__ fs){
  int i = blockIdx.x * 256 + threadIdx.x;
  int ii = i & 63; int h = (i >> 6) & 15; int bs = i >> 10;
  int s = bs & 2047;
  size_t off = (size_t)bs*2048 + h*128 + 2*ii;
  float c = fc[s*64+ii], sn = fs[s*64+ii];
  u32 qq = *(u32*)(q + off);
  float xr = bf2f((u16)(qq & 0xffff)), xi = bf2f((u16)(qq >> 16));
  *(u32*)(q + off) = (u32)f2bf(xr*c - xi*sn) | ((u32)f2bf(xr*sn + xi*c) << 16);
  u32 kk = *(u32*)(k + off);
  xr = bf2f((u16)(kk & 0xffff)); xi = bf2f((u16)(kk >> 16));
  *(u32*)(k + off) = (u32)f2bf(xr*c - xi*sn) | ((u32)f2bf(xr*sn + xi*c) << 16);
}

// ---------------- 2048x8192 transpose (V -> V^T), 64x64 tiles ----------------
__global__ __launch_bounds__(256) void transpose_k(const u16* __restrict__ in,
                                                   u16* __restrict__ out){
  __shared__ u16 tile[64*68];
  int tid = threadIdx.x;
  int tm = blockIdx.x >> 5, tn = blockIdx.x & 31;   // in: [8192][2048]
  const u16* src = in + (size_t)(tm*64)*2048 + tn*64;
  #pragma unroll
  for (int i=0;i<2;i++){
    int idx = i*256 + tid;
    int r = idx >> 3, c8 = (idx & 7)*8;
    *(bf16x8_t*)&tile[r*68 + c8] = *(const bf16x8_t*)(src + (size_t)r*2048 + c8);
  }
  __syncthreads();
  u16* dst = out + (size_t)(tn*64)*8192 + tm*64;
  #pragma unroll
  for (int i=0;i<2;i++){
    int idx = i*256 + tid;
    int oc = idx >> 3, r8 = (idx & 7)*8;
    bf16x8_t v;
    #pragma unroll
    for (int j=0;j<8;j++) v[j] = tile[(r8+j)*68 + oc];
    *(bf16x8_t*)(dst + (size_t)oc*8192 + r8) = v;
  }
}

// ---------------- GEMM: 256x256 tile, BK=64, 8-phase (r9 schedule) ----------
// Identical barrier/vmcnt/stage ledger to round 9 (verified). All in-loop
// addresses are now {lane pointer + compile-time literal} (LDS reads) or
// {per-thread base + SGPR multiple-of-K + scalar col} (staging) -> no per-
// phase VALU address recomputation.

// fragment-read macros: BUF/MH/NHL are literals; offsets fold into ds_read imm
#define RA(BUF,MH) { \
  Ar[0][0]=*(const bf16x8_t*)(pA +BUF*16384+MH*4096);      \
  Ar[0][1]=*(const bf16x8_t*)(pAx+BUF*16384+MH*4096);      \
  Ar[1][0]=*(const bf16x8_t*)(pA +BUF*16384+MH*4096+1024); \
  Ar[1][1]=*(const bf16x8_t*)(pAx+BUF*16384+MH*4096+1024); \
  Ar[2][0]=*(const bf16x8_t*)(pA +BUF*16384+MH*4096+2048); \
  Ar[2][1]=*(const bf16x8_t*)(pAx+BUF*16384+MH*4096+2048); \
  Ar[3][0]=*(const bf16x8_t*)(pA +BUF*16384+MH*4096+3072); \
  Ar[3][1]=*(const bf16x8_t*)(pAx+BUF*16384+MH*4096+3072); }
#define RB(DST,BUF,NHL) { \
  DST[0][0]=*(const bf16x8_t*)(pB +BUF*16384+NHL*2048);      \
  DST[0][1]=*(const bf16x8_t*)(pBx+BUF*16384+NHL*2048);      \
  DST[1][0]=*(const bf16x8_t*)(pB +BUF*16384+NHL*2048+1024); \
  DST[1][1]=*(const bf16x8_t*)(pBx+BUF*16384+NHL*2048+1024); }
// stage one half-tile (2 gl16): BUF/HALF literals, COL scalar (elements)
#define STG_A(BUF,HALF,COL) { \
  gl16(gA + (COL) + HALF*K128,       dA + BUF*16384 + HALF*8192); \
  gl16(gA + (COL) + HALF*K128 + K64, dA + BUF*16384 + HALF*8192 + 4096); }
#define STG_B(BUF,HALF,COL) { \
  gl16(gB + (COL) + HALF*K128,       dB + BUF*16384 + HALF*8192); \
  gl16(gB + (COL) + HALF*K128 + K64, dB + BUF*16384 + HALF*8192 + 4096); }

DEV void MMQ(bf16x8_t (&a)[4][2], bf16x8_t (&b)[2][2], int mh, int nhl,
             f32x4_t (&acc)[8][4]){
  __builtin_amdgcn_s_setprio(1);
  #pragma unroll
  for (int mi=0;mi<4;mi++)
    #pragma unroll
    for (int nj=0;nj<2;nj++)
      #pragma unroll
      for (int kk=0;kk<2;kk++)
        acc[mh*4+mi][nhl*2+nj] = __builtin_amdgcn_mfma_f32_16x16x32_bf16(
            a[mi][kk], b[nj][kk], acc[mh*4+mi][nhl*2+nj], 0,0,0);
  __builtin_amdgcn_s_setprio(0);
}

template<int EPI>
__global__ __launch_bounds__(512, 2) void gemm_bt(const u16* __restrict__ A,
                                                  const u16* __restrict__ B,
                                                  void* __restrict__ C,
                                                  const void* __restrict__ aux,
                                                  const void* __restrict__ aux2,
                                                  int M, int N, int K){
  __shared__ __align__(16) u16 sA[2][2][8192];   // [buf][rowhalf][128x64] 64KB
  __shared__ __align__(16) u16 sB[2][2][8192];   // 64KB
  int tid = threadIdx.x, lane = tid & 63, wave = tid >> 6;
  int l15 = lane & 15, l4 = lane >> 4;
  int nbn = N / 256;
  int nwg = gridDim.x, bid = blockIdx.x;
  int qq = nwg >> 3, rr = nwg & 7;
  int xc = bid & 7, yy = bid >> 3;
  int wg = (xc < rr ? xc*(qq+1) : rr*(qq+1) + (xc-rr)*qq) + yy;
  int tm = wg / nbn, tn = wg % nbn;
  size_t m0 = (size_t)tm*256, n0 = (size_t)tn*256;
  const u16* Ag = A + m0*K;
  const u16* Bg = B + n0*K;
  int wm = wave >> 2, wn = wave & 3;           // 2 x 4 wave grid
  int bh = wn >> 1, wn1 = wn & 1;

  // --- hoisted LDS read lane pointers (kk=0 / kk=1 chunk forms)
  int ch0 = l4 ^ (l15 & 7);
  const u16* pA  = &sA[0][wm][l15*64 + ch0*8];
  const u16* pAx = &sA[0][wm][l15*64 + (ch0^4)*8];
  const u16* pB  = &sB[0][bh][(wn1*64 + l15)*64 + ch0*8];
  const u16* pBx = &sB[0][bh][(wn1*64 + l15)*64 + (ch0^4)*8];
  // --- hoisted staging bases: source chunk0 (rows 0..63), +K64 => chunk1
  int r0 = tid >> 3;
  int lg = (tid & 7) ^ (r0 & 7);
  const u16* gA = Ag + (size_t)r0*K + lg*8;
  const u16* gB = Bg + (size_t)r0*K + lg*8;
  size_t K64 = (size_t)K*64, K128 = K64*2;
  u16* dA = &sA[0][0][tid*8];
  u16* dB = &sB[0][0][tid*8];

  f32x4_t acc[8][4];
  #pragma unroll
  for (int i=0;i<8;i++)
    #pragma unroll
    for (int j=0;j<4;j++)
      acc[i][j] = (f32x4_t){0.f,0.f,0.f,0.f};
  bf16x8_t Ar[4][2], Br0[2][2], Br1[2][2];
  int nk = K / 64;

  // prologue: A(0)->buf0, B(0)->buf0, B(1)->buf1  (12 loads/thread)
  STG_A(0,0,0); STG_A(0,1,0);
  STG_B(0,0,0); STG_B(0,1,0);
  STG_B(1,0,(size_t)64); STG_B(1,1,(size_t)64);
  asm volatile("s_waitcnt vmcnt(4)" ::: "memory");  // A(0),B(0) landed
  BARF();

  for (int i=0; i<nk/2; ++i){
    int T0 = 2*i;
    bool s2 = (T0+2 < nk), s3 = (T0+3 < nk);
    size_t c1 = (size_t)(T0+1)*64, c2 = (size_t)(T0+2)*64, c3 = (size_t)(T0+3)*64;
    // ---- p0: tile T0 (buf0), (mh0,ns0); stage A-h0(T0+1)->buf1
    RA(0,0); RB(Br0,0,0);
    STG_A(1,0,c1);
    BARF(); LGKM0();
    MMQ(Ar, Br0, 0, 0, acc);
    BARF();
    // ---- p1: (mh0,ns1); stage A-h1(T0+1)->buf1
    RB(Br1,0,1);
    STG_A(1,1,c1);
    BARF(); LGKM0();
    MMQ(Ar, Br1, 0, 1, acc);
    BARF();
    // ---- p2: (mh1,ns0); stage B-h0(T0+2)->buf0
    RA(0,1);
    if (s2) STG_B(0,0,c2);
    BARF(); LGKM0();
    MMQ(Ar, Br0, 1, 0, acc);
    BARF();
    // ---- p3: (mh1,ns1); stage B-h1(T0+2); vmcnt(4) => A(T0+1),B(T0+1) landed
    if (s2){
      STG_B(0,1,c2);
      asm volatile("s_waitcnt vmcnt(4)" ::: "memory");
    } else {
      asm volatile("s_waitcnt vmcnt(0)" ::: "memory");
    }
    BARF(); LGKM0();
    MMQ(Ar, Br1, 1, 1, acc);
    BARF();
    // ---- p4: tile T0+1 (buf1), (mh0,ns0); stage A-h0(T0+2)->buf0
    RA(1,0); RB(Br0,1,0);
    if (s2) STG_A(0,0,c2);
    BARF(); LGKM0();
    MMQ(Ar, Br0, 0, 0, acc);
    BARF();
    // ---- p5: (mh0,ns1); stage A-h1(T0+2)->buf0
    RB(Br1,1,1);
    if (s2) STG_A(0,1,c2);
    BARF(); LGKM0();
    MMQ(Ar, Br1, 0, 1, acc);
    BARF();
    // ---- p6: (mh1,ns0); stage B-h0(T0+3)->buf1
    RA(1,1);
    if (s3) STG_B(1,0,c3);
    BARF(); LGKM0();
    MMQ(Ar, Br0, 1, 0, acc);
    BARF();
    // ---- p7: (mh1,ns1); stage B-h1(T0+3); vmcnt(4) => A(T0+2),B(T0+2) landed
    if (s3){
      STG_B(1,1,c3);
      asm volatile("s_waitcnt vmcnt(4)" ::: "memory");
    } else {
      asm volatile("s_waitcnt vmcnt(0)" ::: "memory");
    }
    BARF(); LGKM0();
    MMQ(Ar, Br1, 1, 1, acc);
    BARF();
  }

  #pragma unroll
  for (int am=0; am<8; am++)
    #pragma unroll
    for (int ni=0; ni<4; ni++)
      #pragma unroll
      for (int r=0; r<4; r++){
        float v = acc[am][ni][r];
        size_t rowg = m0 + (am&3)*16 + (am>>2)*64 + wm*128 + l4*4 + r;
        size_t colg = n0 + wn*64 + ni*16 + l15;
        size_t idx = rowg * (size_t)N + colg;
        if constexpr (EPI == 0){
          ((u16*)C)[idx] = f2bf(v);
        } else if constexpr (EPI == 1){
          float s = v / (1.0f + __expf(-v));
          ((u16*)C)[idx] = f2bf(s);
        } else if constexpr (EPI == 2){
          float a = bf2f(((const u16*)aux)[idx]);
          ((u16*)C)[idx] = f2bf(v * a);
        } else {
          float a = ((const float*)aux)[idx];
          float b2 = bf2f(((const u16*)aux2)[idx]);
          ((float*)C)[idx] = v + a + b2;
        }
      }
}

// ---------------- causal flash attention (swapped QK^T, V^T input) ----------
// Fixed-reference softmax (|s| bounded ~25 << exp2 overflow); longest-first.
__global__ __launch_bounds__(256) void attn_k(const u16* __restrict__ Q,
                                              const u16* __restrict__ K,
                                              const u16* __restrict__ VT,
                                              u16* __restrict__ O){
  __shared__ __align__(16) u16 sK[32*128];
  __shared__ __align__(16) u16 sVT[128*32];
  int tid = threadIdx.x, lane = tid & 63, wave = tid >> 6;
  int bid = blockIdx.x;
  int qt = 31 - (bid >> 6);
  int bh = bid & 63; int b = bh >> 4, h = bh & 15;
  int l15 = lane & 15, l4 = lane >> 4;
  size_t base = ((size_t)b*2048)*2048 + (size_t)h*128;
  const u16* VTg0 = VT + ((size_t)h*128)*8192 + (size_t)b*2048;
  int qr0 = qt*64 + wave*16;
  int qrow = qr0 + l15;                       // this lane's single q row
  bf16x8_t qf[4];
  #pragma unroll
  for (int s=0;s<4;s++)
    qf[s] = *(const bf16x8_t*)(Q + base + (size_t)qrow*2048 + s*32 + l4*8);

  f32x4_t oaccT[8];                           // O^T: d = f*16 + l4*4 + r, q = l15
  #pragma unroll
  for (int f=0;f<8;f++) oaccT[f] = (f32x4_t){0.f,0.f,0.f,0.f};
  float lrun = 0.f;

  const float cl2 = 0.08838834764831845f * 1.4426950408889634f; // scale*log2e
  int nkt = (qt + 1) * 2;
  for (int kt=0; kt<nkt; ++kt){
    __syncthreads();          // prior tile's LDS reads done
    const u16* Kg = K + base + (size_t)kt*32*2048;
    #pragma unroll
    for (int i=0;i<2;i++){
      int c = i*256 + tid; int row = c>>4;
      gl16(Kg + (size_t)row*2048 + (size_t)(((c&15) ^ (row&7))*8), &sK[c*8]);
    }
    #pragma unroll
    for (int i=0;i<2;i++){
      int c = i*256 + tid; int d = c>>2;
      gl16(VTg0 + (size_t)d*8192 + kt*32 + (size_t)((((c&3) ^ ((d>>1)&3)))*8),
           &sVT[c*8]);
    }
    __syncthreads();          // staged data visible

    if (kt*32 <= qr0 + 15){   // wave-uniform skip of fully-masked tiles
      f32x4_t sacc[2];
      sacc[0] = (f32x4_t){0.f,0.f,0.f,0.f};
      sacc[1] = (f32x4_t){0.f,0.f,0.f,0.f};
      __builtin_amdgcn_s_setprio(1);
      #pragma unroll
      for (int n=0;n<2;n++)
        #pragma unroll
        for (int s=0;s<4;s++){
          bf16x8_t kf = *(const bf16x8_t*)
              &sK[(n*16 + l15)*128 + (((s*4 + l4) ^ (l15 & 7))*8)];
          sacc[n] = __builtin_amdgcn_mfma_f32_16x16x32_bf16(kf, qf[s], sacc[n], 0,0,0);
        }
      __builtin_amdgcn_s_setprio(0);
      float sum = 0.f;
      bf16x8_t pa;
      bool diag = (kt*32 + 31 > qr0);         // wave-uniform
      if (diag){
        #pragma unroll
        for (int j=0;j<8;j++){
          int n = j>>2, r = j&3;
          float p = exp2f(sacc[n][r] * cl2);
          int kg = kt*32 + n*16 + l4*4 + r;
          if (kg > qrow) p = 0.f;
          sum += p;
          pa[j] = (short)f2bf(p);
        }
      } else {
        #pragma unroll
        for (int j=0;j<8;j++){
          float p = exp2f(sacc[j>>2][j&3] * cl2);
          sum += p;
          pa[j] = (short)f2bf(p);
        }
      }
      sum += __shfl_xor(sum, 16, 64);
      sum += __shfl_xor(sum, 32, 64);
      lrun += sum;
      __builtin_amdgcn_s_setprio(1);
      #pragma unroll
      for (int f=0;f<8;f++){
        int d = f*16 + l15;
        bf16x4_t lo = *(const bf16x4_t*)&sVT[d*32 + (((0*4 + l4) ^ (d & 6))*4)];
        bf16x4_t hi = *(const bf16x4_t*)&sVT[d*32 + (((1*4 + l4) ^ (d & 6))*4)];
        bf16x8_t va;
        va[0]=lo[0]; va[1]=lo[1]; va[2]=lo[2]; va[3]=lo[3];
        va[4]=hi[0]; va[5]=hi[1]; va[6]=hi[2]; va[7]=hi[3];
        oaccT[f] = __builtin_amdgcn_mfma_f32_16x16x32_bf16(va, pa, oaccT[f], 0,0,0);
      }
      __builtin_amdgcn_s_setprio(0);
    }
  }
  float inv = 1.0f / lrun;
  size_t orow = (size_t)b*2048 + qrow;
  #pragma unroll
  for (int f=0;f<8;f++){
    bf16x4_t ov;
    ov[0]=(short)f2bf(oaccT[f][0]*inv); ov[1]=(short)f2bf(oaccT[f][1]*inv);
    ov[2]=(short)f2bf(oaccT[f][2]*inv); ov[3]=(short)f2bf(oaccT[f][3]*inv);
    *(bf16x4_t*)(O + orow*2048 + h*128 + f*16 + l4*4) = ov;
  }
}

// ---------------- host ----------------
extern "C" void kernel_launch(void* const* d_in, const int* in_sizes, int n_in,
                              void* d_out, int out_size, void* d_ws, size_t ws_size,
                              hipStream_t stream){
  (void)in_sizes; (void)n_in; (void)out_size; (void)ws_size;
  const float* x   = (const float*)d_in[0];
  const float* fc  = (const float*)d_in[1];
  const float* fs  = (const float*)d_in[2];
  const float* wq  = (const float*)d_in[4];
  const float* wk  = (const float*)d_in[5];
  const float* wv  = (const float*)d_in[6];
  const float* wo  = (const float*)d_in[7];
  const float* w1  = (const float*)d_in[8];
  const float* w2  = (const float*)d_in[9];
  const float* w3  = (const float*)d_in[10];
  const float* anw = (const float*)d_in[11];
  const float* fnw = (const float*)d_in[12];
  float* out = (float*)d_out;
  char* ws = (char*)d_ws;

  const int M = 8192, D = 2048, HID = 5632;
  const size_t WB   = 23068672ull;   // 5632*2048*2 (reused weight buf)
  const size_t ACT2 = 33554432ull;   // 8192*2048*2

  u16* wbuf = (u16*)(ws);
  u16* xa   = (u16*)(ws + WB);                // rmsnorm(x); later attn O
  u16* qb   = (u16*)(ws + WB + ACT2);         // Q; later t1 = o@wo^T
  u16* kb   = (u16*)(ws + WB + 2*ACT2);       // K; later hf
  u16* vb   = (u16*)(ws + WB + 3*ACT2);       // V
  u16* g1   = (u16*)(ws + WB + 4*ACT2);       // VT (32MB) then g1 (88 MiB)
  u16* vt = g1;
  u16* t1 = qb;
  u16* hf = kb;

  rmsnorm_k<<<M, 256, 0, stream>>>(x, anw, xa);

  cvt_k<<<D*D/8/256, 256, 0, stream>>>(wq, wbuf, D*D/8);
  gemm_bt<0><<<(M/256)*(D/256), 512, 0, stream>>>(xa, wbuf, qb, nullptr, nullptr, M, D, D);
  cvt_k<<<D*D/8/256, 256, 0, stream>>>(wk, wbuf, D*D/8);
  gemm_bt<0><<<(M/256)*(D/256), 512, 0, stream>>>(xa, wbuf, kb, nullptr, nullptr, M, D, D);
  cvt_k<<<D*D/8/256, 256, 0, stream>>>(wv, wbuf, D*D/8);
  gemm_bt<0><<<(M/256)*(D/256), 512, 0, stream>>>(xa, wbuf, vb, nullptr, nullptr, M, D, D);

  rope_k<<<32768, 256, 0, stream>>>(qb, kb, fc, fs);
  transpose_k<<<4096, 256, 0, stream>>>(vb, vt);      // V[8192][2048] -> VT[2048][8192]

  attn_k<<<2048, 256, 0, stream>>>(qb, kb, vt, xa);   // O -> xa

  cvt_k<<<D*D/8/256, 256, 0, stream>>>(wo, wbuf, D*D/8);
  gemm_bt<0><<<(M/256)*(D/256), 512, 0, stream>>>(xa, wbuf, t1, nullptr, nullptr, M, D, D);

  rmsnorm2_k<<<M, 256, 0, stream>>>(x, t1, fnw, hf);

  cvt_k<<<HID*D/8/256, 256, 0, stream>>>(w1, wbuf, HID*D/8);
  gemm_bt<1><<<(M/256)*(HID/256), 512, 0, stream>>>(hf, wbuf, g1, nullptr, nullptr, M, HID, D);
  cvt_k<<<HID*D/8/256, 256, 0, stream>>>(w3, wbuf, HID*D/8);
  gemm_bt<2><<<(M/256)*(HID/256), 512, 0, stream>>>(hf, wbuf, g1, g1, nullptr, M, HID, D);
  cvt_k<<<HID*D/8/256, 256, 0, stream>>>(w2, wbuf, HID*D/8);
  gemm_bt<4><<<(M/256)*(D/256), 512, 0, stream>>>(g1, wbuf, out, x, t1, M, D, HID);
}

// Round 11
// 1116.820 us; speedup vs baseline: 2.0501x; 1.0003x over previous
//
#include <hip/hip_runtime.h>
#include <hip/hip_bf16.h>
#include <stdint.h>

typedef short  bf16x8_t __attribute__((ext_vector_type(8)));
typedef short  bf16x4_t __attribute__((ext_vector_type(4)));
typedef float  f32x4_t  __attribute__((ext_vector_type(4)));
typedef unsigned short u16;
typedef unsigned int   u32;

#define DEV __device__ __forceinline__

DEV u16 f2bf(float f){
  u32 u = __float_as_uint(f);
  u += 0x7fffu + ((u >> 16) & 1u);     // RNE
  return (u16)(u >> 16);
}
DEV float bf2f(u16 h){ return __uint_as_float(((u32)h) << 16); }

DEV void gl16(const void* g, void* l){
  __builtin_amdgcn_global_load_lds(
      (const __attribute__((address_space(1))) void*)g,
      (__attribute__((address_space(3))) void*)l, 16, 0, 0);
}

#define BAR() __builtin_amdgcn_s_barrier()
#define WL8() asm volatile("s_waitcnt lgkmcnt(8)" ::: "memory")
#define WL0() asm volatile("s_waitcnt lgkmcnt(0)" ::: "memory")

// ---------------- f32 -> bf16 convert (8 elems/thread) ----------------
__global__ __launch_bounds__(256) void cvt_k(const float* __restrict__ in,
                                             u16* __restrict__ out, int n8){
  int i = blockIdx.x * 256 + threadIdx.x;
  if (i >= n8) return;
  const float4* p = (const float4*)in;
  float4 a = p[(size_t)i*2], b = p[(size_t)i*2+1];
  bf16x8_t o;
  o[0]=(short)f2bf(a.x); o[1]=(short)f2bf(a.y); o[2]=(short)f2bf(a.z); o[3]=(short)f2bf(a.w);
  o[4]=(short)f2bf(b.x); o[5]=(short)f2bf(b.y); o[6]=(short)f2bf(b.z); o[7]=(short)f2bf(b.w);
  *(bf16x8_t*)(out + (size_t)i*8) = o;
}

// ---------------- RMSNorm: fp32 row (D=2048) -> bf16 ----------------
__global__ __launch_bounds__(256) void rmsnorm_k(const float* __restrict__ x,
                                                 const float* __restrict__ w,
                                                 u16* __restrict__ y){
  int row = blockIdx.x, t = threadIdx.x;
  const float4* xr = (const float4*)(x + (size_t)row*2048);
  float4 a = xr[t*2], b = xr[t*2+1];
  float ss = a.x*a.x+a.y*a.y+a.z*a.z+a.w*a.w + b.x*b.x+b.y*b.y+b.z*b.z+b.w*b.w;
  #pragma unroll
  for (int m = 32; m; m >>= 1) ss += __shfl_xor(ss, m, 64);
  __shared__ float red[4];
  if ((t & 63) == 0) red[t >> 6] = ss;
  __syncthreads();
  float tot = red[0]+red[1]+red[2]+red[3];
  float rs = rsqrtf(tot * (1.0f/2048.0f) + 1e-6f);
  const float4* wr = (const float4*)w;
  float4 wa = wr[t*2], wb = wr[t*2+1];
  bf16x8_t o;
  o[0]=(short)f2bf(a.x*rs*wa.x); o[1]=(short)f2bf(a.y*rs*wa.y);
  o[2]=(short)f2bf(a.z*rs*wa.z); o[3]=(short)f2bf(a.w*rs*wa.w);
  o[4]=(short)f2bf(b.x*rs*wb.x); o[5]=(short)f2bf(b.y*rs*wb.y);
  o[6]=(short)f2bf(b.z*rs*wb.z); o[7]=(short)f2bf(b.w*rs*wb.w);
  *(bf16x8_t*)(y + (size_t)row*2048 + t*8) = o;
}

// ---- RMSNorm2: h = x(f32) + t1(bf16); y = rmsnorm(h)*w -> bf16 ----
__global__ __launch_bounds__(256) void rmsnorm2_k(const float* __restrict__ x,
                                                  const u16* __restrict__ t1,
                                                  const float* __restrict__ w,
                                                  u16* __restrict__ y){
  int row = blockIdx.x, t = threadIdx.x;
  const float4* xr = (const float4*)(x + (size_t)row*2048);
  float4 a = xr[t*2], b = xr[t*2+1];
  bf16x8_t tv = *(const bf16x8_t*)(t1 + (size_t)row*2048 + t*8);
  float h[8];
  h[0]=a.x+bf2f((u16)tv[0]); h[1]=a.y+bf2f((u16)tv[1]);
  h[2]=a.z+bf2f((u16)tv[2]); h[3]=a.w+bf2f((u16)tv[3]);
  h[4]=b.x+bf2f((u16)tv[4]); h[5]=b.y+bf2f((u16)tv[5]);
  h[6]=b.z+bf2f((u16)tv[6]); h[7]=b.w+bf2f((u16)tv[7]);
  float ss = 0.f;
  #pragma unroll
  for (int j=0;j<8;j++) ss += h[j]*h[j];
  #pragma unroll
  for (int m = 32; m; m >>= 1) ss += __shfl_xor(ss, m, 64);
  __shared__ float red[4];
  if ((t & 63) == 0) red[t >> 6] = ss;
  __syncthreads();
  float tot = red[0]+red[1]+red[2]+red[3];
  float rs = rsqrtf(tot * (1.0f/2048.0f) + 1e-6f);
  const float4* wr = (const float4*)w;
  float4 wa = wr[t*2], wb = wr[t*2+1];
  bf16x8_t o;
  o[0]=(short)f2bf(h[0]*rs*wa.x); o[1]=(short)f2bf(h[1]*rs*wa.y);
  o[2]=(short)f2bf(h[2]*rs*wa.z); o[3]=(short)f2bf(h[3]*rs*wa.w);
  o[4]=(short)f2bf(h[4]*rs*wb.x); o[5]=(short)f2bf(h[5]*rs*wb.y);
  o[6]=(short)f2bf(h[6]*rs*wb.z); o[7]=(short)f2bf(h[7]*rs*wb.w);
  *(bf16x8_t*)(y + (size_t)row*2048 + t*8) = o;
}

// ---------------- RoPE in-place on q,k (bf16, B,S,H,HD) ----------------
__global__ __launch_bounds__(256) void rope_k(u16* __restrict__ q, u16* __restrict__ k,
                                              const float* __restrict__ fc,
                                              const float* __restrict__ fs){
  int i = blockIdx.x * 256 + threadIdx.x;
  int ii = i & 63; int h = (i >> 6) & 15; int bs = i >> 10;
  int s = bs & 2047;
  size_t off = (size_t)bs*2048 + h*128 + 2*ii;
  float c = fc[s*64+ii], sn = fs[s*64+ii];
  u32 qq = *(u32*)(q + off);
  float xr = bf2f((u16)(qq & 0xffff)), xi = bf2f((u16)(qq >> 16));
  *(u32*)(q + off) = (u32)f2bf(xr*c - xi*sn) | ((u32)f2bf(xr*sn + xi*c) << 16);
  u32 kk = *(u32*)(k + off);
  xr = bf2f((u16)(kk & 0xffff)); xi = bf2f((u16)(kk >> 16));
  *(u32*)(k + off) = (u32)f2bf(xr*c - xi*sn) | ((u32)f2bf(xr*sn + xi*c) << 16);
}

// ---------------- 2048x8192 transpose (V -> V^T), 64x64 tiles ----------------
__global__ __launch_bounds__(256) void transpose_k(const u16* __restrict__ in,
                                                   u16* __restrict__ out){
  __shared__ u16 tile[64*68];
  int tid = threadIdx.x;
  int tm = blockIdx.x >> 5, tn = blockIdx.x & 31;   // in: [8192][2048]
  const u16* src = in + (size_t)(tm*64)*2048 + tn*64;
  #pragma unroll
  for (int i=0;i<2;i++){
    int idx = i*256 + tid;
    int r = idx >> 3, c8 = (idx & 7)*8;
    *(bf16x8_t*)&tile[r*68 + c8] = *(const bf16x8_t*)(src + (size_t)r*2048 + c8);
  }
  __syncthreads();
  u16* dst = out + (size_t)(tn*64)*8192 + tm*64;
  #pragma unroll
  for (int i=0;i<2;i++){
    int idx = i*256 + tid;
    int oc = idx >> 3, r8 = (idx & 7)*8;
    bf16x8_t v;
    #pragma unroll
    for (int j=0;j<8;j++) v[j] = tile[(r8+j)*68 + oc];
    *(bf16x8_t*)(dst + (size_t)oc*8192 + r8) = v;
  }
}

// ---------------- GEMM: 256x256 tile, BK=64, 8-phase (r9 ledger) ----------
// m201 phase discipline: {ds-reads, stage, [lgkmcnt(8) if 12 reads], barrier,
// lgkmcnt(0), setprio(1), 16 MFMA, setprio(0), barrier}. NO sched_barrier(0)
// anywhere in the loop (m141: SB0 order-pinning defeats the scheduler).
// vmcnt(4) only at p3/p7 (FIFO ledger verified r9). Addresses hoisted (r10).

#define RA(BUF,MH) { \
  Ar[0][0]=*(const bf16x8_t*)(pA +BUF*16384+MH*4096);      \
  Ar[0][1]=*(const bf16x8_t*)(pAx+BUF*16384+MH*4096);      \
  Ar[1][0]=*(const bf16x8_t*)(pA +BUF*16384+MH*4096+1024); \
  Ar[1][1]=*(const bf16x8_t*)(pAx+BUF*16384+MH*4096+1024); \
  Ar[2][0]=*(const bf16x8_t*)(pA +BUF*16384+MH*4096+2048); \
  Ar[2][1]=*(const bf16x8_t*)(pAx+BUF*16384+MH*4096+2048); \
  Ar[3][0]=*(const bf16x8_t*)(pA +BUF*16384+MH*4096+3072); \
  Ar[3][1]=*(const bf16x8_t*)(pAx+BUF*16384+MH*4096+3072); }
#define RB(DST,BUF,NHL) { \
  DST[0][0]=*(const bf16x8_t*)(pB +BUF*16384+NHL*2048);      \
  DST[0][1]=*(const bf16x8_t*)(pBx+BUF*16384+NHL*2048);      \
  DST[1][0]=*(const bf16x8_t*)(pB +BUF*16384+NHL*2048+1024); \
  DST[1][1]=*(const bf16x8_t*)(pBx+BUF*16384+NHL*2048+1024); }
#define STG_A(BUF,HALF,COL) { \
  gl16(gA + (COL) + HALF*K128,       dA + BUF*16384 + HALF*8192); \
  gl16(gA + (COL) + HALF*K128 + K64, dA + BUF*16384 + HALF*8192 + 4096); }
#define STG_B(BUF,HALF,COL) { \
  gl16(gB + (COL) + HALF*K128,       dB + BUF*16384 + HALF*8192); \
  gl16(gB + (COL) + HALF*K128 + K64, dB + BUF*16384 + HALF*8192 + 4096); }

// 16 MFMA cluster, kk OUTERMOST: 8 independent MFMAs between dependent pairs
DEV void MMQ(bf16x8_t (&a)[4][2], bf16x8_t (&b)[2][2], int mh, int nhl,
             f32x4_t (&acc)[8][4]){
  __builtin_amdgcn_s_setprio(1);
  #pragma unroll
  for (int kk=0;kk<2;kk++)
    #pragma unroll
    for (int mi=0;mi<4;mi++)
      #pragma unroll
      for (int nj=0;nj<2;nj++)
        acc[mh*4+mi][nhl*2+nj] = __builtin_amdgcn_mfma_f32_16x16x32_bf16(
            a[mi][kk], b[nj][kk], acc[mh*4+mi][nhl*2+nj], 0,0,0);
  __builtin_amdgcn_s_setprio(0);
}

template<int EPI>
__global__ __launch_bounds__(512, 2) void gemm_bt(const u16* __restrict__ A,
                                                  const u16* __restrict__ B,
                                                  void* __restrict__ C,
                                                  const void* __restrict__ aux,
                                                  const void* __restrict__ aux2,
                                                  int M, int N, int K){
  __shared__ __align__(16) u16 sA[2][2][8192];   // [buf][rowhalf][128x64] 64KB
  __shared__ __align__(16) u16 sB[2][2][8192];   // 64KB
  int tid = threadIdx.x, lane = tid & 63, wave = tid >> 6;
  int l15 = lane & 15, l4 = lane >> 4;
  int nbn = N / 256;
  int nwg = gridDim.x, bid = blockIdx.x;
  int qq = nwg >> 3, rr = nwg & 7;
  int xc = bid & 7, yy = bid >> 3;
  int wg = (xc < rr ? xc*(qq+1) : rr*(qq+1) + (xc-rr)*qq) + yy;
  int tm = wg / nbn, tn = wg % nbn;
  size_t m0 = (size_t)tm*256, n0 = (size_t)tn*256;
  const u16* Ag = A + m0*K;
  const u16* Bg = B + n0*K;
  int wm = wave >> 2, wn = wave & 3;           // 2 x 4 wave grid
  int bh = wn >> 1, wn1 = wn & 1;

  // hoisted LDS read lane pointers (kk=0 / kk=1 chunk forms)
  int ch0 = l4 ^ (l15 & 7);
  const u16* pA  = &sA[0][wm][l15*64 + ch0*8];
  const u16* pAx = &sA[0][wm][l15*64 + (ch0^4)*8];
  const u16* pB  = &sB[0][bh][(wn1*64 + l15)*64 + ch0*8];
  const u16* pBx = &sB[0][bh][(wn1*64 + l15)*64 + (ch0^4)*8];
  // hoisted staging bases
  int r0 = tid >> 3;
  int lg = (tid & 7) ^ (r0 & 7);
  const u16* gA = Ag + (size_t)r0*K + lg*8;
  const u16* gB = Bg + (size_t)r0*K + lg*8;
  size_t K64 = (size_t)K*64, K128 = K64*2;
  u16* dA = &sA[0][0][tid*8];
  u16* dB = &sB[0][0][tid*8];

  f32x4_t acc[8][4];
  #pragma unroll
  for (int i=0;i<8;i++)
    #pragma unroll
    for (int j=0;j<4;j++)
      acc[i][j] = (f32x4_t){0.f,0.f,0.f,0.f};
  bf16x8_t Ar[4][2], Br0[2][2], Br1[2][2];
  int nk = K / 64;

  // prologue: A(0)->buf0, B(0)->buf0, B(1)->buf1  (12 loads/thread)
  STG_A(0,0,0); STG_A(0,1,0);
  STG_B(0,0,0); STG_B(0,1,0);
  STG_B(1,0,(size_t)64); STG_B(1,1,(size_t)64);
  asm volatile("s_waitcnt vmcnt(4)" ::: "memory");  // A(0),B(0) landed
  BAR();

  for (int i=0; i<nk/2; ++i){
    int T0 = 2*i;
    bool s2 = (T0+2 < nk), s3 = (T0+3 < nk);
    size_t c1 = (size_t)(T0+1)*64, c2 = (size_t)(T0+2)*64, c3 = (size_t)(T0+3)*64;
    // ---- p0: tile T0 (buf0), (mh0,ns0); stage A-h0(T0+1)->buf1 [12 reads]
    RA(0,0); RB(Br0,0,0);
    STG_A(1,0,c1);
    WL8(); BAR(); WL0();
    MMQ(Ar, Br0, 0, 0, acc);
    BAR();
    // ---- p1: (mh0,ns1); stage A-h1(T0+1)->buf1
    RB(Br1,0,1);
    STG_A(1,1,c1);
    BAR(); WL0();
    MMQ(Ar, Br1, 0, 1, acc);
    BAR();
    // ---- p2: (mh1,ns0); stage B-h0(T0+2)->buf0
    RA(0,1);
    if (s2) STG_B(0,0,c2);
    BAR(); WL0();
    MMQ(Ar, Br0, 1, 0, acc);
    BAR();
    // ---- p3: (mh1,ns1); stage B-h1(T0+2); vmcnt(4) => A(T0+1),B(T0+1) landed
    if (s2){
      STG_B(0,1,c2);
      asm volatile("s_waitcnt vmcnt(4)" ::: "memory");
    } else {
      asm volatile("s_waitcnt vmcnt(0)" ::: "memory");
    }
    BAR(); WL0();
    MMQ(Ar, Br1, 1, 1, acc);
    BAR();
    // ---- p4: tile T0+1 (buf1), (mh0,ns0); stage A-h0(T0+2)->buf0 [12 reads]
    RA(1,0); RB(Br0,1,0);
    if (s2) STG_A(0,0,c2);
    WL8(); BAR(); WL0();
    MMQ(Ar, Br0, 0, 0, acc);
    BAR();
    // ---- p5: (mh0,ns1); stage A-h1(T0+2)->buf0
    RB(Br1,1,1);
    if (s2) STG_A(0,1,c2);
    BAR(); WL0();
    MMQ(Ar, Br1, 0, 1, acc);
    BAR();
    // ---- p6: (mh1,ns0); stage B-h0(T0+3)->buf1
    RA(1,1);
    if (s3) STG_B(1,0,c3);
    BAR(); WL0();
    MMQ(Ar, Br0, 1, 0, acc);
    BAR();
    // ---- p7: (mh1,ns1); stage B-h1(T0+3); vmcnt(4) => A(T0+2),B(T0+2) landed
    if (s3){
      STG_B(1,1,c3);
      asm volatile("s_waitcnt vmcnt(4)" ::: "memory");
    } else {
      asm volatile("s_waitcnt vmcnt(0)" ::: "memory");
    }
    BAR(); WL0();
    MMQ(Ar, Br1, 1, 1, acc);
    BAR();
  }

  #pragma unroll
  for (int am=0; am<8; am++)
    #pragma unroll
    for (int ni=0; ni<4; ni++)
      #pragma unroll
      for (int r=0; r<4; r++){
        float v = acc[am][ni][r];
        size_t rowg = m0 + (am&3)*16 + (am>>2)*64 + wm*128 + l4*4 + r;
        size_t colg = n0 + wn*64 + ni*16 + l15;
        size_t idx = rowg * (size_t)N + colg;
        if constexpr (EPI == 0){
          ((u16*)C)[idx] = f2bf(v);
        } else if constexpr (EPI == 1){
          float s = v / (1.0f + __expf(-v));
          ((u16*)C)[idx] = f2bf(s);
        } else if constexpr (EPI == 2){
          float a = bf2f(((const u16*)aux)[idx]);
          ((u16*)C)[idx] = f2bf(v * a);
        } else {
          float a = ((const float*)aux)[idx];
          float b2 = bf2f(((const u16*)aux2)[idx]);
          ((float*)C)[idx] = v + a + b2;
        }
      }
}

// ---------------- causal flash attention (swapped QK^T, V^T input) ----------
// Fixed-reference softmax (|s| bounded ~25 << exp2 overflow); longest-first.
__global__ __launch_bounds__(256) void attn_k(const u16* __restrict__ Q,
                                              const u16* __restrict__ K,
                                              const u16* __restrict__ VT,
                                              u16* __restrict__ O){
  __shared__ __align__(16) u16 sK[32*128];
  __shared__ __align__(16) u16 sVT[128*32];
  int tid = threadIdx.x, lane = tid & 63, wave = tid >> 6;
  int bid = blockIdx.x;
  int qt = 31 - (bid >> 6);
  int bh = bid & 63; int b = bh >> 4, h = bh & 15;
  int l15 = lane & 15, l4 = lane >> 4;
  size_t base = ((size_t)b*2048)*2048 + (size_t)h*128;
  const u16* VTg0 = VT + ((size_t)h*128)*8192 + (size_t)b*2048;
  int qr0 = qt*64 + wave*16;
  int qrow = qr0 + l15;                       // this lane's single q row
  bf16x8_t qf[4];
  #pragma unroll
  for (int s=0;s<4;s++)
    qf[s] = *(const bf16x8_t*)(Q + base + (size_t)qrow*2048 + s*32 + l4*8);

  f32x4_t oaccT[8];                           // O^T: d = f*16 + l4*4 + r, q = l15
  #pragma unroll
  for (int f=0;f<8;f++) oaccT[f] = (f32x4_t){0.f,0.f,0.f,0.f};
  float lrun = 0.f;

  const float cl2 = 0.08838834764831845f * 1.4426950408889634f; // scale*log2e
  int nkt = (qt + 1) * 2;
  for (int kt=0; kt<nkt; ++kt){
    __syncthreads();          // prior tile's LDS reads done
    const u16* Kg = K + base + (size_t)kt*32*2048;
    #pragma unroll
    for (int i=0;i<2;i++){
      int c = i*256 + tid; int row = c>>4;
      gl16(Kg + (size_t)row*2048 + (size_t)(((c&15) ^ (row&7))*8), &sK[c*8]);
    }
    #pragma unroll
    for (int i=0;i<2;i++){
      int c = i*256 + tid; int d = c>>2;
      gl16(VTg0 + (size_t)d*8192 + kt*32 + (size_t)((((c&3) ^ ((d>>1)&3)))*8),
           &sVT[c*8]);
    }
    __syncthreads();          // staged data visible

    if (kt*32 <= qr0 + 15){   // wave-uniform skip of fully-masked tiles
      f32x4_t sacc[2];
      sacc[0] = (f32x4_t){0.f,0.f,0.f,0.f};
      sacc[1] = (f32x4_t){0.f,0.f,0.f,0.f};
      __builtin_amdgcn_s_setprio(1);
      #pragma unroll
      for (int n=0;n<2;n++)
        #pragma unroll
        for (int s=0;s<4;s++){
          bf16x8_t kf = *(const bf16x8_t*)
              &sK[(n*16 + l15)*128 + (((s*4 + l4) ^ (l15 & 7))*8)];
          sacc[n] = __builtin_amdgcn_mfma_f32_16x16x32_bf16(kf, qf[s], sacc[n], 0,0,0);
        }
      __builtin_amdgcn_s_setprio(0);
      float sum = 0.f;
      bf16x8_t pa;
      bool diag = (kt*32 + 31 > qr0);         // wave-uniform
      if (diag){
        #pragma unroll
        for (int j=0;j<8;j++){
          int n = j>>2, r = j&3;
          float p = exp2f(sacc[n][r] * cl2);
          int kg = kt*32 + n*16 + l4*4 + r;
          if (kg > qrow) p = 0.f;
          sum += p;
          pa[j] = (short)f2bf(p);
        }
      } else {
        #pragma unroll
        for (int j=0;j<8;j++){
          float p = exp2f(sacc[j>>2][j&3] * cl2);
          sum += p;
          pa[j] = (short)f2bf(p);
        }
      }
      sum += __shfl_xor(sum, 16, 64);
      sum += __shfl_xor(sum, 32, 64);
      lrun += sum;
      __builtin_amdgcn_s_setprio(1);
      #pragma unroll
      for (int f=0;f<8;f++){
        int d = f*16 + l15;
        bf16x4_t lo = *(const bf16x4_t*)&sVT[d*32 + (((0*4 + l4) ^ (d & 6))*4)];
        bf16x4_t hi = *(const bf16x4_t*)&sVT[d*32 + (((1*4 + l4) ^ (d & 6))*4)];
        bf16x8_t va;
        va[0]=lo[0]; va[1]=lo[1]; va[2]=lo[2]; va[3]=lo[3];
        va[4]=hi[0]; va[5]=hi[1]; va[6]=hi[2]; va[7]=hi[3];
        oaccT[f] = __builtin_amdgcn_mfma_f32_16x16x32_bf16(va, pa, oaccT[f], 0,0,0);
      }
      __builtin_amdgcn_s_setprio(0);
    }
  }
  float inv = 1.0f / lrun;
  size_t orow = (size_t)b*2048 + qrow;
  #pragma unroll
  for (int f=0;f<8;f++){
    bf16x4_t ov;
    ov[0]=(short)f2bf(oaccT[f][0]*inv); ov[1]=(short)f2bf(oaccT[f][1]*inv);
    ov[2]=(short)f2bf(oaccT[f][2]*inv); ov[3]=(short)f2bf(oaccT[f][3]*inv);
    *(bf16x4_t*)(O + orow*2048 + h*128 + f*16 + l4*4) = ov;
  }
}

// ---------------- host ----------------
extern "C" void kernel_launch(void* const* d_in, const int* in_sizes, int n_in,
                              void* d_out, int out_size, void* d_ws, size_t ws_size,
                              hipStream_t stream){
  (void)in_sizes; (void)n_in; (void)out_size; (void)ws_size;
  const float* x   = (const float*)d_in[0];
  const float* fc  = (const float*)d_in[1];
  const float* fs  = (const float*)d_in[2];
  const float* wq  = (const float*)d_in[4];
  const float* wk  = (const float*)d_in[5];
  const float* wv  = (const float*)d_in[6];
  const float* wo  = (const float*)d_in[7];
  const float* w1  = (const float*)d_in[8];
  const float* w2  = (const float*)d_in[9];
  const float* w3  = (const float*)d_in[10];
  const float* anw = (const float*)d_in[11];
  const float* fnw = (const float*)d_in[12];
  float* out = (float*)d_out;
  char* ws = (char*)d_ws;

  const int M = 8192, D = 2048, HID = 5632;
  const size_t WB   = 23068672ull;   // 5632*2048*2 (reused weight buf)
  const size_t ACT2 = 33554432ull;   // 8192*2048*2

  u16* wbuf = (u16*)(ws);
  u16* xa   = (u16*)(ws + WB);                // rmsnorm(x); later attn O
  u16* qb   = (u16*)(ws + WB + ACT2);         // Q; later t1 = o@wo^T
  u16* kb   = (u16*)(ws + WB + 2*ACT2);       // K; later hf
  u16* vb   = (u16*)(ws + WB + 3*ACT2);       // V
  u16* g1   = (u16*)(ws + WB + 4*ACT2);       // VT (32MB) then g1 (88 MiB)
  u16* vt = g1;
  u16* t1 = qb;
  u16* hf = kb;

  rmsnorm_k<<<M, 256, 0, stream>>>(x, anw, xa);

  cvt_k<<<D*D/8/256, 256, 0, stream>>>(wq, wbuf, D*D/8);
  gemm_bt<0><<<(M/256)*(D/256), 512, 0, stream>>>(xa, wbuf, qb, nullptr, nullptr, M, D, D);
  cvt_k<<<D*D/8/256, 256, 0, stream>>>(wk, wbuf, D*D/8);
  gemm_bt<0><<<(M/256)*(D/256), 512, 0, stream>>>(xa, wbuf, kb, nullptr, nullptr, M, D, D);
  cvt_k<<<D*D/8/256, 256, 0, stream>>>(wv, wbuf, D*D/8);
  gemm_bt<0><<<(M/256)*(D/256), 512, 0, stream>>>(xa, wbuf, vb, nullptr, nullptr, M, D, D);

  rope_k<<<32768, 256, 0, stream>>>(qb, kb, fc, fs);
  transpose_k<<<4096, 256, 0, stream>>>(vb, vt);      // V[8192][2048] -> VT[2048][8192]

  attn_k<<<2048, 256, 0, stream>>>(qb, kb, vt, xa);   // O -> xa

  cvt_k<<<D*D/8/256, 256, 0, stream>>>(wo, wbuf, D*D/8);
  gemm_bt<0><<<(M/256)*(D/256), 512, 0, stream>>>(xa, wbuf, t1, nullptr, nullptr, M, D, D);

  rmsnorm2_k<<<M, 256, 0, stream>>>(x, t1, fnw, hf);

  cvt_k<<<HID*D/8/256, 256, 0, stream>>>(w1, wbuf, HID*D/8);
  gemm_bt<1><<<(M/256)*(HID/256), 512, 0, stream>>>(hf, wbuf, g1, nullptr, nullptr, M, HID, D);
  cvt_k<<<HID*D/8/256, 256, 0, stream>>>(w3, wbuf, HID*D/8);
  gemm_bt<2><<<(M/256)*(HID/256), 512, 0, stream>>>(hf, wbuf, g1, g1, nullptr, M, HID, D);
  cvt_k<<<HID*D/8/256, 256, 0, stream>>>(w2, wbuf, HID*D/8);
  gemm_bt<4><<<(M/256)*(D/256), 512, 0, stream>>>(g1, wbuf, out, x, t1, M, D, HID);
}